// Round 3
// baseline (6505.830 us; speedup 1.0000x reference)
//
#include <hip/hip_runtime.h>
#include <stdint.h>
#include <stddef.h>
#include <math.h>

// ContextSNN round 11: 3-slot LDS ring (72 KiB) so TWO blocks co-reside per CU
// (144 KiB LDS, 16 waves/CU via __launch_bounds__(512,4)). r10 post-mortem:
// per-K-step gap (~1050 cy) == LDS traffic (88 KB at ~85 B/cy), and with
// 1 block/CU nothing overlaps it. Dual-block co-scheduling (m114 mechanism)
// covers each block's ds_read/barrier phase with the other block's MFMAs.
// Ring keeps >=1-body issue-to-wait distance so vmcnt waits stay ~free.
// Numerics identical (exact i32 plane fold). T=50,B=256,IN=1536,H=4096,OUT=64.

#define T_STEPS 50
#define BATCH   256
#define N_H     4096
#define DEN     8355711   // 127*65536 + 127*256 + 127

typedef unsigned short u16;
typedef __attribute__((ext_vector_type(4))) int i32x4;
typedef __attribute__((ext_vector_type(4))) float f32x4;

#define GLL16(gp, lp) __builtin_amdgcn_global_load_lds( \
    (const __attribute__((address_space(1))) void*)(gp), \
    (__attribute__((address_space(3))) void*)(lp), 16, 0, 0)

// ---------------------------------------------------------------------------
// prep
// ---------------------------------------------------------------------------
__global__ __launch_bounds__(256) void zero_ws(float4* __restrict__ p) {
    p[(size_t)blockIdx.x * 256 + threadIdx.x] = make_float4(0.f, 0.f, 0.f, 0.f);
}

__device__ inline void digits3(float w, float inv_s, int& h, int& m, int& l) {
    int V = (int)rintf(w * inv_s);
    V = min(max(V, -DEN), DEN);
    l = ((V + 128) & 255) - 128;
    const int V2 = (V - l) >> 8;
    m = ((V2 + 128) & 255) - 128;
    h = (V2 - m) >> 8;
}

__global__ __launch_bounds__(256)
void split3_i8(const float4* __restrict__ W, char* __restrict__ P,
               size_t plane_elems, float inv_s)
{
    const size_t i = (size_t)blockIdx.x * 256 + threadIdx.x;
    const float4 w = W[i];
    int h0,m0,l0,h1,m1,l1,h2,m2,l2,h3,m3,l3;
    digits3(w.x, inv_s, h0, m0, l0);
    digits3(w.y, inv_s, h1, m1, l1);
    digits3(w.z, inv_s, h2, m2, l2);
    digits3(w.w, inv_s, h3, m3, l3);
    const uint32_t ph = (uint32_t)(uint8_t)h0 | ((uint32_t)(uint8_t)h1 << 8) |
                        ((uint32_t)(uint8_t)h2 << 16) | ((uint32_t)(uint8_t)h3 << 24);
    const uint32_t pm = (uint32_t)(uint8_t)m0 | ((uint32_t)(uint8_t)m1 << 8) |
                        ((uint32_t)(uint8_t)m2 << 16) | ((uint32_t)(uint8_t)m3 << 24);
    const uint32_t pl = (uint32_t)(uint8_t)l0 | ((uint32_t)(uint8_t)l1 << 8) |
                        ((uint32_t)(uint8_t)l2 << 16) | ((uint32_t)(uint8_t)l3 << 24);
    *(uint32_t*)&P[4 * i]                   = ph;
    *(uint32_t*)&P[plane_elems + 4 * i]     = pm;
    *(uint32_t*)&P[2 * plane_elems + 4 * i] = pl;
}

__global__ __launch_bounds__(256)
void xcvt_i8(const float4* __restrict__ in, uint32_t* __restrict__ out) {
    const size_t i = (size_t)blockIdx.x * 256 + threadIdx.x;
    const float4 v = in[i];
    out[i] = (uint32_t)(v.x > 0.5f) | ((uint32_t)(v.y > 0.5f) << 8) |
             ((uint32_t)(v.z > 0.5f) << 16) | ((uint32_t)(v.w > 0.5f) << 24);
}

// ---------------------------------------------------------------------------
// 3-slot ring-pipelined batched 3-plane i8 GEMM.
// A[6400][K] x Wp[3][4096][K]^T -> cur[6400][4096].
// BM=256, BN=128, BK=64. 512 threads = 8 waves as 4M x 2N; per-wave 64x64.
// LDS: 3 slots x (A 16K + B 8K) = 72 KiB dynamic -> 2 blocks/CU.
// Body t: vmcnt(0) retires slot t+1 (issued one full body ago, wait ~free),
// barrier, stage slot t+2, ds_read frags t+1, MFMA tile t. Slot period 3 x
// register-set period 2 -> unroll 6. Grid 800 = 25 rows x 32 cols (XCD swz).
// ---------------------------------------------------------------------------
template<int K>
__global__ __launch_bounds__(512, 4)
void gemm_planes_ring(const char* __restrict__ A, const char* __restrict__ Wp,
                      float* __restrict__ cur, float s_base)
{
    const int ITERS = 3 * K / 64;     // 192 (K=4096) / 72 (K=1536), both %6==0
    const int SLOT  = 24576;          // 16384 (A) + 8192 (B)
    extern __shared__ char Lds[];     // 3 * SLOT = 73728 B

    const int tid  = threadIdx.x;
    const int wave = tid >> 6, lane = tid & 63;
    const int wr = wave >> 1, wc = wave & 1;

    const int bid   = blockIdx.x;
    const int cbase = (((bid & 7) << 2) + ((bid >> 3) & 3)) * 128;
    const int abase = (bid >> 5) * 256;

    i32x4 acc[4][4];
    f32x4 facc[4][4];
#pragma unroll
    for (int i = 0; i < 4; ++i)
#pragma unroll
        for (int j = 0; j < 4; ++j) { acc[i][j] = (i32x4)(0); facc[i][j] = (f32x4)(0.f); }

    // staging map (verified r10): 3 x GLL16 per thread per tile.
    const int soff = tid * 16;               // 0..8191
    const int rs   = soff >> 6;              // row 0..127
    const int cs   = (soff >> 4) & 3;        // 16B chunk in row
    const int kbs  = ((cs ^ ((rs >> 1) & 3)) << 4);   // XOR bank swizzle
    const size_t aoff0 = (size_t)(abase + rs) * K + kbs;
    const size_t aoff1 = aoff0 + (size_t)128 * K;
    const size_t boff  = (size_t)(cbase + rs) * K + kbs;
    const int dstA0 = wave * 1024;
    const int dstA1 = 8192 + wave * 1024;
    const int dstB  = 16384 + wave * 1024;

    // read-side fragment offsets (verified r9/r10)
    const int rlo = lane & 15, rhi = lane >> 4;
    const int qr  = (rlo >> 1) & 3;
    const int rdA = (wr * 64 + rlo) * 64 + ((rhi ^ qr) << 4);
    const int rdB = 16384 + (wc * 64 + rlo) * 64 + ((rhi ^ qr) << 4);

    auto stage = [&](int u, int slot_off) {
        const int pn = (u * 64) / K;
        const int kn = u * 64 - pn * K;
        char* slot = Lds + slot_off;
        const char* ak = A + kn;
        const char* bk = Wp + (size_t)pn * ((size_t)N_H * K) + kn;
        GLL16(ak + aoff0, slot + dstA0);
        GLL16(ak + aoff1, slot + dstA1);
        GLL16(bk + boff,  slot + dstB);
    };

    // prologue: stage tiles 0,1 into slots 0,1; retire tile 0; read frags 0
    stage(0, 0); stage(1, SLOT);
    asm volatile("s_waitcnt vmcnt(3)" ::: "memory");
    __builtin_amdgcn_s_barrier();
    asm volatile("" ::: "memory");

    i32x4 avA[4], bvA[4], avB[4], bvB[4];
#pragma unroll
    for (int i = 0; i < 4; ++i) avA[i] = *(const i32x4*)(Lds + rdA + i * 1024);
#pragma unroll
    for (int j = 0; j < 4; ++j) bvA[j] = *(const i32x4*)(Lds + rdB + j * 1024);

    // body tt: retire slot(tt+1) loads, barrier, stage slot(tt+2),
    // ds_read frags(tt+1) -> next set, MFMA tile tt from current set.
#define RING_BODY(tt, NXT_OFF, STG_OFF, avC, bvC, avN, bvN)                   \
    {                                                                         \
        asm volatile("s_waitcnt vmcnt(0)" ::: "memory");                      \
        __builtin_amdgcn_s_barrier();                                         \
        asm volatile("" ::: "memory");                                        \
        if ((tt) + 2 < ITERS) stage((tt) + 2, STG_OFF);                       \
        if ((tt) + 1 < ITERS) {                                               \
            const char* nb_ = Lds + (NXT_OFF);                                \
            _Pragma("unroll")                                                 \
            for (int i = 0; i < 4; ++i)                                       \
                avN[i] = *(const i32x4*)(nb_ + rdA + i * 1024);               \
            _Pragma("unroll")                                                 \
            for (int j = 0; j < 4; ++j)                                       \
                bvN[j] = *(const i32x4*)(nb_ + rdB + j * 1024);               \
        }                                                                     \
        __builtin_amdgcn_s_setprio(1);                                        \
        _Pragma("unroll")                                                     \
        for (int i = 0; i < 4; ++i)                                           \
            _Pragma("unroll")                                                 \
            for (int j = 0; j < 4; ++j)                                       \
                acc[i][j] = __builtin_amdgcn_mfma_i32_16x16x64_i8(            \
                    avC[i], bvC[j], acc[i][j], 0, 0, 0);                      \
        __builtin_amdgcn_s_setprio(0);                                        \
        if (((((tt) + 1) * 64) % K) == 0) {                                   \
            const int p_ = ((tt) * 64) / K;                                   \
            const float sc_ = s_base * (float)(65536 >> (8 * p_));            \
            _Pragma("unroll")                                                 \
            for (int i = 0; i < 4; ++i)                                       \
                _Pragma("unroll")                                             \
                for (int j = 0; j < 4; ++j) {                                 \
                    _Pragma("unroll")                                         \
                    for (int r = 0; r < 4; ++r)                               \
                        facc[i][j][r] += sc_ * (float)acc[i][j][r];           \
                    acc[i][j] = (i32x4)(0);                                   \
                }                                                             \
        }                                                                     \
    }

    // slots: tile u lives in slot (u % 3)*SLOT; sets alternate A/B.
    for (int t = 0; t < ITERS; t += 6) {
        RING_BODY(t + 0, SLOT,     2 * SLOT, avA, bvA, avB, bvB);
        RING_BODY(t + 1, 2 * SLOT, 0,        avB, bvB, avA, bvA);
        RING_BODY(t + 2, 0,        SLOT,     avA, bvA, avB, bvB);
        RING_BODY(t + 3, SLOT,     2 * SLOT, avB, bvB, avA, bvA);
        RING_BODY(t + 4, 2 * SLOT, 0,        avA, bvA, avB, bvB);
        RING_BODY(t + 5, 0,        SLOT,     avB, bvB, avA, bvA);
    }
#undef RING_BODY

    const int orow = abase + wr * 64 + rhi * 4;
    const int ocol = cbase + wc * 64 + rlo;
#pragma unroll
    for (int i = 0; i < 4; ++i)
#pragma unroll
        for (int j = 0; j < 4; ++j)
#pragma unroll
            for (int r = 0; r < 4; ++r)
                cur[(size_t)(orow + i * 16 + r) * N_H + ocol + j * 16] = facc[i][j][r];
}

// ---------------------------------------------------------------------------
// FALLBACK: r9 double-buffered plane GEMM (used if dynamic-LDS attr fails)
// ---------------------------------------------------------------------------
template<int K>
__global__ __launch_bounds__(256, 2)
void gemm_planes(const char* __restrict__ A, const char* __restrict__ Wp,
                 float* __restrict__ cur, float s_base)
{
    const int ITERS = 3 * K / 64;
    __shared__ char As[2 * 8192];
    __shared__ char Bs[2 * 8192];

    const int tid  = threadIdx.x;
    const int wave = tid >> 6, lane = tid & 63;
    const int wm = wave >> 1, wn = wave & 1;

    const int bid   = blockIdx.x;
    const int cbase = (((bid & 7) << 2) + ((bid >> 3) & 3)) * 128;
    const int abase = (bid >> 5) * 128;

    i32x4 acc[4][4];
    f32x4 facc[4][4];
#pragma unroll
    for (int i = 0; i < 4; ++i)
#pragma unroll
        for (int j = 0; j < 4; ++j) { acc[i][j] = (i32x4)(0); facc[i][j] = (f32x4)(0.f); }

    const int soff0 = wave * 2048 + lane * 16;
    const int soff1 = soff0 + 1024;
    const int r0 = soff0 >> 6, r1 = soff1 >> 6;
    const int kb0 = ((((soff0 >> 4) & 3) ^ ((r0 >> 1) & 3)) << 4);
    const int kb1 = ((((soff1 >> 4) & 3) ^ ((r1 >> 1) & 3)) << 4);

    const size_t aoff0 = (size_t)(abase + r0) * K + kb0;
    const size_t aoff1 = (size_t)(abase + r1) * K + kb1;
    const size_t boff0 = (size_t)(cbase + r0) * K + kb0;
    const size_t boff1 = (size_t)(cbase + r1) * K + kb1;

    const int sbase = wave * 2048;

    const int rlo = lane & 15, rhi = lane >> 4;
    const int qr = (rlo >> 1) & 3;
    const int rdA = (wm * 64 + rlo) * 64 + ((rhi ^ qr) << 4);
    const int rdB = (wn * 64 + rlo) * 64 + ((rhi ^ qr) << 4);

    {
        GLL16(A + aoff0, As + sbase);
        GLL16(A + aoff1, As + sbase + 1024);
        GLL16(Wp + boff0, Bs + sbase);
        GLL16(Wp + boff1, Bs + sbase + 1024);
    }
    __syncthreads();

    for (int it = 0; it < ITERS; ++it) {
        const int buf = (it & 1) * 8192;
        if (it + 1 < ITERS) {
            const int fn = (it + 1) * 64;
            const int pn = fn / K;
            const int kn = fn - pn * K;
            const int nbuf = 8192 - buf;
            const char* ak = A + kn;
            const char* bk = Wp + (size_t)pn * ((size_t)N_H * K) + kn;
            GLL16(ak + aoff0, As + nbuf + sbase);
            GLL16(ak + aoff1, As + nbuf + sbase + 1024);
            GLL16(bk + boff0, Bs + nbuf + sbase);
            GLL16(bk + boff1, Bs + nbuf + sbase + 1024);
        }

        const char* pAf = As + buf + rdA;
        const char* pBf = Bs + buf + rdB;
        i32x4 av[4], bv[4];
#pragma unroll
        for (int i = 0; i < 4; ++i) av[i] = *(const i32x4*)(pAf + i * 1024);
#pragma unroll
        for (int j = 0; j < 4; ++j) bv[j] = *(const i32x4*)(pBf + j * 1024);
#pragma unroll
        for (int i = 0; i < 4; ++i)
#pragma unroll
            for (int j = 0; j < 4; ++j)
                acc[i][j] = __builtin_amdgcn_mfma_i32_16x16x64_i8(
                    av[i], bv[j], acc[i][j], 0, 0, 0);

        if ((((it + 1) * 64) % K) == 0) {
            const int p = (it * 64) / K;
            const float sc = s_base * (float)(65536 >> (8 * p));
#pragma unroll
            for (int i = 0; i < 4; ++i)
#pragma unroll
                for (int j = 0; j < 4; ++j) {
#pragma unroll
                    for (int r = 0; r < 4; ++r)
                        facc[i][j][r] += sc * (float)acc[i][j][r];
                    acc[i][j] = (i32x4)(0);
                }
        }
        __syncthreads();
    }

    const int orow = abase + wm * 64 + rhi * 4;
    const int ocol = cbase + wn * 64 + rlo;
#pragma unroll
    for (int i = 0; i < 4; ++i)
#pragma unroll
        for (int j = 0; j < 4; ++j)
#pragma unroll
            for (int r = 0; r < 4; ++r)
                cur[(size_t)(orow + i * 16 + r) * N_H + ocol + j * 16] = facc[i][j][r];
}

// ---------------------------------------------------------------------------
// layer-3 i8 GEMM, double-buffered (unchanged, small)
// ---------------------------------------------------------------------------
__global__ __launch_bounds__(256, 2)
void gemm3_i8(const char* __restrict__ A, const char* __restrict__ W3p,
              float* __restrict__ part3, float s_base)
{
    __shared__ char As[2 * 8192];
    __shared__ char Bs[2 * 4096];

    const int tid  = threadIdx.x;
    const int wave = tid >> 6, lane = tid & 63;
    const int wm = wave >> 1, wn = wave & 1;

    const int rowbase = blockIdx.x * 128;
    const int z = blockIdx.y;
    const int p = z >> 1;
    const int kstart = (z & 1) * 2048;

    i32x4 acc[4][2];
#pragma unroll
    for (int i = 0; i < 4; ++i)
#pragma unroll
        for (int j = 0; j < 2; ++j) acc[i][j] = (i32x4)(0);

    const int soff0 = wave * 2048 + lane * 16;
    const int soff1 = soff0 + 1024;
    const int r0 = soff0 >> 6, r1 = soff1 >> 6;
    const int kb0 = ((((soff0 >> 4) & 3) ^ ((r0 >> 1) & 3)) << 4);
    const int kb1 = ((((soff1 >> 4) & 3) ^ ((r1 >> 1) & 3)) << 4);
    const int soffB = tid * 16;
    const int rB = soffB >> 6;
    const int kbB = ((((soffB >> 4) & 3) ^ ((rB >> 1) & 3)) << 4);

    const size_t aoff0 = (size_t)(rowbase + r0) * 4096 + kb0;
    const size_t aoff1 = (size_t)(rowbase + r1) * 4096 + kb1;
    const size_t boff  = (size_t)rB * 4096 + kbB;

    const char* Bp = W3p + (size_t)p * 64 * 4096;
    const int sbase = wave * 2048;
    const int sbaseB = wave * 1024;

    const int rlo = lane & 15, rhi = lane >> 4;
    const int qr = (rlo >> 1) & 3;
    const int rdA = (wm * 64 + rlo) * 64 + ((rhi ^ qr) << 4);
    const int rdB = (wn * 32 + rlo) * 64 + ((rhi ^ qr) << 4);

    {
        GLL16(A + kstart + aoff0, As + sbase);
        GLL16(A + kstart + aoff1, As + sbase + 1024);
        GLL16(Bp + kstart + boff, Bs + sbaseB);
    }
    __syncthreads();

    for (int it = 0; it < 32; ++it) {
        const int bufA = (it & 1) * 8192;
        const int bufB = (it & 1) * 4096;
        if (it + 1 < 32) {
            const int kn = kstart + (it + 1) * 64;
            GLL16(A + kn + aoff0, As + (8192 - bufA) + sbase);
            GLL16(A + kn + aoff1, As + (8192 - bufA) + sbase + 1024);
            GLL16(Bp + kn + boff, Bs + (4096 - bufB) + sbaseB);
        }

        const char* pAf = As + bufA + rdA;
        const char* pBf = Bs + bufB + rdB;
        i32x4 av[4], bv[2];
#pragma unroll
        for (int i = 0; i < 4; ++i) av[i] = *(const i32x4*)(pAf + i * 1024);
#pragma unroll
        for (int j = 0; j < 2; ++j) bv[j] = *(const i32x4*)(pBf + j * 1024);
#pragma unroll
        for (int i = 0; i < 4; ++i)
#pragma unroll
            for (int j = 0; j < 2; ++j)
                acc[i][j] = __builtin_amdgcn_mfma_i32_16x16x64_i8(
                    av[i], bv[j], acc[i][j], 0, 0, 0);
        __syncthreads();
    }

    const float sc = s_base * (float)(65536 >> (8 * p));
    float* pout = part3 + (size_t)z * (12800 * 64);
    const int orow = rowbase + wm * 64 + rhi * 4;
    const int ocol = wn * 32 + rlo;
#pragma unroll
    for (int i = 0; i < 4; ++i)
#pragma unroll
        for (int j = 0; j < 2; ++j)
#pragma unroll
            for (int r = 0; r < 4; ++r)
                pout[(size_t)(orow + i * 16 + r) * 64 + ocol + j * 16] =
                    (float)acc[i][j][r] * sc;
}

// ---------------------------------------------------------------------------
// elementwise LIF time-scan over 25 steps (one chunk)
// ---------------------------------------------------------------------------
__global__ __launch_bounds__(256)
void lif_scan(const float* __restrict__ cur, const float* __restrict__ bias,
              float* __restrict__ mem, char* __restrict__ sout)
{
    const int i4  = blockIdx.x * 256 + threadIdx.x;   // 0..262143
    const int col = (i4 << 2) & (N_H - 1);
    const int b   = i4 >> 10;
    const float4 bv = *(const float4*)&bias[col];
    const size_t mbase = (size_t)b * N_H + col;
    float4 m = *(const float4*)&mem[mbase];

    for (int t = 0; t < 25; ++t) {
        const size_t off = ((size_t)t * BATCH + b) * N_H + col;
        const float4 cv = *(const float4*)&cur[off];
        float4 mn;
        { const float c = cv.x + bv.x;
          mn.x = 0.9f * m.x + c - ((m.x > 1.0f) ? 1.0f : 0.0f); }
        { const float c = cv.y + bv.y;
          mn.y = 0.9f * m.y + c - ((m.y > 1.0f) ? 1.0f : 0.0f); }
        { const float c = cv.z + bv.z;
          mn.z = 0.9f * m.z + c - ((m.z > 1.0f) ? 1.0f : 0.0f); }
        { const float c = cv.w + bv.w;
          mn.w = 0.9f * m.w + c - ((m.w > 1.0f) ? 1.0f : 0.0f); }
        const uint32_t sp = (uint32_t)(mn.x > 1.0f) | ((uint32_t)(mn.y > 1.0f) << 8) |
                            ((uint32_t)(mn.z > 1.0f) << 16) | ((uint32_t)(mn.w > 1.0f) << 24);
        *(uint32_t*)&sout[off] = sp;
        m = mn;
    }
    *(float4*)&mem[mbase] = m;
}

template<int NG>
__global__ __launch_bounds__(256)
void lif3_scan(const float* __restrict__ part, const float* __restrict__ b3,
               float* __restrict__ out)
{
    const int g = blockIdx.x * 256 + threadIdx.x;
    const int j = g & 63;
    const int b = g >> 6;
    const float bj = b3[j];
    float m = 0.f, accum = 0.f;
    for (int t = 0; t < T_STEPS; ++t) {
        const size_t row = (size_t)t * 256 + b;
        float cur = bj;
#pragma unroll
        for (int q = 0; q < NG; ++q)
            cur += part[(size_t)q * (12800 * 64) + row * 64 + j];
        const float reset = (m > 1.0f) ? 1.0f : 0.0f;
        m = 0.9f * m + cur - reset;
        accum += (m > 1.0f) ? 1.0f : 0.0f;
    }
    out[g] = accum;
}

// ---------------------------------------------------------------------------
// fp32 fallback path (round 1) — used only if ws_size too small
// ---------------------------------------------------------------------------
template<int K, bool PACK_BITS>
__global__ __launch_bounds__(512)
void gemm_lif(const float* __restrict__ A, const float* __restrict__ W,
              const float* __restrict__ bias, float* __restrict__ mem,
              float* __restrict__ s_f32, uint32_t* __restrict__ s_bits)
{
    __shared__ float Asf[32][68];
    __shared__ float Wsf[32][68];
    __shared__ uint8_t us[64][64];

    const int tid = threadIdx.x;
    const int abase = blockIdx.y * 64;
    const int cbase = blockIdx.x * 64;
    const int tx = tid & 15;
    const int ty = tid >> 4;

    float acc[2][4];
#pragma unroll
    for (int i = 0; i < 2; ++i)
#pragma unroll
        for (int j = 0; j < 4; ++j) acc[i][j] = 0.f;

    const int lrow = tid >> 3;
    const int lg = tid & 7;

    for (int k0 = 0; k0 < K; k0 += 32) {
        const float4 av = *(const float4*)&A[(size_t)(abase + lrow) * K + k0 + lg * 4];
        const float4 wv = *(const float4*)&W[(size_t)(cbase + lrow) * K + k0 + lg * 4];
        __syncthreads();
        Asf[lg * 4 + 0][lrow] = av.x; Asf[lg * 4 + 1][lrow] = av.y;
        Asf[lg * 4 + 2][lrow] = av.z; Asf[lg * 4 + 3][lrow] = av.w;
        Wsf[lg * 4 + 0][lrow] = wv.x; Wsf[lg * 4 + 1][lrow] = wv.y;
        Wsf[lg * 4 + 2][lrow] = wv.z; Wsf[lg * 4 + 3][lrow] = wv.w;
        __syncthreads();
#pragma unroll
        for (int kk = 0; kk < 32; ++kk) {
            const float2 a2 = *(const float2*)&Asf[kk][ty * 2];
            const float4 b4 = *(const float4*)&Wsf[kk][tx * 4];
            acc[0][0] += a2.x * b4.x; acc[0][1] += a2.x * b4.y;
            acc[0][2] += a2.x * b4.z; acc[0][3] += a2.x * b4.w;
            acc[1][0] += a2.y * b4.x; acc[1][1] += a2.y * b4.y;
            acc[1][2] += a2.y * b4.z; acc[1][3] += a2.y * b4.w;
        }
    }

    const int r0 = abase + ty * 2;
    const int c0loc = tx * 4;
    const int c0 = cbase + c0loc;
    const float4 bv = *(const float4*)&bias[c0];

#pragma unroll
    for (int i = 0; i < 2; ++i) {
        const size_t off = (size_t)(r0 + i) * N_H + c0;
        const float4 mp = *(const float4*)&mem[off];
        float4 mn, sp;
        { float cur = acc[i][0] + bv.x;
          mn.x = 0.9f * mp.x + cur - ((mp.x > 1.0f) ? 1.0f : 0.0f);
          sp.x = (mn.x > 1.0f) ? 1.0f : 0.0f; }
        { float cur = acc[i][1] + bv.y;
          mn.y = 0.9f * mp.y + cur - ((mp.y > 1.0f) ? 1.0f : 0.0f);
          sp.y = (mn.y > 1.0f) ? 1.0f : 0.0f; }
        { float cur = acc[i][2] + bv.z;
          mn.z = 0.9f * mp.z + cur - ((mp.z > 1.0f) ? 1.0f : 0.0f);
          sp.z = (mn.z > 1.0f) ? 1.0f : 0.0f; }
        { float cur = acc[i][3] + bv.w;
          mn.w = 0.9f * mp.w + cur - ((mp.w > 1.0f) ? 1.0f : 0.0f);
          sp.w = (mn.w > 1.0f) ? 1.0f : 0.0f; }
        *(float4*)&mem[off] = mn;
        if constexpr (!PACK_BITS) {
            *(float4*)&s_f32[off] = sp;
        } else {
            us[ty * 2 + i][c0loc + 0] = (uint8_t)sp.x;
            us[ty * 2 + i][c0loc + 1] = (uint8_t)sp.y;
            us[ty * 2 + i][c0loc + 2] = (uint8_t)sp.z;
            us[ty * 2 + i][c0loc + 3] = (uint8_t)sp.w;
        }
    }

    if constexpr (PACK_BITS) {
        __syncthreads();
        if (tid < 128) {
            const int r = tid >> 1;
            const int w = tid & 1;
            uint32_t bits = 0;
#pragma unroll
            for (int b = 0; b < 32; ++b)
                bits |= ((uint32_t)us[r][w * 32 + b]) << b;
            s_bits[(size_t)(abase + r) * 128 + (cbase >> 5) + w] = bits;
        }
    }
}

__global__ __launch_bounds__(256)
void gemm3_bits(const uint32_t* __restrict__ s_bits, const float* __restrict__ W3,
                float* __restrict__ part)
{
    __shared__ float Asf[32][68];
    __shared__ float Wsf[32][68];

    const int tid = threadIdx.x;
    const int rowbase = blockIdx.x * 64;
    const int ks = blockIdx.y;
    const int tx = tid & 15;
    const int ty = tid >> 4;

    float acc[4][4];
#pragma unroll
    for (int i = 0; i < 4; ++i)
#pragma unroll
        for (int j = 0; j < 4; ++j) acc[i][j] = 0.f;

    const int r  = tid & 63;
    const int q  = tid >> 6;
    const int wr = tid >> 3;
    const int wg = tid & 7;

    for (int c = 0; c < 32; ++c) {
        const int k0 = ks * 1024 + c * 32;
        const uint32_t word = s_bits[(size_t)(rowbase + r) * 128 + (k0 >> 5)];
        const float4 wv0 = *(const float4*)&W3[(size_t)wr * 4096 + k0 + wg * 4];
        const float4 wv1 = *(const float4*)&W3[(size_t)(wr + 32) * 4096 + k0 + wg * 4];
        __syncthreads();
#pragma unroll
        for (int u = 0; u < 8; ++u)
            Asf[q * 8 + u][r] = (float)((word >> (q * 8 + u)) & 1u);
        Wsf[wg * 4 + 0][wr] = wv0.x;
        Wsf[wg * 4 + 1][wr] = wv0.y;
        Wsf[wg * 4 + 2][wr] = wv0.z;
        Wsf[wg * 4 + 3][wr] = wv0.w;
        Wsf[wg * 4 + 0][wr + 32] = wv1.x;
        Wsf[wg * 4 + 1][wr + 32] = wv1.y;
        Wsf[wg * 4 + 2][wr + 32] = wv1.z;
        Wsf[wg * 4 + 3][wr + 32] = wv1.w;
        __syncthreads();
#pragma unroll
        for (int kk = 0; kk < 32; ++kk) {
            const float4 a4 = *(const float4*)&Asf[kk][ty * 4];
            const float4 b4 = *(const float4*)&Wsf[kk][tx * 4];
            acc[0][0] += a4.x * b4.x; acc[0][1] += a4.x * b4.y;
            acc[0][2] += a4.x * b4.z; acc[0][3] += a4.x * b4.w;
            acc[1][0] += a4.y * b4.x; acc[1][1] += a4.y * b4.y;
            acc[1][2] += a4.y * b4.z; acc[1][3] += a4.y * b4.w;
            acc[2][0] += a4.z * b4.x; acc[2][1] += a4.z * b4.y;
            acc[2][2] += a4.z * b4.z; acc[2][3] += a4.z * b4.w;
            acc[3][0] += a4.w * b4.x; acc[3][1] += a4.w * b4.y;
            acc[3][2] += a4.w * b4.z; acc[3][3] += a4.w * b4.w;
        }
    }
#pragma unroll
    for (int i = 0; i < 4; ++i) {
        float4 v = make_float4(acc[i][0], acc[i][1], acc[i][2], acc[i][3]);
        *(float4*)&part[((size_t)ks * 12800 + rowbase + ty * 4 + i) * 64 + tx * 4] = v;
    }
}

// ---------------------------------------------------------------------------
extern "C" void kernel_launch(void* const* d_in, const int* in_sizes, int n_in,
                              void* d_out, int out_size, void* d_ws, size_t ws_size,
                              hipStream_t stream)
{
    const float* x  = (const float*)d_in[0];
    const float* W1 = (const float*)d_in[1];
    const float* b1 = (const float*)d_in[2];
    const float* W2 = (const float*)d_in[3];
    const float* b2 = (const float*)d_in[4];
    const float* W3 = (const float*)d_in[5];
    const float* b3 = (const float*)d_in[6];

    char* ws = (char*)d_ws;

    // layout (bytes):
    const size_t oW1p = 0;              //  18,874,368  W1 planes i8
    const size_t oW2p = 18874368;       //  50,331,648  W2 planes i8
    const size_t oW3p = 69206016;       //     786,432  W3 planes i8
    const size_t oXi8 = 69992448;       //  19,660,800  input spikes i8
    const size_t oS1  = 89653248;       //  26,214,400  s1 (one 25-step chunk)
    const size_t oS2  = 115867648;      //  52,428,800  s2 (all 50 steps)
    const size_t oM1  = 168296448;      //   4,194,304  m1 carry
    const size_t oM2  = 172490752;      //   4,194,304  m2 carry (contig w/ m1)
    const size_t oCur = 176685056;      // 104,857,600  cur1/cur2 shared; part3 alias
    const size_t NEED = 281542656;

    const double bnd1 = 1.0 / sqrt(1536.0);
    const double bnd2 = 1.0 / 64.0;
    const double bnd3 = 1.0 / 64.0;
    const float inv1 = (float)((double)DEN / bnd1), sb1 = (float)(bnd1 / (double)DEN);
    const float inv2 = (float)((double)DEN / bnd2), sb2 = (float)(bnd2 / (double)DEN);
    const float inv3 = (float)((double)DEN / bnd3), sb3 = (float)(bnd3 / (double)DEN);

    // one-time: allow 72 KiB dynamic LDS for the ring kernels (host-side
    // config call, graph-capture safe). Fallback to proven r9 kernel if fails.
    static const bool ring_ok = []() {
        hipError_t e1 = hipFuncSetAttribute(
            reinterpret_cast<const void*>(&gemm_planes_ring<1536>),
            hipFuncAttributeMaxDynamicSharedMemorySize, 73728);
        hipError_t e2 = hipFuncSetAttribute(
            reinterpret_cast<const void*>(&gemm_planes_ring<4096>),
            hipFuncAttributeMaxDynamicSharedMemorySize, 73728);
        return e1 == hipSuccess && e2 == hipSuccess;
    }();

    if (ws_size >= NEED) {
        char*  W1p  = ws + oW1p;
        char*  W2p  = ws + oW2p;
        char*  W3p  = ws + oW3p;
        char*  xi8  = ws + oXi8;
        char*  s1   = ws + oS1;
        char*  s2   = ws + oS2;
        float* m1   = (float*)(ws + oM1);
        float* m2   = (float*)(ws + oM2);
        float* cur  = (float*)(ws + oCur);
        float* part3 = cur;   // reuse after lif2_scan of chunk 1

        split3_i8<<<6144, 256, 0, stream>>>((const float4*)W1, W1p,
                                            (size_t)4096 * 1536, inv1);
        split3_i8<<<16384, 256, 0, stream>>>((const float4*)W2, W2p,
                                             (size_t)4096 * 4096, inv2);
        split3_i8<<<256, 256, 0, stream>>>((const float4*)W3, W3p,
                                           (size_t)64 * 4096, inv3);
        xcvt_i8<<<19200, 256, 0, stream>>>((const float4*)x, (uint32_t*)xi8);
        zero_ws<<<2048, 256, 0, stream>>>((float4*)m1);   // m1 + m2 contiguous

        const size_t chunk_rows = (size_t)25 * BATCH;     // 6400
        for (int chunk = 0; chunk < 2; ++chunk) {
            if (ring_ok) {
                gemm_planes_ring<1536><<<800, 512, 73728, stream>>>(
                    xi8 + chunk * chunk_rows * 1536, W1p, cur, sb1);
            } else {
                gemm_planes<1536><<<1600, 256, 0, stream>>>(
                    xi8 + chunk * chunk_rows * 1536, W1p, cur, sb1);
            }
            lif_scan<<<1024, 256, 0, stream>>>(cur, b1, m1, s1);
            if (ring_ok) {
                gemm_planes_ring<4096><<<800, 512, 73728, stream>>>(
                    s1, W2p, cur, sb2);
            } else {
                gemm_planes<4096><<<1600, 256, 0, stream>>>(s1, W2p, cur, sb2);
            }
            lif_scan<<<1024, 256, 0, stream>>>(cur, b2, m2,
                                               s2 + chunk * chunk_rows * N_H);
        }
        gemm3_i8<<<dim3(100, 6), 256, 0, stream>>>(s2, W3p, part3, sb3);
        lif3_scan<6><<<64, 256, 0, stream>>>(part3, b3, (float*)d_out);
    } else {
        float*    m1     = (float*)(ws);
        float*    m2     = (float*)(ws + (size_t)4 * 1024 * 1024);
        float*    s1f    = (float*)(ws + (size_t)8 * 1024 * 1024);
        uint32_t* s2bits = (uint32_t*)(ws + (size_t)12 * 1024 * 1024);
        float*    part   = (float*)(ws + (size_t)20 * 1024 * 1024);

        zero_ws<<<2048, 256, 0, stream>>>((float4*)m1);
        for (int t = 0; t < T_STEPS; ++t) {
            gemm_lif<1536, false><<<dim3(64, 4), 512, 0, stream>>>(
                x + (size_t)t * BATCH * 1536, W1, b1, m1, s1f, nullptr);
            gemm_lif<4096, true><<<dim3(64, 4), 512, 0, stream>>>(
                s1f, W2, b2, m2, nullptr, s2bits + (size_t)t * BATCH * 128);
        }
        gemm3_bits<<<dim3(200, 4), 256, 0, stream>>>(s2bits, W3, part);
        lif3_scan<4><<<64, 256, 0, stream>>>(part, b3, (float*)d_out);
    }
}

// Round 4
// 2948.283 us; speedup vs baseline: 2.2067x; 2.2067x over previous
//
#include <hip/hip_runtime.h>
#include <stdint.h>
#include <stddef.h>
#include <math.h>

// ContextSNN round 12: B-direct plane GEMM. r11 post-mortem: (512,4) forced a
// 128-reg cap -> total spill (VGPR=64, 8.9GB scratch). Registers forbid 2
// blocks/CU at this footprint, so instead shrink the LDS bound itself:
// B fragments load DIRECT global->reg (the source pre-swizzle and read
// swizzle cancel: lane(rlo,rhi) frag j = W[cbase+wc*64+j*16+rlo][kn+rhi*16]),
// A stays via global_load_lds in a 4-slot static-LDS ring (64 KiB),
// stage-ahead-3, per-body wait vmcnt(2) (never 0 mid-loop). LDS/step drops
// 88KB->48KB; B traffic moves to L2 (XCD-swizzle keeps it local).
// Numerics identical (exact i32 plane fold). T=50,B=256,IN=1536,H=4096,OUT=64.

#define T_STEPS 50
#define BATCH   256
#define N_H     4096
#define DEN     8355711   // 127*65536 + 127*256 + 127

typedef unsigned short u16;
typedef __attribute__((ext_vector_type(4))) int i32x4;
typedef __attribute__((ext_vector_type(4))) float f32x4;

#define GLL16(gp, lp) __builtin_amdgcn_global_load_lds( \
    (const __attribute__((address_space(1))) void*)(gp), \
    (__attribute__((address_space(3))) void*)(lp), 16, 0, 0)

// ---------------------------------------------------------------------------
// prep
// ---------------------------------------------------------------------------
__global__ __launch_bounds__(256) void zero_ws(float4* __restrict__ p) {
    p[(size_t)blockIdx.x * 256 + threadIdx.x] = make_float4(0.f, 0.f, 0.f, 0.f);
}

__device__ inline void digits3(float w, float inv_s, int& h, int& m, int& l) {
    int V = (int)rintf(w * inv_s);
    V = min(max(V, -DEN), DEN);
    l = ((V + 128) & 255) - 128;
    const int V2 = (V - l) >> 8;
    m = ((V2 + 128) & 255) - 128;
    h = (V2 - m) >> 8;
}

__global__ __launch_bounds__(256)
void split3_i8(const float4* __restrict__ W, char* __restrict__ P,
               size_t plane_elems, float inv_s)
{
    const size_t i = (size_t)blockIdx.x * 256 + threadIdx.x;
    const float4 w = W[i];
    int h0,m0,l0,h1,m1,l1,h2,m2,l2,h3,m3,l3;
    digits3(w.x, inv_s, h0, m0, l0);
    digits3(w.y, inv_s, h1, m1, l1);
    digits3(w.z, inv_s, h2, m2, l2);
    digits3(w.w, inv_s, h3, m3, l3);
    const uint32_t ph = (uint32_t)(uint8_t)h0 | ((uint32_t)(uint8_t)h1 << 8) |
                        ((uint32_t)(uint8_t)h2 << 16) | ((uint32_t)(uint8_t)h3 << 24);
    const uint32_t pm = (uint32_t)(uint8_t)m0 | ((uint32_t)(uint8_t)m1 << 8) |
                        ((uint32_t)(uint8_t)m2 << 16) | ((uint32_t)(uint8_t)m3 << 24);
    const uint32_t pl = (uint32_t)(uint8_t)l0 | ((uint32_t)(uint8_t)l1 << 8) |
                        ((uint32_t)(uint8_t)l2 << 16) | ((uint32_t)(uint8_t)l3 << 24);
    *(uint32_t*)&P[4 * i]                   = ph;
    *(uint32_t*)&P[plane_elems + 4 * i]     = pm;
    *(uint32_t*)&P[2 * plane_elems + 4 * i] = pl;
}

__global__ __launch_bounds__(256)
void xcvt_i8(const float4* __restrict__ in, uint32_t* __restrict__ out) {
    const size_t i = (size_t)blockIdx.x * 256 + threadIdx.x;
    const float4 v = in[i];
    out[i] = (uint32_t)(v.x > 0.5f) | ((uint32_t)(v.y > 0.5f) << 8) |
             ((uint32_t)(v.z > 0.5f) << 16) | ((uint32_t)(v.w > 0.5f) << 24);
}

// ---------------------------------------------------------------------------
// B-direct batched 3-plane i8 GEMM. A[6400][K] x Wp[3][4096][K]^T -> cur.
// BM=256, BN=128, BK=64. 512 thr = 8 waves (4M x 2N); per-wave 64x64.
// A: 4-slot static-LDS ring (4 x 16 KiB), stage-ahead-3 via global_load_lds.
// B: direct global->reg dwordx4 per fragment (no LDS).
// Per body: wait vmcnt(2) [leaves newest stage pair in flight], barrier,
// load B(t+1) regs, stage A(t+3), ds_read A-frags(t+1), MFMA(t), fold.
// Grid 800 = 25 row-blocks x 32 col-blocks (XCD swizzle on cols).
// ---------------------------------------------------------------------------
template<int K>
__global__ __launch_bounds__(512, 2)
void gemm_planes_bd(const char* __restrict__ A, const char* __restrict__ Wp,
                    float* __restrict__ cur, float s_base)
{
    const int ITERS = 3 * K / 64;     // 192 (K=4096) / 72 (K=1536), both %4==0
    __shared__ char As[4][16384];     // 64 KiB static

    const int tid  = threadIdx.x;
    const int wave = tid >> 6, lane = tid & 63;
    const int wr = wave >> 1, wc = wave & 1;

    const int bid   = blockIdx.x;
    const int cbase = (((bid & 7) << 2) + ((bid >> 3) & 3)) * 128;
    const int abase = (bid >> 5) * 256;

    i32x4 acc[4][4];
    f32x4 facc[4][4];
#pragma unroll
    for (int i = 0; i < 4; ++i)
#pragma unroll
        for (int j = 0; j < 4; ++j) { acc[i][j] = (i32x4)(0); facc[i][j] = (f32x4)(0.f); }

    // A staging map (verified r10): 2 x GLL16 per thread per tile (16 KB).
    const int soff = tid * 16;               // 0..8191
    const int rs   = soff >> 6;              // row 0..127
    const int cs   = (soff >> 4) & 3;        // 16B chunk in row
    const int kbs  = ((cs ^ ((rs >> 1) & 3)) << 4);   // XOR bank swizzle
    const size_t aoff0 = (size_t)(abase + rs) * K + kbs;
    const size_t aoff1 = aoff0 + (size_t)128 * K;
    const int dstA0 = wave * 1024;
    const int dstA1 = 8192 + wave * 1024;

    // A-frag read offsets (verified r9/r10)
    const int rlo = lane & 15, rhi = lane >> 4;
    const int qr  = (rlo >> 1) & 3;
    const int rdA = (wr * 64 + rlo) * 64 + ((rhi ^ qr) << 4);

    // B-frag direct-global byte offsets (swizzles cancel; derived r12):
    // frag j: W[cbase + wc*64 + j*16 + rlo][kn + rhi*16 .. +15]
    const size_t bb0 = (size_t)(cbase + wc * 64 +  0 + rlo) * K + rhi * 16;
    const size_t bb1 = (size_t)(cbase + wc * 64 + 16 + rlo) * K + rhi * 16;
    const size_t bb2 = (size_t)(cbase + wc * 64 + 32 + rlo) * K + rhi * 16;
    const size_t bb3 = (size_t)(cbase + wc * 64 + 48 + rlo) * K + rhi * 16;

    auto stage = [&](int u, char* slot) {
        const int pn = (u * 64) / K;
        const int kn = u * 64 - pn * K;
        const char* ak = A + kn;
        GLL16(ak + aoff0, slot + dstA0);
        GLL16(ak + aoff1, slot + dstA1);
    };

    i32x4 avA[4], bvA[4], avB[4], bvB[4];

    // prologue: B(0) regs first, then stage tiles 0,1,2.
    {
        const char* bk = Wp;   // pn=0, kn=0
        bvA[0] = *(const i32x4*)(bk + bb0);
        bvA[1] = *(const i32x4*)(bk + bb1);
        bvA[2] = *(const i32x4*)(bk + bb2);
        bvA[3] = *(const i32x4*)(bk + bb3);
    }
    stage(0, &As[0][0]); stage(1, &As[1][0]); stage(2, &As[2][0]);
    // retire B(0)+stage(0); leave stage(1),stage(2) (4 loads) in flight
    asm volatile("s_waitcnt vmcnt(4)" ::: "memory");
    __builtin_amdgcn_s_barrier();
    asm volatile("" ::: "memory");
#pragma unroll
    for (int i = 0; i < 4; ++i) avA[i] = *(const i32x4*)(&As[0][0] + rdA + i * 1024);

#define BD_BODY(tt, NSLOT, SSLOT, avC, bvC, avN, bvN)                         \
    {                                                                         \
        if ((tt) + 2 < ITERS) { asm volatile("s_waitcnt vmcnt(2)" ::: "memory"); } \
        else                  { asm volatile("s_waitcnt vmcnt(0)" ::: "memory"); } \
        __builtin_amdgcn_s_barrier();                                         \
        asm volatile("" ::: "memory");                                        \
        if ((tt) + 1 < ITERS) {                                               \
            const int pn_ = (((tt) + 1) * 64) / K;                            \
            const int kn_ = ((tt) + 1) * 64 - pn_ * K;                        \
            const char* bk_ = Wp + (size_t)pn_ * ((size_t)N_H * K) + kn_;     \
            bvN[0] = *(const i32x4*)(bk_ + bb0);                              \
            bvN[1] = *(const i32x4*)(bk_ + bb1);                              \
            bvN[2] = *(const i32x4*)(bk_ + bb2);                              \
            bvN[3] = *(const i32x4*)(bk_ + bb3);                              \
        }                                                                     \
        if ((tt) + 3 < ITERS) stage((tt) + 3, &As[SSLOT][0]);                 \
        if ((tt) + 1 < ITERS) {                                               \
            const char* nb_ = &As[NSLOT][0];                                  \
            _Pragma("unroll")                                                 \
            for (int i = 0; i < 4; ++i)                                       \
                avN[i] = *(const i32x4*)(nb_ + rdA + i * 1024);               \
        }                                                                     \
        __builtin_amdgcn_s_setprio(1);                                        \
        _Pragma("unroll")                                                     \
        for (int i = 0; i < 4; ++i)                                           \
            _Pragma("unroll")                                                 \
            for (int j = 0; j < 4; ++j)                                       \
                acc[i][j] = __builtin_amdgcn_mfma_i32_16x16x64_i8(            \
                    avC[i], bvC[j], acc[i][j], 0, 0, 0);                      \
        __builtin_amdgcn_s_setprio(0);                                        \
        if (((((tt) + 1) * 64) % K) == 0) {                                   \
            const int p_ = ((tt) * 64) / K;                                   \
            const float sc_ = s_base * (float)(65536 >> (8 * p_));            \
            _Pragma("unroll")                                                 \
            for (int i = 0; i < 4; ++i)                                       \
                _Pragma("unroll")                                             \
                for (int j = 0; j < 4; ++j) {                                 \
                    _Pragma("unroll")                                         \
                    for (int r = 0; r < 4; ++r)                               \
                        facc[i][j][r] += sc_ * (float)acc[i][j][r];           \
                    acc[i][j] = (i32x4)(0);                                   \
                }                                                             \
        }                                                                     \
    }

    // slot of tile u = u % 4; register sets alternate A/B (period 2).
    for (int t = 0; t < ITERS; t += 4) {
        BD_BODY(t + 0, 1, 3, avA, bvA, avB, bvB);
        BD_BODY(t + 1, 2, 0, avB, bvB, avA, bvA);
        BD_BODY(t + 2, 3, 1, avA, bvA, avB, bvB);
        BD_BODY(t + 3, 0, 2, avB, bvB, avA, bvA);
    }
#undef BD_BODY

    const int orow = abase + wr * 64 + rhi * 4;
    const int ocol = cbase + wc * 64 + rlo;
#pragma unroll
    for (int i = 0; i < 4; ++i)
#pragma unroll
        for (int j = 0; j < 4; ++j)
#pragma unroll
            for (int r = 0; r < 4; ++r)
                cur[(size_t)(orow + i * 16 + r) * N_H + ocol + j * 16] = facc[i][j][r];
}

// ---------------------------------------------------------------------------
// layer-3 i8 GEMM, double-buffered (unchanged, small)
// ---------------------------------------------------------------------------
__global__ __launch_bounds__(256, 2)
void gemm3_i8(const char* __restrict__ A, const char* __restrict__ W3p,
              float* __restrict__ part3, float s_base)
{
    __shared__ char As[2 * 8192];
    __shared__ char Bs[2 * 4096];

    const int tid  = threadIdx.x;
    const int wave = tid >> 6, lane = tid & 63;
    const int wm = wave >> 1, wn = wave & 1;

    const int rowbase = blockIdx.x * 128;
    const int z = blockIdx.y;
    const int p = z >> 1;
    const int kstart = (z & 1) * 2048;

    i32x4 acc[4][2];
#pragma unroll
    for (int i = 0; i < 4; ++i)
#pragma unroll
        for (int j = 0; j < 2; ++j) acc[i][j] = (i32x4)(0);

    const int soff0 = wave * 2048 + lane * 16;
    const int soff1 = soff0 + 1024;
    const int r0 = soff0 >> 6, r1 = soff1 >> 6;
    const int kb0 = ((((soff0 >> 4) & 3) ^ ((r0 >> 1) & 3)) << 4);
    const int kb1 = ((((soff1 >> 4) & 3) ^ ((r1 >> 1) & 3)) << 4);
    const int soffB = tid * 16;
    const int rB = soffB >> 6;
    const int kbB = ((((soffB >> 4) & 3) ^ ((rB >> 1) & 3)) << 4);

    const size_t aoff0 = (size_t)(rowbase + r0) * 4096 + kb0;
    const size_t aoff1 = (size_t)(rowbase + r1) * 4096 + kb1;
    const size_t boff  = (size_t)rB * 4096 + kbB;

    const char* Bp = W3p + (size_t)p * 64 * 4096;
    const int sbase = wave * 2048;
    const int sbaseB = wave * 1024;

    const int rlo = lane & 15, rhi = lane >> 4;
    const int qr = (rlo >> 1) & 3;
    const int rdA = (wm * 64 + rlo) * 64 + ((rhi ^ qr) << 4);
    const int rdB = (wn * 32 + rlo) * 64 + ((rhi ^ qr) << 4);

    {
        GLL16(A + kstart + aoff0, As + sbase);
        GLL16(A + kstart + aoff1, As + sbase + 1024);
        GLL16(Bp + kstart + boff, Bs + sbaseB);
    }
    __syncthreads();

    for (int it = 0; it < 32; ++it) {
        const int bufA = (it & 1) * 8192;
        const int bufB = (it & 1) * 4096;
        if (it + 1 < 32) {
            const int kn = kstart + (it + 1) * 64;
            GLL16(A + kn + aoff0, As + (8192 - bufA) + sbase);
            GLL16(A + kn + aoff1, As + (8192 - bufA) + sbase + 1024);
            GLL16(Bp + kn + boff, Bs + (4096 - bufB) + sbaseB);
        }

        const char* pAf = As + bufA + rdA;
        const char* pBf = Bs + bufB + rdB;
        i32x4 av[4], bv[2];
#pragma unroll
        for (int i = 0; i < 4; ++i) av[i] = *(const i32x4*)(pAf + i * 1024);
#pragma unroll
        for (int j = 0; j < 2; ++j) bv[j] = *(const i32x4*)(pBf + j * 1024);
#pragma unroll
        for (int i = 0; i < 4; ++i)
#pragma unroll
            for (int j = 0; j < 2; ++j)
                acc[i][j] = __builtin_amdgcn_mfma_i32_16x16x64_i8(
                    av[i], bv[j], acc[i][j], 0, 0, 0);
        __syncthreads();
    }

    const float sc = s_base * (float)(65536 >> (8 * p));
    float* pout = part3 + (size_t)z * (12800 * 64);
    const int orow = rowbase + wm * 64 + rhi * 4;
    const int ocol = wn * 32 + rlo;
#pragma unroll
    for (int i = 0; i < 4; ++i)
#pragma unroll
        for (int j = 0; j < 2; ++j)
#pragma unroll
            for (int r = 0; r < 4; ++r)
                pout[(size_t)(orow + i * 16 + r) * 64 + ocol + j * 16] =
                    (float)acc[i][j][r] * sc;
}

// ---------------------------------------------------------------------------
// elementwise LIF time-scan over 25 steps (one chunk)
// ---------------------------------------------------------------------------
__global__ __launch_bounds__(256)
void lif_scan(const float* __restrict__ cur, const float* __restrict__ bias,
              float* __restrict__ mem, char* __restrict__ sout)
{
    const int i4  = blockIdx.x * 256 + threadIdx.x;   // 0..262143
    const int col = (i4 << 2) & (N_H - 1);
    const int b   = i4 >> 10;
    const float4 bv = *(const float4*)&bias[col];
    const size_t mbase = (size_t)b * N_H + col;
    float4 m = *(const float4*)&mem[mbase];

    for (int t = 0; t < 25; ++t) {
        const size_t off = ((size_t)t * BATCH + b) * N_H + col;
        const float4 cv = *(const float4*)&cur[off];
        float4 mn;
        { const float c = cv.x + bv.x;
          mn.x = 0.9f * m.x + c - ((m.x > 1.0f) ? 1.0f : 0.0f); }
        { const float c = cv.y + bv.y;
          mn.y = 0.9f * m.y + c - ((m.y > 1.0f) ? 1.0f : 0.0f); }
        { const float c = cv.z + bv.z;
          mn.z = 0.9f * m.z + c - ((m.z > 1.0f) ? 1.0f : 0.0f); }
        { const float c = cv.w + bv.w;
          mn.w = 0.9f * m.w + c - ((m.w > 1.0f) ? 1.0f : 0.0f); }
        const uint32_t sp = (uint32_t)(mn.x > 1.0f) | ((uint32_t)(mn.y > 1.0f) << 8) |
                            ((uint32_t)(mn.z > 1.0f) << 16) | ((uint32_t)(mn.w > 1.0f) << 24);
        *(uint32_t*)&sout[off] = sp;
        m = mn;
    }
    *(float4*)&mem[mbase] = m;
}

template<int NG>
__global__ __launch_bounds__(256)
void lif3_scan(const float* __restrict__ part, const float* __restrict__ b3,
               float* __restrict__ out)
{
    const int g = blockIdx.x * 256 + threadIdx.x;
    const int j = g & 63;
    const int b = g >> 6;
    const float bj = b3[j];
    float m = 0.f, accum = 0.f;
    for (int t = 0; t < T_STEPS; ++t) {
        const size_t row = (size_t)t * 256 + b;
        float cur = bj;
#pragma unroll
        for (int q = 0; q < NG; ++q)
            cur += part[(size_t)q * (12800 * 64) + row * 64 + j];
        const float reset = (m > 1.0f) ? 1.0f : 0.0f;
        m = 0.9f * m + cur - reset;
        accum += (m > 1.0f) ? 1.0f : 0.0f;
    }
    out[g] = accum;
}

// ---------------------------------------------------------------------------
// fp32 fallback path (round 1) — used only if ws_size too small
// ---------------------------------------------------------------------------
template<int K, bool PACK_BITS>
__global__ __launch_bounds__(512)
void gemm_lif(const float* __restrict__ A, const float* __restrict__ W,
              const float* __restrict__ bias, float* __restrict__ mem,
              float* __restrict__ s_f32, uint32_t* __restrict__ s_bits)
{
    __shared__ float Asf[32][68];
    __shared__ float Wsf[32][68];
    __shared__ uint8_t us[64][64];

    const int tid = threadIdx.x;
    const int abase = blockIdx.y * 64;
    const int cbase = blockIdx.x * 64;
    const int tx = tid & 15;
    const int ty = tid >> 4;

    float acc[2][4];
#pragma unroll
    for (int i = 0; i < 2; ++i)
#pragma unroll
        for (int j = 0; j < 4; ++j) acc[i][j] = 0.f;

    const int lrow = tid >> 3;
    const int lg = tid & 7;

    for (int k0 = 0; k0 < K; k0 += 32) {
        const float4 av = *(const float4*)&A[(size_t)(abase + lrow) * K + k0 + lg * 4];
        const float4 wv = *(const float4*)&W[(size_t)(cbase + lrow) * K + k0 + lg * 4];
        __syncthreads();
        Asf[lg * 4 + 0][lrow] = av.x; Asf[lg * 4 + 1][lrow] = av.y;
        Asf[lg * 4 + 2][lrow] = av.z; Asf[lg * 4 + 3][lrow] = av.w;
        Wsf[lg * 4 + 0][lrow] = wv.x; Wsf[lg * 4 + 1][lrow] = wv.y;
        Wsf[lg * 4 + 2][lrow] = wv.z; Wsf[lg * 4 + 3][lrow] = wv.w;
        __syncthreads();
#pragma unroll
        for (int kk = 0; kk < 32; ++kk) {
            const float2 a2 = *(const float2*)&Asf[kk][ty * 2];
            const float4 b4 = *(const float4*)&Wsf[kk][tx * 4];
            acc[0][0] += a2.x * b4.x; acc[0][1] += a2.x * b4.y;
            acc[0][2] += a2.x * b4.z; acc[0][3] += a2.x * b4.w;
            acc[1][0] += a2.y * b4.x; acc[1][1] += a2.y * b4.y;
            acc[1][2] += a2.y * b4.z; acc[1][3] += a2.y * b4.w;
        }
    }

    const int r0 = abase + ty * 2;
    const int c0loc = tx * 4;
    const int c0 = cbase + c0loc;
    const float4 bv = *(const float4*)&bias[c0];

#pragma unroll
    for (int i = 0; i < 2; ++i) {
        const size_t off = (size_t)(r0 + i) * N_H + c0;
        const float4 mp = *(const float4*)&mem[off];
        float4 mn, sp;
        { float cur = acc[i][0] + bv.x;
          mn.x = 0.9f * mp.x + cur - ((mp.x > 1.0f) ? 1.0f : 0.0f);
          sp.x = (mn.x > 1.0f) ? 1.0f : 0.0f; }
        { float cur = acc[i][1] + bv.y;
          mn.y = 0.9f * mp.y + cur - ((mp.y > 1.0f) ? 1.0f : 0.0f);
          sp.y = (mn.y > 1.0f) ? 1.0f : 0.0f; }
        { float cur = acc[i][2] + bv.z;
          mn.z = 0.9f * mp.z + cur - ((mp.z > 1.0f) ? 1.0f : 0.0f);
          sp.z = (mn.z > 1.0f) ? 1.0f : 0.0f; }
        { float cur = acc[i][3] + bv.w;
          mn.w = 0.9f * mp.w + cur - ((mp.w > 1.0f) ? 1.0f : 0.0f);
          sp.w = (mn.w > 1.0f) ? 1.0f : 0.0f; }
        *(float4*)&mem[off] = mn;
        if constexpr (!PACK_BITS) {
            *(float4*)&s_f32[off] = sp;
        } else {
            us[ty * 2 + i][c0loc + 0] = (uint8_t)sp.x;
            us[ty * 2 + i][c0loc + 1] = (uint8_t)sp.y;
            us[ty * 2 + i][c0loc + 2] = (uint8_t)sp.z;
            us[ty * 2 + i][c0loc + 3] = (uint8_t)sp.w;
        }
    }

    if constexpr (PACK_BITS) {
        __syncthreads();
        if (tid < 128) {
            const int r = tid >> 1;
            const int w = tid & 1;
            uint32_t bits = 0;
#pragma unroll
            for (int b = 0; b < 32; ++b)
                bits |= ((uint32_t)us[r][w * 32 + b]) << b;
            s_bits[(size_t)(abase + r) * 128 + (cbase >> 5) + w] = bits;
        }
    }
}

__global__ __launch_bounds__(256)
void gemm3_bits(const uint32_t* __restrict__ s_bits, const float* __restrict__ W3,
                float* __restrict__ part)
{
    __shared__ float Asf[32][68];
    __shared__ float Wsf[32][68];

    const int tid = threadIdx.x;
    const int rowbase = blockIdx.x * 64;
    const int ks = blockIdx.y;
    const int tx = tid & 15;
    const int ty = tid >> 4;

    float acc[4][4];
#pragma unroll
    for (int i = 0; i < 4; ++i)
#pragma unroll
        for (int j = 0; j < 4; ++j) acc[i][j] = 0.f;

    const int r  = tid & 63;
    const int q  = tid >> 6;
    const int wr = tid >> 3;
    const int wg = tid & 7;

    for (int c = 0; c < 32; ++c) {
        const int k0 = ks * 1024 + c * 32;
        const uint32_t word = s_bits[(size_t)(rowbase + r) * 128 + (k0 >> 5)];
        const float4 wv0 = *(const float4*)&W3[(size_t)wr * 4096 + k0 + wg * 4];
        const float4 wv1 = *(const float4*)&W3[(size_t)(wr + 32) * 4096 + k0 + wg * 4];
        __syncthreads();
#pragma unroll
        for (int u = 0; u < 8; ++u)
            Asf[q * 8 + u][r] = (float)((word >> (q * 8 + u)) & 1u);
        Wsf[wg * 4 + 0][wr] = wv0.x;
        Wsf[wg * 4 + 1][wr] = wv0.y;
        Wsf[wg * 4 + 2][wr] = wv0.z;
        Wsf[wg * 4 + 3][wr] = wv0.w;
        Wsf[wg * 4 + 0][wr + 32] = wv1.x;
        Wsf[wg * 4 + 1][wr + 32] = wv1.y;
        Wsf[wg * 4 + 2][wr + 32] = wv1.z;
        Wsf[wg * 4 + 3][wr + 32] = wv1.w;
        __syncthreads();
#pragma unroll
        for (int kk = 0; kk < 32; ++kk) {
            const float4 a4 = *(const float4*)&Asf[kk][ty * 4];
            const float4 b4 = *(const float4*)&Wsf[kk][tx * 4];
            acc[0][0] += a4.x * b4.x; acc[0][1] += a4.x * b4.y;
            acc[0][2] += a4.x * b4.z; acc[0][3] += a4.x * b4.w;
            acc[1][0] += a4.y * b4.x; acc[1][1] += a4.y * b4.y;
            acc[1][2] += a4.y * b4.z; acc[1][3] += a4.y * b4.w;
            acc[2][0] += a4.z * b4.x; acc[2][1] += a4.z * b4.y;
            acc[2][2] += a4.z * b4.z; acc[2][3] += a4.z * b4.w;
            acc[3][0] += a4.w * b4.x; acc[3][1] += a4.w * b4.y;
            acc[3][2] += a4.w * b4.z; acc[3][3] += a4.w * b4.w;
        }
    }
#pragma unroll
    for (int i = 0; i < 4; ++i) {
        float4 v = make_float4(acc[i][0], acc[i][1], acc[i][2], acc[i][3]);
        *(float4*)&part[((size_t)ks * 12800 + rowbase + ty * 4 + i) * 64 + tx * 4] = v;
    }
}

// ---------------------------------------------------------------------------
extern "C" void kernel_launch(void* const* d_in, const int* in_sizes, int n_in,
                              void* d_out, int out_size, void* d_ws, size_t ws_size,
                              hipStream_t stream)
{
    const float* x  = (const float*)d_in[0];
    const float* W1 = (const float*)d_in[1];
    const float* b1 = (const float*)d_in[2];
    const float* W2 = (const float*)d_in[3];
    const float* b2 = (const float*)d_in[4];
    const float* W3 = (const float*)d_in[5];
    const float* b3 = (const float*)d_in[6];

    char* ws = (char*)d_ws;

    // layout (bytes):
    const size_t oW1p = 0;              //  18,874,368  W1 planes i8
    const size_t oW2p = 18874368;       //  50,331,648  W2 planes i8
    const size_t oW3p = 69206016;       //     786,432  W3 planes i8
    const size_t oXi8 = 69992448;       //  19,660,800  input spikes i8
    const size_t oS1  = 89653248;       //  26,214,400  s1 (one 25-step chunk)
    const size_t oS2  = 115867648;      //  52,428,800  s2 (all 50 steps)
    const size_t oM1  = 168296448;      //   4,194,304  m1 carry
    const size_t oM2  = 172490752;      //   4,194,304  m2 carry (contig w/ m1)
    const size_t oCur = 176685056;      // 104,857,600  cur1/cur2 shared; part3 alias
    const size_t NEED = 281542656;

    const double bnd1 = 1.0 / sqrt(1536.0);
    const double bnd2 = 1.0 / 64.0;
    const double bnd3 = 1.0 / 64.0;
    const float inv1 = (float)((double)DEN / bnd1), sb1 = (float)(bnd1 / (double)DEN);
    const float inv2 = (float)((double)DEN / bnd2), sb2 = (float)(bnd2 / (double)DEN);
    const float inv3 = (float)((double)DEN / bnd3), sb3 = (float)(bnd3 / (double)DEN);

    if (ws_size >= NEED) {
        char*  W1p  = ws + oW1p;
        char*  W2p  = ws + oW2p;
        char*  W3p  = ws + oW3p;
        char*  xi8  = ws + oXi8;
        char*  s1   = ws + oS1;
        char*  s2   = ws + oS2;
        float* m1   = (float*)(ws + oM1);
        float* m2   = (float*)(ws + oM2);
        float* cur  = (float*)(ws + oCur);
        float* part3 = cur;   // reuse after lif2_scan of chunk 1

        split3_i8<<<6144, 256, 0, stream>>>((const float4*)W1, W1p,
                                            (size_t)4096 * 1536, inv1);
        split3_i8<<<16384, 256, 0, stream>>>((const float4*)W2, W2p,
                                             (size_t)4096 * 4096, inv2);
        split3_i8<<<256, 256, 0, stream>>>((const float4*)W3, W3p,
                                           (size_t)64 * 4096, inv3);
        xcvt_i8<<<19200, 256, 0, stream>>>((const float4*)x, (uint32_t*)xi8);
        zero_ws<<<2048, 256, 0, stream>>>((float4*)m1);   // m1 + m2 contiguous

        const size_t chunk_rows = (size_t)25 * BATCH;     // 6400
        for (int chunk = 0; chunk < 2; ++chunk) {
            gemm_planes_bd<1536><<<800, 512, 0, stream>>>(
                xi8 + chunk * chunk_rows * 1536, W1p, cur, sb1);
            lif_scan<<<1024, 256, 0, stream>>>(cur, b1, m1, s1);
            gemm_planes_bd<4096><<<800, 512, 0, stream>>>(s1, W2p, cur, sb2);
            lif_scan<<<1024, 256, 0, stream>>>(cur, b2, m2,
                                               s2 + chunk * chunk_rows * N_H);
        }
        gemm3_i8<<<dim3(100, 6), 256, 0, stream>>>(s2, W3p, part3, sb3);
        lif3_scan<6><<<64, 256, 0, stream>>>(part3, b3, (float*)d_out);
    } else {
        float*    m1     = (float*)(ws);
        float*    m2     = (float*)(ws + (size_t)4 * 1024 * 1024);
        float*    s1f    = (float*)(ws + (size_t)8 * 1024 * 1024);
        uint32_t* s2bits = (uint32_t*)(ws + (size_t)12 * 1024 * 1024);
        float*    part   = (float*)(ws + (size_t)20 * 1024 * 1024);

        zero_ws<<<2048, 256, 0, stream>>>((float4*)m1);
        for (int t = 0; t < T_STEPS; ++t) {
            gemm_lif<1536, false><<<dim3(64, 4), 512, 0, stream>>>(
                x + (size_t)t * BATCH * 1536, W1, b1, m1, s1f, nullptr);
            gemm_lif<4096, true><<<dim3(64, 4), 512, 0, stream>>>(
                s1f, W2, b2, m2, nullptr, s2bits + (size_t)t * BATCH * 128);
        }
        gemm3_bits<<<dim3(200, 4), 256, 0, stream>>>(s2bits, W3, part);
        lif3_scan<4><<<64, 256, 0, stream>>>(part, b3, (float*)d_out);
    }
}

// Round 5
// 2909.778 us; speedup vs baseline: 2.2359x; 1.0132x over previous
//
#include <hip/hip_runtime.h>
#include <stdint.h>
#include <stddef.h>
#include <math.h>

// ContextSNN round 13: B-direct with corrected wait discipline.
// r12 failed because vmcnt(2) at body top drained the just-issued B loads
// (1-body lookahead, full L2/HBM latency per body -> 13% MfmaUtil).
// r13: B loads 2-body lookahead in a 3-deep rotating reg set; body-top wait
// is vmcnt(6) == exactly the previous body's issues (4 B + 2 A-stage),
// placed BEFORE the barrier (r10 cross-wave invariant: every wave's
// stage(t+1) retired before any wave ds_reads slot t+1). LDS traffic/body
// drops 88KB -> 48KB (A only; floor ~565cy vs MFMA 585cy). B duplication
// across the 4 same-wc waves is absorbed by L1 (same 64B lines, one CU).
// A-side maps byte-identical to r10 (verified); B addresses identical to
// r12 (verified). Exact i32 plane fold unchanged. T=50,B=256,IN=1536,H=4096.

#define T_STEPS 50
#define BATCH   256
#define N_H     4096
#define DEN     8355711   // 127*65536 + 127*256 + 127

typedef unsigned short u16;
typedef __attribute__((ext_vector_type(4))) int i32x4;
typedef __attribute__((ext_vector_type(4))) float f32x4;

#define GLL16(gp, lp) __builtin_amdgcn_global_load_lds( \
    (const __attribute__((address_space(1))) void*)(gp), \
    (__attribute__((address_space(3))) void*)(lp), 16, 0, 0)

// ---------------------------------------------------------------------------
// prep
// ---------------------------------------------------------------------------
__global__ __launch_bounds__(256) void zero_ws(float4* __restrict__ p) {
    p[(size_t)blockIdx.x * 256 + threadIdx.x] = make_float4(0.f, 0.f, 0.f, 0.f);
}

__device__ inline void digits3(float w, float inv_s, int& h, int& m, int& l) {
    int V = (int)rintf(w * inv_s);
    V = min(max(V, -DEN), DEN);
    l = ((V + 128) & 255) - 128;
    const int V2 = (V - l) >> 8;
    m = ((V2 + 128) & 255) - 128;
    h = (V2 - m) >> 8;
}

__global__ __launch_bounds__(256)
void split3_i8(const float4* __restrict__ W, char* __restrict__ P,
               size_t plane_elems, float inv_s)
{
    const size_t i = (size_t)blockIdx.x * 256 + threadIdx.x;
    const float4 w = W[i];
    int h0,m0,l0,h1,m1,l1,h2,m2,l2,h3,m3,l3;
    digits3(w.x, inv_s, h0, m0, l0);
    digits3(w.y, inv_s, h1, m1, l1);
    digits3(w.z, inv_s, h2, m2, l2);
    digits3(w.w, inv_s, h3, m3, l3);
    const uint32_t ph = (uint32_t)(uint8_t)h0 | ((uint32_t)(uint8_t)h1 << 8) |
                        ((uint32_t)(uint8_t)h2 << 16) | ((uint32_t)(uint8_t)h3 << 24);
    const uint32_t pm = (uint32_t)(uint8_t)m0 | ((uint32_t)(uint8_t)m1 << 8) |
                        ((uint32_t)(uint8_t)m2 << 16) | ((uint32_t)(uint8_t)m3 << 24);
    const uint32_t pl = (uint32_t)(uint8_t)l0 | ((uint32_t)(uint8_t)l1 << 8) |
                        ((uint32_t)(uint8_t)l2 << 16) | ((uint32_t)(uint8_t)l3 << 24);
    *(uint32_t*)&P[4 * i]                   = ph;
    *(uint32_t*)&P[plane_elems + 4 * i]     = pm;
    *(uint32_t*)&P[2 * plane_elems + 4 * i] = pl;
}

__global__ __launch_bounds__(256)
void xcvt_i8(const float4* __restrict__ in, uint32_t* __restrict__ out) {
    const size_t i = (size_t)blockIdx.x * 256 + threadIdx.x;
    const float4 v = in[i];
    out[i] = (uint32_t)(v.x > 0.5f) | ((uint32_t)(v.y > 0.5f) << 8) |
             ((uint32_t)(v.z > 0.5f) << 16) | ((uint32_t)(v.w > 0.5f) << 24);
}

// ---------------------------------------------------------------------------
// B-direct batched 3-plane i8 GEMM, corrected pipeline.
// A[6400][K] x Wp[3][4096][K]^T -> cur[6400][4096].
// BM=256, BN=128, BK=64. 512 thr = 8 waves (4M x 2N); per-wave 64x64.
// A: 4-slot static-LDS ring (4x16 KiB), staged 3 ahead via global_load_lds.
// B: direct global->reg dwordx4, 3-deep rotating set, loaded 2 ahead.
// Body t: vmcnt(6) [= body t-1's issues] BEFORE barrier; barrier; issue
// B(t+2); stage A(t+3); ds_read A-frags(t+1); 16 MFMA on tile t; fold.
// Grid 800 = 25 row-blocks x 32 col-blocks (XCD swizzle on cols).
// ---------------------------------------------------------------------------
template<int K>
__global__ __launch_bounds__(512, 2)
void gemm_planes_bd2(const char* __restrict__ A, const char* __restrict__ Wp,
                     float* __restrict__ cur, float s_base)
{
    const int ITERS = 3 * K / 64;     // 192 (K=4096) / 72 (K=1536); %12 == 0
    __shared__ char As[4][16384];     // 64 KiB static

    const int tid  = threadIdx.x;
    const int wave = tid >> 6, lane = tid & 63;
    const int wr = wave >> 1, wc = wave & 1;

    const int bid   = blockIdx.x;
    const int cbase = (((bid & 7) << 2) + ((bid >> 3) & 3)) * 128;
    const int abase = (bid >> 5) * 256;

    i32x4 acc[4][4];
    f32x4 facc[4][4];
#pragma unroll
    for (int i = 0; i < 4; ++i)
#pragma unroll
        for (int j = 0; j < 4; ++j) { acc[i][j] = (i32x4)(0); facc[i][j] = (f32x4)(0.f); }

    // A staging map (verified r10): 2 x GLL16 per thread per tile (16 KB).
    const int soff = tid * 16;               // 0..8191
    const int rs   = soff >> 6;              // row 0..127
    const int cs   = (soff >> 4) & 3;        // 16B chunk in row
    const int kbs  = ((cs ^ ((rs >> 1) & 3)) << 4);   // XOR bank swizzle
    const size_t aoff0 = (size_t)(abase + rs) * K + kbs;
    const size_t aoff1 = aoff0 + (size_t)128 * K;
    const int dstA0 = wave * 1024;
    const int dstA1 = 8192 + wave * 1024;

    // A-frag read offsets (verified r9/r10)
    const int rlo = lane & 15, rhi = lane >> 4;
    const int qr  = (rlo >> 1) & 3;
    const int rdA = (wr * 64 + rlo) * 64 + ((rhi ^ qr) << 4);

    // B-frag direct-global byte offsets (verified r12):
    // frag j: W[cbase + wc*64 + j*16 + rlo][kn + rhi*16 .. +15]
    const size_t bb0 = (size_t)(cbase + wc * 64 +  0 + rlo) * K + rhi * 16;
    const size_t bb1 = (size_t)(cbase + wc * 64 + 16 + rlo) * K + rhi * 16;
    const size_t bb2 = (size_t)(cbase + wc * 64 + 32 + rlo) * K + rhi * 16;
    const size_t bb3 = (size_t)(cbase + wc * 64 + 48 + rlo) * K + rhi * 16;

#define LOADB(u, BV)                                                          \
    {                                                                         \
        const int pn_ = ((u) * 64) / K;                                       \
        const int kn_ = (u) * 64 - pn_ * K;                                   \
        const char* bk_ = Wp + (size_t)pn_ * ((size_t)N_H * K) + kn_;         \
        BV[0] = *(const i32x4*)(bk_ + bb0);                                   \
        BV[1] = *(const i32x4*)(bk_ + bb1);                                   \
        BV[2] = *(const i32x4*)(bk_ + bb2);                                   \
        BV[3] = *(const i32x4*)(bk_ + bb3);                                   \
    }

#define STAGEA(u, SS)                                                         \
    {                                                                         \
        const int pn_ = ((u) * 64) / K;                                       \
        const int kn_ = (u) * 64 - pn_ * K;                                   \
        const char* ak_ = A + kn_;                                            \
        GLL16(ak_ + aoff0, &As[SS][0] + dstA0);                               \
        GLL16(ak_ + aoff1, &As[SS][0] + dstA1);                               \
    }

#define READA(SN, AV)                                                         \
    {                                                                         \
        const char* nb_ = &As[SN][0];                                         \
        _Pragma("unroll")                                                     \
        for (int i = 0; i < 4; ++i)                                           \
            AV[i] = *(const i32x4*)(nb_ + rdA + i * 1024);                    \
    }

#define FOLD(tt)                                                              \
    if (((((tt) + 1) * 64) % K) == 0) {                                       \
        const int p_ = ((tt) * 64) / K;                                       \
        const float sc_ = s_base * (float)(65536 >> (8 * p_));                \
        _Pragma("unroll")                                                     \
        for (int i = 0; i < 4; ++i)                                           \
            _Pragma("unroll")                                                 \
            for (int j = 0; j < 4; ++j) {                                     \
                _Pragma("unroll")                                             \
                for (int r = 0; r < 4; ++r)                                   \
                    facc[i][j][r] += sc_ * (float)acc[i][j][r];               \
                acc[i][j] = (i32x4)(0);                                       \
            }                                                                 \
    }

// BODY(tt, NW, AVC, AVN, BVC, BVL, SN, SS, GB, GS, GR):
//   wait vmcnt(NW) [== loads issued in body tt-1]; barrier;
//   GB: load B(tt+2) -> BVL; GS: stage A(tt+3) -> slot SS;
//   GR: ds_read A-frags(tt+1) from slot SN -> AVN; MFMA(tt) AVC x BVC; fold.
#define BODY(tt, NW, AVC, AVN, BVC, BVL, SN, SS, GB, GS, GR)                  \
    {                                                                         \
        asm volatile("s_waitcnt vmcnt(" #NW ")" ::: "memory");                \
        __builtin_amdgcn_s_barrier();                                         \
        asm volatile("" ::: "memory");                                        \
        if (GB) LOADB((tt) + 2, BVL);                                         \
        if (GS) STAGEA((tt) + 3, SS);                                         \
        if (GR) READA(SN, AVN);                                               \
        __builtin_amdgcn_s_setprio(1);                                        \
        _Pragma("unroll")                                                     \
        for (int i = 0; i < 4; ++i)                                           \
            _Pragma("unroll")                                                 \
            for (int j = 0; j < 4; ++j)                                       \
                acc[i][j] = __builtin_amdgcn_mfma_i32_16x16x64_i8(            \
                    AVC[i], BVC[j], acc[i][j], 0, 0, 0);                      \
        __builtin_amdgcn_s_setprio(0);                                        \
        FOLD(tt);                                                             \
    }

    i32x4 av0[4], av1[4], bv0[4], bv1[4], bv2[4];

    // prologue: B(0), B(1); stage tiles 0,1,2. vmcnt(4) leaves stage(1,2)
    // in flight (stage(0)+B retired on every wave before barrier).
    LOADB(0, bv0);
    LOADB(1, bv1);
    STAGEA(0, 0); STAGEA(1, 1); STAGEA(2, 2);
    asm volatile("s_waitcnt vmcnt(4)" ::: "memory");
    __builtin_amdgcn_s_barrier();
    asm volatile("" ::: "memory");
    READA(0, av0);

    // body 0 (t=0): previous "body" (prologue after stage(1)) left 2 in
    // flight -> NW=2. Mapping per t: AVC=t%2, BVC=t%3, BVL=(t+2)%3,
    // SN=(t+1)%4, SS=(t+3)%4.
    BODY(0, 2, av0, av1, bv0, bv2, 1, 3, 1, 1, 1);

    // main loop: t = 1 + 12k; all rotation residues fixed (12 = lcm(2,3,4)).
    // Steady NW = 6 (= 4 B + 2 stage issued in previous body).
    int t = 1;
    for (; t + 11 < ITERS - 3; t += 12) {
        BODY(t + 0,  6, av1, av0, bv1, bv0, 2, 0, 1, 1, 1);
        BODY(t + 1,  6, av0, av1, bv2, bv1, 3, 1, 1, 1, 1);
        BODY(t + 2,  6, av1, av0, bv0, bv2, 0, 2, 1, 1, 1);
        BODY(t + 3,  6, av0, av1, bv1, bv0, 1, 3, 1, 1, 1);
        BODY(t + 4,  6, av1, av0, bv2, bv1, 2, 0, 1, 1, 1);
        BODY(t + 5,  6, av0, av1, bv0, bv2, 3, 1, 1, 1, 1);
        BODY(t + 6,  6, av1, av0, bv1, bv0, 0, 2, 1, 1, 1);
        BODY(t + 7,  6, av0, av1, bv2, bv1, 1, 3, 1, 1, 1);
        BODY(t + 8,  6, av1, av0, bv0, bv2, 2, 0, 1, 1, 1);
        BODY(t + 9,  6, av0, av1, bv1, bv0, 3, 1, 1, 1, 1);
        BODY(t + 10, 6, av1, av0, bv2, bv1, 0, 2, 1, 1, 1);
        BODY(t + 11, 6, av0, av1, bv0, bv2, 1, 3, 1, 1, 1);
    }

    // tail: 11 bodies, t = ITERS-11 .. ITERS-1 (same residues as main).
    // Guards: GB = j<9, GS = j<8, GR = j<10. NW = 4*[j<10] + 2*[j<9].
    BODY(t + 0,  6, av1, av0, bv1, bv0, 2, 0, 1, 1, 1);
    BODY(t + 1,  6, av0, av1, bv2, bv1, 3, 1, 1, 1, 1);
    BODY(t + 2,  6, av1, av0, bv0, bv2, 0, 2, 1, 1, 1);
    BODY(t + 3,  6, av0, av1, bv1, bv0, 1, 3, 1, 1, 1);
    BODY(t + 4,  6, av1, av0, bv2, bv1, 2, 0, 1, 1, 1);
    BODY(t + 5,  6, av0, av1, bv0, bv2, 3, 1, 1, 1, 1);
    BODY(t + 6,  6, av1, av0, bv1, bv0, 0, 2, 1, 1, 1);
    BODY(t + 7,  6, av0, av1, bv2, bv1, 1, 3, 1, 1, 1);
    BODY(t + 8,  6, av1, av0, bv0, bv2, 2, 0, 1, 0, 1);
    BODY(t + 9,  4, av0, av1, bv1, bv0, 3, 1, 0, 0, 1);
    BODY(t + 10, 0, av1, av0, bv2, bv1, 0, 2, 0, 0, 0);

#undef BODY
#undef FOLD
#undef READA
#undef STAGEA
#undef LOADB

    const int orow = abase + wr * 64 + rhi * 4;
    const int ocol = cbase + wc * 64 + rlo;
#pragma unroll
    for (int i = 0; i < 4; ++i)
#pragma unroll
        for (int j = 0; j < 4; ++j)
#pragma unroll
            for (int r = 0; r < 4; ++r)
                cur[(size_t)(orow + i * 16 + r) * N_H + ocol + j * 16] = facc[i][j][r];
}

// ---------------------------------------------------------------------------
// layer-3 i8 GEMM, double-buffered (unchanged, small)
// ---------------------------------------------------------------------------
__global__ __launch_bounds__(256, 2)
void gemm3_i8(const char* __restrict__ A, const char* __restrict__ W3p,
              float* __restrict__ part3, float s_base)
{
    __shared__ char As[2 * 8192];
    __shared__ char Bs[2 * 4096];

    const int tid  = threadIdx.x;
    const int wave = tid >> 6, lane = tid & 63;
    const int wm = wave >> 1, wn = wave & 1;

    const int rowbase = blockIdx.x * 128;
    const int z = blockIdx.y;
    const int p = z >> 1;
    const int kstart = (z & 1) * 2048;

    i32x4 acc[4][2];
#pragma unroll
    for (int i = 0; i < 4; ++i)
#pragma unroll
        for (int j = 0; j < 2; ++j) acc[i][j] = (i32x4)(0);

    const int soff0 = wave * 2048 + lane * 16;
    const int soff1 = soff0 + 1024;
    const int r0 = soff0 >> 6, r1 = soff1 >> 6;
    const int kb0 = ((((soff0 >> 4) & 3) ^ ((r0 >> 1) & 3)) << 4);
    const int kb1 = ((((soff1 >> 4) & 3) ^ ((r1 >> 1) & 3)) << 4);
    const int soffB = tid * 16;
    const int rB = soffB >> 6;
    const int kbB = ((((soffB >> 4) & 3) ^ ((rB >> 1) & 3)) << 4);

    const size_t aoff0 = (size_t)(rowbase + r0) * 4096 + kb0;
    const size_t aoff1 = (size_t)(rowbase + r1) * 4096 + kb1;
    const size_t boff  = (size_t)rB * 4096 + kbB;

    const char* Bp = W3p + (size_t)p * 64 * 4096;
    const int sbase = wave * 2048;
    const int sbaseB = wave * 1024;

    const int rlo = lane & 15, rhi = lane >> 4;
    const int qr = (rlo >> 1) & 3;
    const int rdA = (wm * 64 + rlo) * 64 + ((rhi ^ qr) << 4);
    const int rdB = (wn * 32 + rlo) * 64 + ((rhi ^ qr) << 4);

    {
        GLL16(A + kstart + aoff0, As + sbase);
        GLL16(A + kstart + aoff1, As + sbase + 1024);
        GLL16(Bp + kstart + boff, Bs + sbaseB);
    }
    __syncthreads();

    for (int it = 0; it < 32; ++it) {
        const int bufA = (it & 1) * 8192;
        const int bufB = (it & 1) * 4096;
        if (it + 1 < 32) {
            const int kn = kstart + (it + 1) * 64;
            GLL16(A + kn + aoff0, As + (8192 - bufA) + sbase);
            GLL16(A + kn + aoff1, As + (8192 - bufA) + sbase + 1024);
            GLL16(Bp + kn + boff, Bs + (4096 - bufB) + sbaseB);
        }

        const char* pAf = As + bufA + rdA;
        const char* pBf = Bs + bufB + rdB;
        i32x4 av[4], bv[2];
#pragma unroll
        for (int i = 0; i < 4; ++i) av[i] = *(const i32x4*)(pAf + i * 1024);
#pragma unroll
        for (int j = 0; j < 2; ++j) bv[j] = *(const i32x4*)(pBf + j * 1024);
#pragma unroll
        for (int i = 0; i < 4; ++i)
#pragma unroll
            for (int j = 0; j < 2; ++j)
                acc[i][j] = __builtin_amdgcn_mfma_i32_16x16x64_i8(
                    av[i], bv[j], acc[i][j], 0, 0, 0);
        __syncthreads();
    }

    const float sc = s_base * (float)(65536 >> (8 * p));
    float* pout = part3 + (size_t)z * (12800 * 64);
    const int orow = rowbase + wm * 64 + rhi * 4;
    const int ocol = wn * 32 + rlo;
#pragma unroll
    for (int i = 0; i < 4; ++i)
#pragma unroll
        for (int j = 0; j < 2; ++j)
#pragma unroll
            for (int r = 0; r < 4; ++r)
                pout[(size_t)(orow + i * 16 + r) * 64 + ocol + j * 16] =
                    (float)acc[i][j][r] * sc;
}

// ---------------------------------------------------------------------------
// elementwise LIF time-scan over 25 steps (one chunk)
// ---------------------------------------------------------------------------
__global__ __launch_bounds__(256)
void lif_scan(const float* __restrict__ cur, const float* __restrict__ bias,
              float* __restrict__ mem, char* __restrict__ sout)
{
    const int i4  = blockIdx.x * 256 + threadIdx.x;   // 0..262143
    const int col = (i4 << 2) & (N_H - 1);
    const int b   = i4 >> 10;
    const float4 bv = *(const float4*)&bias[col];
    const size_t mbase = (size_t)b * N_H + col;
    float4 m = *(const float4*)&mem[mbase];

    for (int t = 0; t < 25; ++t) {
        const size_t off = ((size_t)t * BATCH + b) * N_H + col;
        const float4 cv = *(const float4*)&cur[off];
        float4 mn;
        { const float c = cv.x + bv.x;
          mn.x = 0.9f * m.x + c - ((m.x > 1.0f) ? 1.0f : 0.0f); }
        { const float c = cv.y + bv.y;
          mn.y = 0.9f * m.y + c - ((m.y > 1.0f) ? 1.0f : 0.0f); }
        { const float c = cv.z + bv.z;
          mn.z = 0.9f * m.z + c - ((m.z > 1.0f) ? 1.0f : 0.0f); }
        { const float c = cv.w + bv.w;
          mn.w = 0.9f * m.w + c - ((m.w > 1.0f) ? 1.0f : 0.0f); }
        const uint32_t sp = (uint32_t)(mn.x > 1.0f) | ((uint32_t)(mn.y > 1.0f) << 8) |
                            ((uint32_t)(mn.z > 1.0f) << 16) | ((uint32_t)(mn.w > 1.0f) << 24);
        *(uint32_t*)&sout[off] = sp;
        m = mn;
    }
    *(float4*)&mem[mbase] = m;
}

template<int NG>
__global__ __launch_bounds__(256)
void lif3_scan(const float* __restrict__ part, const float* __restrict__ b3,
               float* __restrict__ out)
{
    const int g = blockIdx.x * 256 + threadIdx.x;
    const int j = g & 63;
    const int b = g >> 6;
    const float bj = b3[j];
    float m = 0.f, accum = 0.f;
    for (int t = 0; t < T_STEPS; ++t) {
        const size_t row = (size_t)t * 256 + b;
        float cur = bj;
#pragma unroll
        for (int q = 0; q < NG; ++q)
            cur += part[(size_t)q * (12800 * 64) + row * 64 + j];
        const float reset = (m > 1.0f) ? 1.0f : 0.0f;
        m = 0.9f * m + cur - reset;
        accum += (m > 1.0f) ? 1.0f : 0.0f;
    }
    out[g] = accum;
}

// ---------------------------------------------------------------------------
// fp32 fallback path (round 1) — used only if ws_size too small
// ---------------------------------------------------------------------------
template<int K, bool PACK_BITS>
__global__ __launch_bounds__(512)
void gemm_lif(const float* __restrict__ A, const float* __restrict__ W,
              const float* __restrict__ bias, float* __restrict__ mem,
              float* __restrict__ s_f32, uint32_t* __restrict__ s_bits)
{
    __shared__ float Asf[32][68];
    __shared__ float Wsf[32][68];
    __shared__ uint8_t us[64][64];

    const int tid = threadIdx.x;
    const int abase = blockIdx.y * 64;
    const int cbase = blockIdx.x * 64;
    const int tx = tid & 15;
    const int ty = tid >> 4;

    float acc[2][4];
#pragma unroll
    for (int i = 0; i < 2; ++i)
#pragma unroll
        for (int j = 0; j < 4; ++j) acc[i][j] = 0.f;

    const int lrow = tid >> 3;
    const int lg = tid & 7;

    for (int k0 = 0; k0 < K; k0 += 32) {
        const float4 av = *(const float4*)&A[(size_t)(abase + lrow) * K + k0 + lg * 4];
        const float4 wv = *(const float4*)&W[(size_t)(cbase + lrow) * K + k0 + lg * 4];
        __syncthreads();
        Asf[lg * 4 + 0][lrow] = av.x; Asf[lg * 4 + 1][lrow] = av.y;
        Asf[lg * 4 + 2][lrow] = av.z; Asf[lg * 4 + 3][lrow] = av.w;
        Wsf[lg * 4 + 0][lrow] = wv.x; Wsf[lg * 4 + 1][lrow] = wv.y;
        Wsf[lg * 4 + 2][lrow] = wv.z; Wsf[lg * 4 + 3][lrow] = wv.w;
        __syncthreads();
#pragma unroll
        for (int kk = 0; kk < 32; ++kk) {
            const float2 a2 = *(const float2*)&Asf[kk][ty * 2];
            const float4 b4 = *(const float4*)&Wsf[kk][tx * 4];
            acc[0][0] += a2.x * b4.x; acc[0][1] += a2.x * b4.y;
            acc[0][2] += a2.x * b4.z; acc[0][3] += a2.x * b4.w;
            acc[1][0] += a2.y * b4.x; acc[1][1] += a2.y * b4.y;
            acc[1][2] += a2.y * b4.z; acc[1][3] += a2.y * b4.w;
        }
    }

    const int r0 = abase + ty * 2;
    const int c0loc = tx * 4;
    const int c0 = cbase + c0loc;
    const float4 bv = *(const float4*)&bias[c0];

#pragma unroll
    for (int i = 0; i < 2; ++i) {
        const size_t off = (size_t)(r0 + i) * N_H + c0;
        const float4 mp = *(const float4*)&mem[off];
        float4 mn, sp;
        { float cur = acc[i][0] + bv.x;
          mn.x = 0.9f * mp.x + cur - ((mp.x > 1.0f) ? 1.0f : 0.0f);
          sp.x = (mn.x > 1.0f) ? 1.0f : 0.0f; }
        { float cur = acc[i][1] + bv.y;
          mn.y = 0.9f * mp.y + cur - ((mp.y > 1.0f) ? 1.0f : 0.0f);
          sp.y = (mn.y > 1.0f) ? 1.0f : 0.0f; }
        { float cur = acc[i][2] + bv.z;
          mn.z = 0.9f * mp.z + cur - ((mp.z > 1.0f) ? 1.0f : 0.0f);
          sp.z = (mn.z > 1.0f) ? 1.0f : 0.0f; }
        { float cur = acc[i][3] + bv.w;
          mn.w = 0.9f * mp.w + cur - ((mp.w > 1.0f) ? 1.0f : 0.0f);
          sp.w = (mn.w > 1.0f) ? 1.0f : 0.0f; }
        *(float4*)&mem[off] = mn;
        if constexpr (!PACK_BITS) {
            *(float4*)&s_f32[off] = sp;
        } else {
            us[ty * 2 + i][c0loc + 0] = (uint8_t)sp.x;
            us[ty * 2 + i][c0loc + 1] = (uint8_t)sp.y;
            us[ty * 2 + i][c0loc + 2] = (uint8_t)sp.z;
            us[ty * 2 + i][c0loc + 3] = (uint8_t)sp.w;
        }
    }

    if constexpr (PACK_BITS) {
        __syncthreads();
        if (tid < 128) {
            const int r = tid >> 1;
            const int w = tid & 1;
            uint32_t bits = 0;
#pragma unroll
            for (int b = 0; b < 32; ++b)
                bits |= ((uint32_t)us[r][w * 32 + b]) << b;
            s_bits[(size_t)(abase + r) * 128 + (cbase >> 5) + w] = bits;
        }
    }
}

__global__ __launch_bounds__(256)
void gemm3_bits(const uint32_t* __restrict__ s_bits, const float* __restrict__ W3,
                float* __restrict__ part)
{
    __shared__ float Asf[32][68];
    __shared__ float Wsf[32][68];

    const int tid = threadIdx.x;
    const int rowbase = blockIdx.x * 64;
    const int ks = blockIdx.y;
    const int tx = tid & 15;
    const int ty = tid >> 4;

    float acc[4][4];
#pragma unroll
    for (int i = 0; i < 4; ++i)
#pragma unroll
        for (int j = 0; j < 4; ++j) acc[i][j] = 0.f;

    const int r  = tid & 63;
    const int q  = tid >> 6;
    const int wr = tid >> 3;
    const int wg = tid & 7;

    for (int c = 0; c < 32; ++c) {
        const int k0 = ks * 1024 + c * 32;
        const uint32_t word = s_bits[(size_t)(rowbase + r) * 128 + (k0 >> 5)];
        const float4 wv0 = *(const float4*)&W3[(size_t)wr * 4096 + k0 + wg * 4];
        const float4 wv1 = *(const float4*)&W3[(size_t)(wr + 32) * 4096 + k0 + wg * 4];
        __syncthreads();
#pragma unroll
        for (int u = 0; u < 8; ++u)
            Asf[q * 8 + u][r] = (float)((word >> (q * 8 + u)) & 1u);
        Wsf[wg * 4 + 0][wr] = wv0.x;
        Wsf[wg * 4 + 1][wr] = wv0.y;
        Wsf[wg * 4 + 2][wr] = wv0.z;
        Wsf[wg * 4 + 3][wr] = wv0.w;
        Wsf[wg * 4 + 0][wr + 32] = wv1.x;
        Wsf[wg * 4 + 1][wr + 32] = wv1.y;
        Wsf[wg * 4 + 2][wr + 32] = wv1.z;
        Wsf[wg * 4 + 3][wr + 32] = wv1.w;
        __syncthreads();
#pragma unroll
        for (int kk = 0; kk < 32; ++kk) {
            const float4 a4 = *(const float4*)&Asf[kk][ty * 4];
            const float4 b4 = *(const float4*)&Wsf[kk][tx * 4];
            acc[0][0] += a4.x * b4.x; acc[0][1] += a4.x * b4.y;
            acc[0][2] += a4.x * b4.z; acc[0][3] += a4.x * b4.w;
            acc[1][0] += a4.y * b4.x; acc[1][1] += a4.y * b4.y;
            acc[1][2] += a4.y * b4.z; acc[1][3] += a4.y * b4.w;
            acc[2][0] += a4.z * b4.x; acc[2][1] += a4.z * b4.y;
            acc[2][2] += a4.z * b4.z; acc[2][3] += a4.z * b4.w;
            acc[3][0] += a4.w * b4.x; acc[3][1] += a4.w * b4.y;
            acc[3][2] += a4.w * b4.z; acc[3][3] += a4.w * b4.w;
        }
    }
#pragma unroll
    for (int i = 0; i < 4; ++i) {
        float4 v = make_float4(acc[i][0], acc[i][1], acc[i][2], acc[i][3]);
        *(float4*)&part[((size_t)ks * 12800 + rowbase + ty * 4 + i) * 64 + tx * 4] = v;
    }
}

// ---------------------------------------------------------------------------
extern "C" void kernel_launch(void* const* d_in, const int* in_sizes, int n_in,
                              void* d_out, int out_size, void* d_ws, size_t ws_size,
                              hipStream_t stream)
{
    const float* x  = (const float*)d_in[0];
    const float* W1 = (const float*)d_in[1];
    const float* b1 = (const float*)d_in[2];
    const float* W2 = (const float*)d_in[3];
    const float* b2 = (const float*)d_in[4];
    const float* W3 = (const float*)d_in[5];
    const float* b3 = (const float*)d_in[6];

    char* ws = (char*)d_ws;

    // layout (bytes):
    const size_t oW1p = 0;              //  18,874,368  W1 planes i8
    const size_t oW2p = 18874368;       //  50,331,648  W2 planes i8
    const size_t oW3p = 69206016;       //     786,432  W3 planes i8
    const size_t oXi8 = 69992448;       //  19,660,800  input spikes i8
    const size_t oS1  = 89653248;       //  26,214,400  s1 (one 25-step chunk)
    const size_t oS2  = 115867648;      //  52,428,800  s2 (all 50 steps)
    const size_t oM1  = 168296448;      //   4,194,304  m1 carry
    const size_t oM2  = 172490752;      //   4,194,304  m2 carry (contig w/ m1)
    const size_t oCur = 176685056;      // 104,857,600  cur1/cur2 shared; part3 alias
    const size_t NEED = 281542656;

    const double bnd1 = 1.0 / sqrt(1536.0);
    const double bnd2 = 1.0 / 64.0;
    const double bnd3 = 1.0 / 64.0;
    const float inv1 = (float)((double)DEN / bnd1), sb1 = (float)(bnd1 / (double)DEN);
    const float inv2 = (float)((double)DEN / bnd2), sb2 = (float)(bnd2 / (double)DEN);
    const float inv3 = (float)((double)DEN / bnd3), sb3 = (float)(bnd3 / (double)DEN);

    if (ws_size >= NEED) {
        char*  W1p  = ws + oW1p;
        char*  W2p  = ws + oW2p;
        char*  W3p  = ws + oW3p;
        char*  xi8  = ws + oXi8;
        char*  s1   = ws + oS1;
        char*  s2   = ws + oS2;
        float* m1   = (float*)(ws + oM1);
        float* m2   = (float*)(ws + oM2);
        float* cur  = (float*)(ws + oCur);
        float* part3 = cur;   // reuse after lif2_scan of chunk 1

        split3_i8<<<6144, 256, 0, stream>>>((const float4*)W1, W1p,
                                            (size_t)4096 * 1536, inv1);
        split3_i8<<<16384, 256, 0, stream>>>((const float4*)W2, W2p,
                                             (size_t)4096 * 4096, inv2);
        split3_i8<<<256, 256, 0, stream>>>((const float4*)W3, W3p,
                                           (size_t)64 * 4096, inv3);
        xcvt_i8<<<19200, 256, 0, stream>>>((const float4*)x, (uint32_t*)xi8);
        zero_ws<<<2048, 256, 0, stream>>>((float4*)m1);   // m1 + m2 contiguous

        const size_t chunk_rows = (size_t)25 * BATCH;     // 6400
        for (int chunk = 0; chunk < 2; ++chunk) {
            gemm_planes_bd2<1536><<<800, 512, 0, stream>>>(
                xi8 + chunk * chunk_rows * 1536, W1p, cur, sb1);
            lif_scan<<<1024, 256, 0, stream>>>(cur, b1, m1, s1);
            gemm_planes_bd2<4096><<<800, 512, 0, stream>>>(s1, W2p, cur, sb2);
            lif_scan<<<1024, 256, 0, stream>>>(cur, b2, m2,
                                               s2 + chunk * chunk_rows * N_H);
        }
        gemm3_i8<<<dim3(100, 6), 256, 0, stream>>>(s2, W3p, part3, sb3);
        lif3_scan<6><<<64, 256, 0, stream>>>(part3, b3, (float*)d_out);
    } else {
        float*    m1     = (float*)(ws);
        float*    m2     = (float*)(ws + (size_t)4 * 1024 * 1024);
        float*    s1f    = (float*)(ws + (size_t)8 * 1024 * 1024);
        uint32_t* s2bits = (uint32_t*)(ws + (size_t)12 * 1024 * 1024);
        float*    part   = (float*)(ws + (size_t)20 * 1024 * 1024);

        zero_ws<<<2048, 256, 0, stream>>>((float4*)m1);
        for (int t = 0; t < T_STEPS; ++t) {
            gemm_lif<1536, false><<<dim3(64, 4), 512, 0, stream>>>(
                x + (size_t)t * BATCH * 1536, W1, b1, m1, s1f, nullptr);
            gemm_lif<4096, true><<<dim3(64, 4), 512, 0, stream>>>(
                s1f, W2, b2, m2, nullptr, s2bits + (size_t)t * BATCH * 128);
        }
        gemm3_bits<<<dim3(200, 4), 256, 0, stream>>>(s2bits, W3, part);
        lif3_scan<4><<<64, 256, 0, stream>>>(part, b3, (float*)d_out);
    }
}

// Round 7
// 2902.789 us; speedup vs baseline: 2.2412x; 1.0024x over previous
//
#include <hip/hip_runtime.h>
#include <stdint.h>
#include <stddef.h>
#include <math.h>

// ContextSNN round 15: resubmit of r14 (container-level infra failure, no
// kernel verdict). r14 = r13 B-direct pipeline with the register cap fixed:
// empirically (r11/r12/r13) VGPR cap = 256/(launch_bounds 2nd arg) for
// 512-thread blocks (observed 64/128/128); pipeline needs ~230 regs ->
// __launch_bounds__(512, 1) for the full 256. Occupancy 1 block/CU,
// 2 waves/SIMD == proven r10 ring. Pipeline: A 4-slot LDS ring staged 3
// ahead via global_load_lds; B direct global->reg, 3-deep rotation, 2-body
// lookahead; body-top s_waitcnt vmcnt(6) (= prev body's 4 B + 2 A issues)
// BEFORE the barrier; never drains mid-loop. Exact i32 plane fold unchanged.

#define T_STEPS 50
#define BATCH   256
#define N_H     4096
#define DEN     8355711   // 127*65536 + 127*256 + 127

typedef unsigned short u16;
typedef __attribute__((ext_vector_type(4))) int i32x4;
typedef __attribute__((ext_vector_type(4))) float f32x4;

#define GLL16(gp, lp) __builtin_amdgcn_global_load_lds( \
    (const __attribute__((address_space(1))) void*)(gp), \
    (__attribute__((address_space(3))) void*)(lp), 16, 0, 0)

// ---------------------------------------------------------------------------
// prep
// ---------------------------------------------------------------------------
__global__ __launch_bounds__(256) void zero_ws(float4* __restrict__ p) {
    p[(size_t)blockIdx.x * 256 + threadIdx.x] = make_float4(0.f, 0.f, 0.f, 0.f);
}

__device__ inline void digits3(float w, float inv_s, int& h, int& m, int& l) {
    int V = (int)rintf(w * inv_s);
    V = min(max(V, -DEN), DEN);
    l = ((V + 128) & 255) - 128;
    const int V2 = (V - l) >> 8;
    m = ((V2 + 128) & 255) - 128;
    h = (V2 - m) >> 8;
}

__global__ __launch_bounds__(256)
void split3_i8(const float4* __restrict__ W, char* __restrict__ P,
               size_t plane_elems, float inv_s)
{
    const size_t i = (size_t)blockIdx.x * 256 + threadIdx.x;
    const float4 w = W[i];
    int h0,m0,l0,h1,m1,l1,h2,m2,l2,h3,m3,l3;
    digits3(w.x, inv_s, h0, m0, l0);
    digits3(w.y, inv_s, h1, m1, l1);
    digits3(w.z, inv_s, h2, m2, l2);
    digits3(w.w, inv_s, h3, m3, l3);
    const uint32_t ph = (uint32_t)(uint8_t)h0 | ((uint32_t)(uint8_t)h1 << 8) |
                        ((uint32_t)(uint8_t)h2 << 16) | ((uint32_t)(uint8_t)h3 << 24);
    const uint32_t pm = (uint32_t)(uint8_t)m0 | ((uint32_t)(uint8_t)m1 << 8) |
                        ((uint32_t)(uint8_t)m2 << 16) | ((uint32_t)(uint8_t)m3 << 24);
    const uint32_t pl = (uint32_t)(uint8_t)l0 | ((uint32_t)(uint8_t)l1 << 8) |
                        ((uint32_t)(uint8_t)l2 << 16) | ((uint32_t)(uint8_t)l3 << 24);
    *(uint32_t*)&P[4 * i]                   = ph;
    *(uint32_t*)&P[plane_elems + 4 * i]     = pm;
    *(uint32_t*)&P[2 * plane_elems + 4 * i] = pl;
}

__global__ __launch_bounds__(256)
void xcvt_i8(const float4* __restrict__ in, uint32_t* __restrict__ out) {
    const size_t i = (size_t)blockIdx.x * 256 + threadIdx.x;
    const float4 v = in[i];
    out[i] = (uint32_t)(v.x > 0.5f) | ((uint32_t)(v.y > 0.5f) << 8) |
             ((uint32_t)(v.z > 0.5f) << 16) | ((uint32_t)(v.w > 0.5f) << 24);
}

// ---------------------------------------------------------------------------
// B-direct batched 3-plane i8 GEMM (r13 pipeline, 256-reg budget).
// A[6400][K] x Wp[3][4096][K]^T -> cur[6400][4096].
// BM=256, BN=128, BK=64. 512 thr = 8 waves (4M x 2N); per-wave 64x64.
// Grid 800 = 25 row-blocks x 32 col-blocks (XCD swizzle on cols).
// ---------------------------------------------------------------------------
template<int K>
__global__ __launch_bounds__(512, 1)
void gemm_planes_bd2(const char* __restrict__ A, const char* __restrict__ Wp,
                     float* __restrict__ cur, float s_base)
{
    const int ITERS = 3 * K / 64;     // 192 (K=4096) / 72 (K=1536); %12 == 0
    __shared__ char As[4][16384];     // 64 KiB static

    const int tid  = threadIdx.x;
    const int wave = tid >> 6, lane = tid & 63;
    const int wr = wave >> 1, wc = wave & 1;

    const int bid   = blockIdx.x;
    const int cbase = (((bid & 7) << 2) + ((bid >> 3) & 3)) * 128;
    const int abase = (bid >> 5) * 256;

    i32x4 acc[4][4];
    f32x4 facc[4][4];
#pragma unroll
    for (int i = 0; i < 4; ++i)
#pragma unroll
        for (int j = 0; j < 4; ++j) { acc[i][j] = (i32x4)(0); facc[i][j] = (f32x4)(0.f); }

    // A staging map (verified r10): 2 x GLL16 per thread per tile (16 KB).
    const int soff = tid * 16;               // 0..8191
    const int rs   = soff >> 6;              // row 0..127
    const int cs   = (soff >> 4) & 3;        // 16B chunk in row
    const int kbs  = ((cs ^ ((rs >> 1) & 3)) << 4);   // XOR bank swizzle
    const size_t aoff0 = (size_t)(abase + rs) * K + kbs;
    const size_t aoff1 = aoff0 + (size_t)128 * K;
    const int dstA0 = wave * 1024;
    const int dstA1 = 8192 + wave * 1024;

    // A-frag read offsets (verified r9/r10)
    const int rlo = lane & 15, rhi = lane >> 4;
    const int qr  = (rlo >> 1) & 3;
    const int rdA = (wr * 64 + rlo) * 64 + ((rhi ^ qr) << 4);

    // B-frag direct-global byte offsets (verified r12/r13):
    // frag j: W[cbase + wc*64 + j*16 + rlo][kn + rhi*16 .. +15]
    const size_t bb0 = (size_t)(cbase + wc * 64 +  0 + rlo) * K + rhi * 16;
    const size_t bb1 = (size_t)(cbase + wc * 64 + 16 + rlo) * K + rhi * 16;
    const size_t bb2 = (size_t)(cbase + wc * 64 + 32 + rlo) * K + rhi * 16;
    const size_t bb3 = (size_t)(cbase + wc * 64 + 48 + rlo) * K + rhi * 16;

#define LOADB(u, BV)                                                          \
    {                                                                         \
        const int pn_ = ((u) * 64) / K;                                       \
        const int kn_ = (u) * 64 - pn_ * K;                                   \
        const char* bk_ = Wp + (size_t)pn_ * ((size_t)N_H * K) + kn_;         \
        BV[0] = *(const i32x4*)(bk_ + bb0);                                   \
        BV[1] = *(const i32x4*)(bk_ + bb1);                                   \
        BV[2] = *(const i32x4*)(bk_ + bb2);                                   \
        BV[3] = *(const i32x4*)(bk_ + bb3);                                   \
    }

#define STAGEA(u, SS)                                                         \
    {                                                                         \
        const int pn_ = ((u) * 64) / K;                                       \
        const int kn_ = (u) * 64 - pn_ * K;                                   \
        const char* ak_ = A + kn_;                                            \
        GLL16(ak_ + aoff0, &As[SS][0] + dstA0);                               \
        GLL16(ak_ + aoff1, &As[SS][0] + dstA1);                               \
    }

#define READA(SN, AV)                                                         \
    {                                                                         \
        const char* nb_ = &As[SN][0];                                         \
        _Pragma("unroll")                                                     \
        for (int i = 0; i < 4; ++i)                                           \
            AV[i] = *(const i32x4*)(nb_ + rdA + i * 1024);                    \
    }

#define FOLD(tt)                                                              \
    if (((((tt) + 1) * 64) % K) == 0) {                                       \
        const int p_ = ((tt) * 64) / K;                                       \
        const float sc_ = s_base * (float)(65536 >> (8 * p_));                \
        _Pragma("unroll")                                                     \
        for (int i = 0; i < 4; ++i)                                           \
            _Pragma("unroll")                                                 \
            for (int j = 0; j < 4; ++j) {                                     \
                _Pragma("unroll")                                             \
                for (int r = 0; r < 4; ++r)                                   \
                    facc[i][j][r] += sc_ * (float)acc[i][j][r];               \
                acc[i][j] = (i32x4)(0);                                       \
            }                                                                 \
    }

// BODY(tt, NW, AVC, AVN, BVC, BVL, SN, SS, GB, GS, GR):
//   wait vmcnt(NW) [== loads issued in body tt-1]; barrier;
//   GB: load B(tt+2) -> BVL; GS: stage A(tt+3) -> slot SS;
//   GR: ds_read A-frags(tt+1) from slot SN -> AVN; MFMA(tt) AVC x BVC; fold.
#define BODY(tt, NW, AVC, AVN, BVC, BVL, SN, SS, GB, GS, GR)                  \
    {                                                                         \
        asm volatile("s_waitcnt vmcnt(" #NW ")" ::: "memory");                \
        __builtin_amdgcn_s_barrier();                                         \
        asm volatile("" ::: "memory");                                        \
        if (GB) LOADB((tt) + 2, BVL);                                         \
        if (GS) STAGEA((tt) + 3, SS);                                         \
        if (GR) READA(SN, AVN);                                               \
        __builtin_amdgcn_s_setprio(1);                                        \
        _Pragma("unroll")                                                     \
        for (int i = 0; i < 4; ++i)                                           \
            _Pragma("unroll")                                                 \
            for (int j = 0; j < 4; ++j)                                       \
                acc[i][j] = __builtin_amdgcn_mfma_i32_16x16x64_i8(            \
                    AVC[i], BVC[j], acc[i][j], 0, 0, 0);                      \
        __builtin_amdgcn_s_setprio(0);                                        \
        FOLD(tt);                                                             \
    }

    i32x4 av0[4], av1[4], bv0[4], bv1[4], bv2[4];

    // prologue: B(0), B(1); stage tiles 0,1,2. vmcnt(4) leaves stage(1,2)
    // in flight (stage(0)+B retired on every wave before barrier).
    LOADB(0, bv0);
    LOADB(1, bv1);
    STAGEA(0, 0); STAGEA(1, 1); STAGEA(2, 2);
    asm volatile("s_waitcnt vmcnt(4)" ::: "memory");
    __builtin_amdgcn_s_barrier();
    asm volatile("" ::: "memory");
    READA(0, av0);

    // body 0 (t=0): prologue left 4 in flight after stage(1),stage(2);
    // wait to 2 (retire stage(1)) before reading slot 1.
    BODY(0, 2, av0, av1, bv0, bv2, 1, 3, 1, 1, 1);

    // main loop: t = 1 + 12k; all rotation residues fixed (12 = lcm(2,3,4)).
    // Steady NW = 6 (= 4 B + 2 stage issued in previous body).
    int t = 1;
    for (; t + 11 < ITERS - 3; t += 12) {
        BODY(t + 0,  6, av1, av0, bv1, bv0, 2, 0, 1, 1, 1);
        BODY(t + 1,  6, av0, av1, bv2, bv1, 3, 1, 1, 1, 1);
        BODY(t + 2,  6, av1, av0, bv0, bv2, 0, 2, 1, 1, 1);
        BODY(t + 3,  6, av0, av1, bv1, bv0, 1, 3, 1, 1, 1);
        BODY(t + 4,  6, av1, av0, bv2, bv1, 2, 0, 1, 1, 1);
        BODY(t + 5,  6, av0, av1, bv0, bv2, 3, 1, 1, 1, 1);
        BODY(t + 6,  6, av1, av0, bv1, bv0, 0, 2, 1, 1, 1);
        BODY(t + 7,  6, av0, av1, bv2, bv1, 1, 3, 1, 1, 1);
        BODY(t + 8,  6, av1, av0, bv0, bv2, 2, 0, 1, 1, 1);
        BODY(t + 9,  6, av0, av1, bv1, bv0, 3, 1, 1, 1, 1);
        BODY(t + 10, 6, av1, av0, bv2, bv1, 0, 2, 1, 1, 1);
        BODY(t + 11, 6, av0, av1, bv0, bv2, 1, 3, 1, 1, 1);
    }

    // tail: 11 bodies, t = ITERS-11 .. ITERS-1 (same residues as main).
    BODY(t + 0,  6, av1, av0, bv1, bv0, 2, 0, 1, 1, 1);
    BODY(t + 1,  6, av0, av1, bv2, bv1, 3, 1, 1, 1, 1);
    BODY(t + 2,  6, av1, av0, bv0, bv2, 0, 2, 1, 1, 1);
    BODY(t + 3,  6, av0, av1, bv1, bv0, 1, 3, 1, 1, 1);
    BODY(t + 4,  6, av1, av0, bv2, bv1, 2, 0, 1, 1, 1);
    BODY(t + 5,  6, av0, av1, bv0, bv2, 3, 1, 1, 1, 1);
    BODY(t + 6,  6, av1, av0, bv1, bv0, 0, 2, 1, 1, 1);
    BODY(t + 7,  6, av0, av1, bv2, bv1, 1, 3, 1, 1, 1);
    BODY(t + 8,  6, av1, av0, bv0, bv2, 2, 0, 1, 0, 1);
    BODY(t + 9,  4, av0, av1, bv1, bv0, 3, 1, 0, 0, 1);
    BODY(t + 10, 0, av1, av0, bv2, bv1, 0, 2, 0, 0, 0);

#undef BODY
#undef FOLD
#undef READA
#undef STAGEA
#undef LOADB

    const int orow = abase + wr * 64 + rhi * 4;
    const int ocol = cbase + wc * 64 + rlo;
#pragma unroll
    for (int i = 0; i < 4; ++i)
#pragma unroll
        for (int j = 0; j < 4; ++j)
#pragma unroll
            for (int r = 0; r < 4; ++r)
                cur[(size_t)(orow + i * 16 + r) * N_H + ocol + j * 16] = facc[i][j][r];
}

// ---------------------------------------------------------------------------
// layer-3 i8 GEMM, double-buffered (unchanged, small)
// ---------------------------------------------------------------------------
__global__ __launch_bounds__(256, 2)
void gemm3_i8(const char* __restrict__ A, const char* __restrict__ W3p,
              float* __restrict__ part3, float s_base)
{
    __shared__ char As[2 * 8192];
    __shared__ char Bs[2 * 4096];

    const int tid  = threadIdx.x;
    const int wave = tid >> 6, lane = tid & 63;
    const int wm = wave >> 1, wn = wave & 1;

    const int rowbase = blockIdx.x * 128;
    const int z = blockIdx.y;
    const int p = z >> 1;
    const int kstart = (z & 1) * 2048;

    i32x4 acc[4][2];
#pragma unroll
    for (int i = 0; i < 4; ++i)
#pragma unroll
        for (int j = 0; j < 2; ++j) acc[i][j] = (i32x4)(0);

    const int soff0 = wave * 2048 + lane * 16;
    const int soff1 = soff0 + 1024;
    const int r0 = soff0 >> 6, r1 = soff1 >> 6;
    const int kb0 = ((((soff0 >> 4) & 3) ^ ((r0 >> 1) & 3)) << 4);
    const int kb1 = ((((soff1 >> 4) & 3) ^ ((r1 >> 1) & 3)) << 4);
    const int soffB = tid * 16;
    const int rB = soffB >> 6;
    const int kbB = ((((soffB >> 4) & 3) ^ ((rB >> 1) & 3)) << 4);

    const size_t aoff0 = (size_t)(rowbase + r0) * 4096 + kb0;
    const size_t aoff1 = (size_t)(rowbase + r1) * 4096 + kb1;
    const size_t boff  = (size_t)rB * 4096 + kbB;

    const char* Bp = W3p + (size_t)p * 64 * 4096;
    const int sbase = wave * 2048;
    const int sbaseB = wave * 1024;

    const int rlo = lane & 15, rhi = lane >> 4;
    const int qr = (rlo >> 1) & 3;
    const int rdA = (wm * 64 + rlo) * 64 + ((rhi ^ qr) << 4);
    const int rdB = (wn * 32 + rlo) * 64 + ((rhi ^ qr) << 4);

    {
        GLL16(A + kstart + aoff0, As + sbase);
        GLL16(A + kstart + aoff1, As + sbase + 1024);
        GLL16(Bp + kstart + boff, Bs + sbaseB);
    }
    __syncthreads();

    for (int it = 0; it < 32; ++it) {
        const int bufA = (it & 1) * 8192;
        const int bufB = (it & 1) * 4096;
        if (it + 1 < 32) {
            const int kn = kstart + (it + 1) * 64;
            GLL16(A + kn + aoff0, As + (8192 - bufA) + sbase);
            GLL16(A + kn + aoff1, As + (8192 - bufA) + sbase + 1024);
            GLL16(Bp + kn + boff, Bs + (4096 - bufB) + sbaseB);
        }

        const char* pAf = As + bufA + rdA;
        const char* pBf = Bs + bufB + rdB;
        i32x4 av[4], bv[2];
#pragma unroll
        for (int i = 0; i < 4; ++i) av[i] = *(const i32x4*)(pAf + i * 1024);
#pragma unroll
        for (int j = 0; j < 2; ++j) bv[j] = *(const i32x4*)(pBf + j * 1024);
#pragma unroll
        for (int i = 0; i < 4; ++i)
#pragma unroll
            for (int j = 0; j < 2; ++j)
                acc[i][j] = __builtin_amdgcn_mfma_i32_16x16x64_i8(
                    av[i], bv[j], acc[i][j], 0, 0, 0);
        __syncthreads();
    }

    const float sc = s_base * (float)(65536 >> (8 * p));
    float* pout = part3 + (size_t)z * (12800 * 64);
    const int orow = rowbase + wm * 64 + rhi * 4;
    const int ocol = wn * 32 + rlo;
#pragma unroll
    for (int i = 0; i < 4; ++i)
#pragma unroll
        for (int j = 0; j < 2; ++j)
#pragma unroll
            for (int r = 0; r < 4; ++r)
                pout[(size_t)(orow + i * 16 + r) * 64 + ocol + j * 16] =
                    (float)acc[i][j][r] * sc;
}

// ---------------------------------------------------------------------------
// elementwise LIF time-scan over 25 steps (one chunk)
// ---------------------------------------------------------------------------
__global__ __launch_bounds__(256)
void lif_scan(const float* __restrict__ cur, const float* __restrict__ bias,
              float* __restrict__ mem, char* __restrict__ sout)
{
    const int i4  = blockIdx.x * 256 + threadIdx.x;   // 0..262143
    const int col = (i4 << 2) & (N_H - 1);
    const int b   = i4 >> 10;
    const float4 bv = *(const float4*)&bias[col];
    const size_t mbase = (size_t)b * N_H + col;
    float4 m = *(const float4*)&mem[mbase];

    for (int t = 0; t < 25; ++t) {
        const size_t off = ((size_t)t * BATCH + b) * N_H + col;
        const float4 cv = *(const float4*)&cur[off];
        float4 mn;
        { const float c = cv.x + bv.x;
          mn.x = 0.9f * m.x + c - ((m.x > 1.0f) ? 1.0f : 0.0f); }
        { const float c = cv.y + bv.y;
          mn.y = 0.9f * m.y + c - ((m.y > 1.0f) ? 1.0f : 0.0f); }
        { const float c = cv.z + bv.z;
          mn.z = 0.9f * m.z + c - ((m.z > 1.0f) ? 1.0f : 0.0f); }
        { const float c = cv.w + bv.w;
          mn.w = 0.9f * m.w + c - ((m.w > 1.0f) ? 1.0f : 0.0f); }
        const uint32_t sp = (uint32_t)(mn.x > 1.0f) | ((uint32_t)(mn.y > 1.0f) << 8) |
                            ((uint32_t)(mn.z > 1.0f) << 16) | ((uint32_t)(mn.w > 1.0f) << 24);
        *(uint32_t*)&sout[off] = sp;
        m = mn;
    }
    *(float4*)&mem[mbase] = m;
}

template<int NG>
__global__ __launch_bounds__(256)
void lif3_scan(const float* __restrict__ part, const float* __restrict__ b3,
               float* __restrict__ out)
{
    const int g = blockIdx.x * 256 + threadIdx.x;
    const int j = g & 63;
    const int b = g >> 6;
    const float bj = b3[j];
    float m = 0.f, accum = 0.f;
    for (int t = 0; t < T_STEPS; ++t) {
        const size_t row = (size_t)t * 256 + b;
        float cur = bj;
#pragma unroll
        for (int q = 0; q < NG; ++q)
            cur += part[(size_t)q * (12800 * 64) + row * 64 + j];
        const float reset = (m > 1.0f) ? 1.0f : 0.0f;
        m = 0.9f * m + cur - reset;
        accum += (m > 1.0f) ? 1.0f : 0.0f;
    }
    out[g] = accum;
}

// ---------------------------------------------------------------------------
// fp32 fallback path (round 1) — used only if ws_size too small
// ---------------------------------------------------------------------------
template<int K, bool PACK_BITS>
__global__ __launch_bounds__(512)
void gemm_lif(const float* __restrict__ A, const float* __restrict__ W,
              const float* __restrict__ bias, float* __restrict__ mem,
              float* __restrict__ s_f32, uint32_t* __restrict__ s_bits)
{
    __shared__ float Asf[32][68];
    __shared__ float Wsf[32][68];
    __shared__ uint8_t us[64][64];

    const int tid = threadIdx.x;
    const int abase = blockIdx.y * 64;
    const int cbase = blockIdx.x * 64;
    const int tx = tid & 15;
    const int ty = tid >> 4;

    float acc[2][4];
#pragma unroll
    for (int i = 0; i < 2; ++i)
#pragma unroll
        for (int j = 0; j < 4; ++j) acc[i][j] = 0.f;

    const int lrow = tid >> 3;
    const int lg = tid & 7;

    for (int k0 = 0; k0 < K; k0 += 32) {
        const float4 av = *(const float4*)&A[(size_t)(abase + lrow) * K + k0 + lg * 4];
        const float4 wv = *(const float4*)&W[(size_t)(cbase + lrow) * K + k0 + lg * 4];
        __syncthreads();
        Asf[lg * 4 + 0][lrow] = av.x; Asf[lg * 4 + 1][lrow] = av.y;
        Asf[lg * 4 + 2][lrow] = av.z; Asf[lg * 4 + 3][lrow] = av.w;
        Wsf[lg * 4 + 0][lrow] = wv.x; Wsf[lg * 4 + 1][lrow] = wv.y;
        Wsf[lg * 4 + 2][lrow] = wv.z; Wsf[lg * 4 + 3][lrow] = wv.w;
        __syncthreads();
#pragma unroll
        for (int kk = 0; kk < 32; ++kk) {
            const float2 a2 = *(const float2*)&Asf[kk][ty * 2];
            const float4 b4 = *(const float4*)&Wsf[kk][tx * 4];
            acc[0][0] += a2.x * b4.x; acc[0][1] += a2.x * b4.y;
            acc[0][2] += a2.x * b4.z; acc[0][3] += a2.x * b4.w;
            acc[1][0] += a2.y * b4.x; acc[1][1] += a2.y * b4.y;
            acc[1][2] += a2.y * b4.z; acc[1][3] += a2.y * b4.w;
        }
    }

    const int r0 = abase + ty * 2;
    const int c0loc = tx * 4;
    const int c0 = cbase + c0loc;
    const float4 bv = *(const float4*)&bias[c0];

#pragma unroll
    for (int i = 0; i < 2; ++i) {
        const size_t off = (size_t)(r0 + i) * N_H + c0;
        const float4 mp = *(const float4*)&mem[off];
        float4 mn, sp;
        { float cur = acc[i][0] + bv.x;
          mn.x = 0.9f * mp.x + cur - ((mp.x > 1.0f) ? 1.0f : 0.0f);
          sp.x = (mn.x > 1.0f) ? 1.0f : 0.0f; }
        { float cur = acc[i][1] + bv.y;
          mn.y = 0.9f * mp.y + cur - ((mp.y > 1.0f) ? 1.0f : 0.0f);
          sp.y = (mn.y > 1.0f) ? 1.0f : 0.0f; }
        { float cur = acc[i][2] + bv.z;
          mn.z = 0.9f * mp.z + cur - ((mp.z > 1.0f) ? 1.0f : 0.0f);
          sp.z = (mn.z > 1.0f) ? 1.0f : 0.0f; }
        { float cur = acc[i][3] + bv.w;
          mn.w = 0.9f * mp.w + cur - ((mp.w > 1.0f) ? 1.0f : 0.0f);
          sp.w = (mn.w > 1.0f) ? 1.0f : 0.0f; }
        *(float4*)&mem[off] = mn;
        if constexpr (!PACK_BITS) {
            *(float4*)&s_f32[off] = sp;
        } else {
            us[ty * 2 + i][c0loc + 0] = (uint8_t)sp.x;
            us[ty * 2 + i][c0loc + 1] = (uint8_t)sp.y;
            us[ty * 2 + i][c0loc + 2] = (uint8_t)sp.z;
            us[ty * 2 + i][c0loc + 3] = (uint8_t)sp.w;
        }
    }

    if constexpr (PACK_BITS) {
        __syncthreads();
        if (tid < 128) {
            const int r = tid >> 1;
            const int w = tid & 1;
            uint32_t bits = 0;
#pragma unroll
            for (int b = 0; b < 32; ++b)
                bits |= ((uint32_t)us[r][w * 32 + b]) << b;
            s_bits[(size_t)(abase + r) * 128 + (cbase >> 5) + w] = bits;
        }
    }
}

__global__ __launch_bounds__(256)
void gemm3_bits(const uint32_t* __restrict__ s_bits, const float* __restrict__ W3,
                float* __restrict__ part)
{
    __shared__ float Asf[32][68];
    __shared__ float Wsf[32][68];

    const int tid = threadIdx.x;
    const int rowbase = blockIdx.x * 64;
    const int ks = blockIdx.y;
    const int tx = tid & 15;
    const int ty = tid >> 4;

    float acc[4][4];
#pragma unroll
    for (int i = 0; i < 4; ++i)
#pragma unroll
        for (int j = 0; j < 4; ++j) acc[i][j] = 0.f;

    const int r  = tid & 63;
    const int q  = tid >> 6;
    const int wr = tid >> 3;
    const int wg = tid & 7;

    for (int c = 0; c < 32; ++c) {
        const int k0 = ks * 1024 + c * 32;
        const uint32_t word = s_bits[(size_t)(rowbase + r) * 128 + (k0 >> 5)];
        const float4 wv0 = *(const float4*)&W3[(size_t)wr * 4096 + k0 + wg * 4];
        const float4 wv1 = *(const float4*)&W3[(size_t)(wr + 32) * 4096 + k0 + wg * 4];
        __syncthreads();
#pragma unroll
        for (int u = 0; u < 8; ++u)
            Asf[q * 8 + u][r] = (float)((word >> (q * 8 + u)) & 1u);
        Wsf[wg * 4 + 0][wr] = wv0.x;
        Wsf[wg * 4 + 1][wr] = wv0.y;
        Wsf[wg * 4 + 2][wr] = wv0.z;
        Wsf[wg * 4 + 3][wr] = wv0.w;
        Wsf[wg * 4 + 0][wr + 32] = wv1.x;
        Wsf[wg * 4 + 1][wr + 32] = wv1.y;
        Wsf[wg * 4 + 2][wr + 32] = wv1.z;
        Wsf[wg * 4 + 3][wr + 32] = wv1.w;
        __syncthreads();
#pragma unroll
        for (int kk = 0; kk < 32; ++kk) {
            const float4 a4 = *(const float4*)&Asf[kk][ty * 4];
            const float4 b4 = *(const float4*)&Wsf[kk][tx * 4];
            acc[0][0] += a4.x * b4.x; acc[0][1] += a4.x * b4.y;
            acc[0][2] += a4.x * b4.z; acc[0][3] += a4.x * b4.w;
            acc[1][0] += a4.y * b4.x; acc[1][1] += a4.y * b4.y;
            acc[1][2] += a4.y * b4.z; acc[1][3] += a4.y * b4.w;
            acc[2][0] += a4.z * b4.x; acc[2][1] += a4.z * b4.y;
            acc[2][2] += a4.z * b4.z; acc[2][3] += a4.z * b4.w;
            acc[3][0] += a4.w * b4.x; acc[3][1] += a4.w * b4.y;
            acc[3][2] += a4.w * b4.z; acc[3][3] += a4.w * b4.w;
        }
    }
#pragma unroll
    for (int i = 0; i < 4; ++i) {
        float4 v = make_float4(acc[i][0], acc[i][1], acc[i][2], acc[i][3]);
        *(float4*)&part[((size_t)ks * 12800 + rowbase + ty * 4 + i) * 64 + tx * 4] = v;
    }
}

// ---------------------------------------------------------------------------
extern "C" void kernel_launch(void* const* d_in, const int* in_sizes, int n_in,
                              void* d_out, int out_size, void* d_ws, size_t ws_size,
                              hipStream_t stream)
{
    const float* x  = (const float*)d_in[0];
    const float* W1 = (const float*)d_in[1];
    const float* b1 = (const float*)d_in[2];
    const float* W2 = (const float*)d_in[3];
    const float* b2 = (const float*)d_in[4];
    const float* W3 = (const float*)d_in[5];
    const float* b3 = (const float*)d_in[6];

    char* ws = (char*)d_ws;

    // layout (bytes):
    const size_t oW1p = 0;              //  18,874,368  W1 planes i8
    const size_t oW2p = 18874368;       //  50,331,648  W2 planes i8
    const size_t oW3p = 69206016;       //     786,432  W3 planes i8
    const size_t oXi8 = 69992448;       //  19,660,800  input spikes i8
    const size_t oS1  = 89653248;       //  26,214,400  s1 (one 25-step chunk)
    const size_t oS2  = 115867648;      //  52,428,800  s2 (all 50 steps)
    const size_t oM1  = 168296448;      //   4,194,304  m1 carry
    const size_t oM2  = 172490752;      //   4,194,304  m2 carry (contig w/ m1)
    const size_t oCur = 176685056;      // 104,857,600  cur1/cur2 shared; part3 alias
    const size_t NEED = 281542656;

    const double bnd1 = 1.0 / sqrt(1536.0);
    const double bnd2 = 1.0 / 64.0;
    const double bnd3 = 1.0 / 64.0;
    const float inv1 = (float)((double)DEN / bnd1), sb1 = (float)(bnd1 / (double)DEN);
    const float inv2 = (float)((double)DEN / bnd2), sb2 = (float)(bnd2 / (double)DEN);
    const float inv3 = (float)((double)DEN / bnd3), sb3 = (float)(bnd3 / (double)DEN);

    if (ws_size >= NEED) {
        char*  W1p  = ws + oW1p;
        char*  W2p  = ws + oW2p;
        char*  W3p  = ws + oW3p;
        char*  xi8  = ws + oXi8;
        char*  s1   = ws + oS1;
        char*  s2   = ws + oS2;
        float* m1   = (float*)(ws + oM1);
        float* m2   = (float*)(ws + oM2);
        float* cur  = (float*)(ws + oCur);
        float* part3 = cur;   // reuse after lif2_scan of chunk 1

        split3_i8<<<6144, 256, 0, stream>>>((const float4*)W1, W1p,
                                            (size_t)4096 * 1536, inv1);
        split3_i8<<<16384, 256, 0, stream>>>((const float4*)W2, W2p,
                                             (size_t)4096 * 4096, inv2);
        split3_i8<<<256, 256, 0, stream>>>((const float4*)W3, W3p,
                                           (size_t)64 * 4096, inv3);
        xcvt_i8<<<19200, 256, 0, stream>>>((const float4*)x, (uint32_t*)xi8);
        zero_ws<<<2048, 256, 0, stream>>>((float4*)m1);   // m1 + m2 contiguous

        const size_t chunk_rows = (size_t)25 * BATCH;     // 6400
        for (int chunk = 0; chunk < 2; ++chunk) {
            gemm_planes_bd2<1536><<<800, 512, 0, stream>>>(
                xi8 + chunk * chunk_rows * 1536, W1p, cur, sb1);
            lif_scan<<<1024, 256, 0, stream>>>(cur, b1, m1, s1);
            gemm_planes_bd2<4096><<<800, 512, 0, stream>>>(s1, W2p, cur, sb2);
            lif_scan<<<1024, 256, 0, stream>>>(cur, b2, m2,
                                               s2 + chunk * chunk_rows * N_H);
        }
        gemm3_i8<<<dim3(100, 6), 256, 0, stream>>>(s2, W3p, part3, sb3);
        lif3_scan<6><<<64, 256, 0, stream>>>(part3, b3, (float*)d_out);
    } else {
        float*    m1     = (float*)(ws);
        float*    m2     = (float*)(ws + (size_t)4 * 1024 * 1024);
        float*    s1f    = (float*)(ws + (size_t)8 * 1024 * 1024);
        uint32_t* s2bits = (uint32_t*)(ws + (size_t)12 * 1024 * 1024);
        float*    part   = (float*)(ws + (size_t)20 * 1024 * 1024);

        zero_ws<<<2048, 256, 0, stream>>>((float4*)m1);
        for (int t = 0; t < T_STEPS; ++t) {
            gemm_lif<1536, false><<<dim3(64, 4), 512, 0, stream>>>(
                x + (size_t)t * BATCH * 1536, W1, b1, m1, s1f, nullptr);
            gemm_lif<4096, true><<<dim3(64, 4), 512, 0, stream>>>(
                s1f, W2, b2, m2, nullptr, s2bits + (size_t)t * BATCH * 128);
        }
        gemm3_bits<<<dim3(200, 4), 256, 0, stream>>>(s2bits, W3, part);
        lif3_scan<4><<<64, 256, 0, stream>>>(part, b3, (float*)d_out);
    }
}

// Round 8
// 2324.100 us; speedup vs baseline: 2.7993x; 1.2490x over previous
//
#include <hip/hip_runtime.h>
#include <stdint.h>
#include <stddef.h>
#include <math.h>

// ContextSNN round 16: B-direct on the PROVEN 256-thread/128x128 geometry.
// r13/r15 post-mortem: 512-thread blocks are hard-capped at 128 arch VGPRs
// (observed 3x; second launch_bounds arg irrelevant) -> the ~170-arch B-direct
// pipeline spilled every time. r10's 256-thread config is the one proven to
// get what it asks (84 arch + AGPRs, no spill; cap 256 at 8 waves/CU).
// Trimmed pipeline: av single-set read in-body (2-blocks/CU co-residency
// hides lgkm); bv 2-deep loaded 1 body ahead, issued BEFORE the A-stage so
// the compiler's counted pre-MFMA wait retires B and keeps A-stage in
// flight; 3-slot A-only LDS ring (24 KiB) staged 2 ahead; body-top
// s_waitcnt vmcnt(6) (= prev body's 4 B + 2 A) BEFORE the barrier; never
// drains mid-loop. Arch ~132 + acc 64 AGPR. Exact i32 plane fold unchanged.

#define T_STEPS 50
#define BATCH   256
#define N_H     4096
#define DEN     8355711   // 127*65536 + 127*256 + 127

typedef unsigned short u16;
typedef __attribute__((ext_vector_type(4))) int i32x4;
typedef __attribute__((ext_vector_type(4))) float f32x4;

#define GLL16(gp, lp) __builtin_amdgcn_global_load_lds( \
    (const __attribute__((address_space(1))) void*)(gp), \
    (__attribute__((address_space(3))) void*)(lp), 16, 0, 0)

// ---------------------------------------------------------------------------
// prep
// ---------------------------------------------------------------------------
__global__ __launch_bounds__(256) void zero_ws(float4* __restrict__ p) {
    p[(size_t)blockIdx.x * 256 + threadIdx.x] = make_float4(0.f, 0.f, 0.f, 0.f);
}

__device__ inline void digits3(float w, float inv_s, int& h, int& m, int& l) {
    int V = (int)rintf(w * inv_s);
    V = min(max(V, -DEN), DEN);
    l = ((V + 128) & 255) - 128;
    const int V2 = (V - l) >> 8;
    m = ((V2 + 128) & 255) - 128;
    h = (V2 - m) >> 8;
}

__global__ __launch_bounds__(256)
void split3_i8(const float4* __restrict__ W, char* __restrict__ P,
               size_t plane_elems, float inv_s)
{
    const size_t i = (size_t)blockIdx.x * 256 + threadIdx.x;
    const float4 w = W[i];
    int h0,m0,l0,h1,m1,l1,h2,m2,l2,h3,m3,l3;
    digits3(w.x, inv_s, h0, m0, l0);
    digits3(w.y, inv_s, h1, m1, l1);
    digits3(w.z, inv_s, h2, m2, l2);
    digits3(w.w, inv_s, h3, m3, l3);
    const uint32_t ph = (uint32_t)(uint8_t)h0 | ((uint32_t)(uint8_t)h1 << 8) |
                        ((uint32_t)(uint8_t)h2 << 16) | ((uint32_t)(uint8_t)h3 << 24);
    const uint32_t pm = (uint32_t)(uint8_t)m0 | ((uint32_t)(uint8_t)m1 << 8) |
                        ((uint32_t)(uint8_t)m2 << 16) | ((uint32_t)(uint8_t)m3 << 24);
    const uint32_t pl = (uint32_t)(uint8_t)l0 | ((uint32_t)(uint8_t)l1 << 8) |
                        ((uint32_t)(uint8_t)l2 << 16) | ((uint32_t)(uint8_t)l3 << 24);
    *(uint32_t*)&P[4 * i]                   = ph;
    *(uint32_t*)&P[plane_elems + 4 * i]     = pm;
    *(uint32_t*)&P[2 * plane_elems + 4 * i] = pl;
}

__global__ __launch_bounds__(256)
void xcvt_i8(const float4* __restrict__ in, uint32_t* __restrict__ out) {
    const size_t i = (size_t)blockIdx.x * 256 + threadIdx.x;
    const float4 v = in[i];
    out[i] = (uint32_t)(v.x > 0.5f) | ((uint32_t)(v.y > 0.5f) << 8) |
             ((uint32_t)(v.z > 0.5f) << 16) | ((uint32_t)(v.w > 0.5f) << 24);
}

// ---------------------------------------------------------------------------
// B-direct batched 3-plane i8 GEMM, 256 threads, 128x128 tile (r10 geometry).
// A[6400][K] x Wp[3][4096][K]^T -> cur[6400][4096].
// 4 waves (2M x 2N), per-wave 64x64. Grid 1600 = 50 rows x 32 cols (XCD swz).
// A: 3-slot LDS ring (3 x 8 KiB), staged 2 ahead via global_load_lds.
// B: direct global->reg dwordx4, 2-deep rotation, 1 body ahead.
// Body t: vmcnt(6) [prev body's 4 B + 2 A]; barrier; LOADB(t+1);
// STAGEA(t+2); ds_read av(t) in-body; 16 MFMA (av x bv[t%2]); fold.
// ---------------------------------------------------------------------------
template<int K>
__global__ __launch_bounds__(256, 2)
void gemm_planes_bd3(const char* __restrict__ A, const char* __restrict__ Wp,
                     float* __restrict__ cur, float s_base)
{
    const int ITERS = 3 * K / 64;     // 192 (K=4096) / 72 (K=1536); %6 == 0
    __shared__ char As[3][8192];      // 24 KiB

    const int tid  = threadIdx.x;
    const int wave = tid >> 6, lane = tid & 63;
    const int wm = wave >> 1, wn = wave & 1;

    const int bid   = blockIdx.x;
    const int cbase = (((bid & 7) << 2) + ((bid >> 3) & 3)) * 128;
    const int abase = (bid >> 5) * 128;

    i32x4 acc[4][4];
    f32x4 facc[4][4];
#pragma unroll
    for (int i = 0; i < 4; ++i)
#pragma unroll
        for (int j = 0; j < 4; ++j) { acc[i][j] = (i32x4)(0); facc[i][j] = (f32x4)(0.f); }

    // A staging map (byte-identical to r10's verified A side): 2 GLL16/thread.
    const int soff0 = wave * 2048 + lane * 16;
    const int soff1 = soff0 + 1024;
    const int r0 = soff0 >> 6, r1 = soff1 >> 6;
    const int kb0 = ((((soff0 >> 4) & 3) ^ ((r0 >> 1) & 3)) << 4);
    const int kb1 = ((((soff1 >> 4) & 3) ^ ((r1 >> 1) & 3)) << 4);
    const uint32_t aoff0 = (uint32_t)((abase + r0) * K + kb0);
    const uint32_t aoff1 = (uint32_t)((abase + r1) * K + kb1);
    const int dstA0 = wave * 2048;          // GLL16 dest: base + lane*16
    const int dstA1 = wave * 2048 + 1024;

    // A-frag read offsets (verified r9/r10)
    const int rlo = lane & 15, rhi = lane >> 4;
    const int qr  = (rlo >> 1) & 3;
    const int rdA = (wm * 64 + rlo) * 64 + ((rhi ^ qr) << 4);

    // B-frag direct-global byte offsets (verified r12..r15 structure):
    // frag j: W[cbase + wn*64 + j*16 + rlo][kn + rhi*16 .. +15]
    const uint32_t bb0 = (uint32_t)((cbase + wn * 64 +  0 + rlo) * K + rhi * 16);
    const uint32_t bb1 = (uint32_t)((cbase + wn * 64 + 16 + rlo) * K + rhi * 16);
    const uint32_t bb2 = (uint32_t)((cbase + wn * 64 + 32 + rlo) * K + rhi * 16);
    const uint32_t bb3 = (uint32_t)((cbase + wn * 64 + 48 + rlo) * K + rhi * 16);

#define LOADB(u, BV)                                                          \
    {                                                                         \
        const int pn_ = ((u) * 64) / K;                                       \
        const int kn_ = (u) * 64 - pn_ * K;                                   \
        const char* bk_ = Wp + (size_t)pn_ * ((size_t)N_H * K) + kn_;         \
        BV[0] = *(const i32x4*)(bk_ + bb0);                                   \
        BV[1] = *(const i32x4*)(bk_ + bb1);                                   \
        BV[2] = *(const i32x4*)(bk_ + bb2);                                   \
        BV[3] = *(const i32x4*)(bk_ + bb3);                                   \
    }

#define STAGEA(u, SS)                                                         \
    {                                                                         \
        const int pn_ = ((u) * 64) / K;                                       \
        const int kn_ = (u) * 64 - pn_ * K;                                   \
        const char* ak_ = A + kn_;                                            \
        GLL16(ak_ + aoff0, &As[SS][0] + dstA0);                               \
        GLL16(ak_ + aoff1, &As[SS][0] + dstA1);                               \
    }

#define FOLD(tt)                                                              \
    if (((((tt) + 1) * 64) % K) == 0) {                                       \
        const int p_ = ((tt) * 64) / K;                                       \
        const float sc_ = s_base * (float)(65536 >> (8 * p_));                \
        _Pragma("unroll")                                                     \
        for (int i = 0; i < 4; ++i)                                           \
            _Pragma("unroll")                                                 \
            for (int j = 0; j < 4; ++j) {                                     \
                _Pragma("unroll")                                             \
                for (int r = 0; r < 4; ++r)                                   \
                    facc[i][j][r] += sc_ * (float)acc[i][j][r];               \
                acc[i][j] = (i32x4)(0);                                       \
            }                                                                 \
    }

// BODY(tt, NW, BVC, BVL, SN, SS, GB, GS):
//   wait vmcnt(NW) [== loads issued in body tt-1]; barrier;
//   GB: load B(tt+1) -> BVL (issued FIRST: oldest in this body);
//   GS: stage A(tt+2) -> slot SS;
//   ds_read av <- slot SN (tile tt, staged 2 bodies ago, retired at top);
//   16 MFMA av x BVC; fold.
#define BODY(tt, NW, BVC, BVL, SN, SS, GB, GS)                                \
    {                                                                         \
        asm volatile("s_waitcnt vmcnt(" #NW ")" ::: "memory");                \
        __builtin_amdgcn_s_barrier();                                         \
        asm volatile("" ::: "memory");                                        \
        if (GB) LOADB((tt) + 1, BVL);                                         \
        if (GS) STAGEA((tt) + 2, SS);                                         \
        {                                                                     \
            const char* nb_ = &As[SN][0];                                     \
            _Pragma("unroll")                                                 \
            for (int i = 0; i < 4; ++i)                                       \
                av[i] = *(const i32x4*)(nb_ + rdA + i * 1024);                \
        }                                                                     \
        __builtin_amdgcn_s_setprio(1);                                        \
        _Pragma("unroll")                                                     \
        for (int i = 0; i < 4; ++i)                                           \
            _Pragma("unroll")                                                 \
            for (int j = 0; j < 4; ++j)                                       \
                acc[i][j] = __builtin_amdgcn_mfma_i32_16x16x64_i8(            \
                    av[i], BVC[j], acc[i][j], 0, 0, 0);                       \
        __builtin_amdgcn_s_setprio(0);                                        \
        FOLD(tt);                                                             \
    }

    i32x4 av[4], bv0[4], bv1[4];

    // prologue: B(0) first (oldest), then stage tiles 0,1. 8 outstanding;
    // body 0's vmcnt(2) retires B(0)+stage(0), leaves stage(1)'s 2.
    LOADB(0, bv0);
    STAGEA(0, 0);
    STAGEA(1, 1);

    // body 0: tt=0, slot 0, uses bv0, loads bv1, stages slot 2.
    BODY(0, 2, bv0, bv1, 0, 2, 1, 1);

    // main loop: bodies tt = t..t+5, t = 1 + 6k, up to ITERS-6.
    // Residues for t==1 mod 6: parity odd,even,... slots 1,2,0,1,2,0;
    // stage slots (tt+2)%3 = 0,1,2,0,1,2. Steady NW = 6.
    int t = 1;
    for (; t + 11 <= ITERS; t += 6) {
        BODY(t + 0, 6, bv1, bv0, 1, 0, 1, 1);
        BODY(t + 1, 6, bv0, bv1, 2, 1, 1, 1);
        BODY(t + 2, 6, bv1, bv0, 0, 2, 1, 1);
        BODY(t + 3, 6, bv0, bv1, 1, 0, 1, 1);
        BODY(t + 4, 6, bv1, bv0, 2, 1, 1, 1);
        BODY(t + 5, 6, bv0, bv1, 0, 2, 1, 1);
    }

    // tail: 5 bodies tt = ITERS-5 .. ITERS-1 (ITERS%6==0 -> tt==1..5 mod 6:
    // parity odd,even,odd,even,odd; slots 1,2,0,1,2).
    BODY(t + 0, 6, bv1, bv0, 1, 0, 1, 1);   // tt=ITERS-5: stage(ITERS-3)
    BODY(t + 1, 6, bv0, bv1, 2, 1, 1, 1);   // tt=ITERS-4: stage(ITERS-2)
    BODY(t + 2, 6, bv1, bv0, 0, 2, 1, 1);   // tt=ITERS-3: stage(ITERS-1)
    BODY(t + 3, 6, bv0, bv1, 1, 0, 1, 0);   // tt=ITERS-2: load B(ITERS-1)
    BODY(t + 4, 4, bv1, bv0, 2, 1, 0, 0);   // tt=ITERS-1: prev issued 4

#undef BODY
#undef FOLD
#undef STAGEA
#undef LOADB

    const int orow = abase + wm * 64 + rhi * 4;
    const int ocol = cbase + wn * 64 + rlo;
#pragma unroll
    for (int i = 0; i < 4; ++i)
#pragma unroll
        for (int j = 0; j < 4; ++j)
#pragma unroll
            for (int r = 0; r < 4; ++r)
                cur[(size_t)(orow + i * 16 + r) * N_H + ocol + j * 16] = facc[i][j][r];
}

// ---------------------------------------------------------------------------
// layer-3 i8 GEMM, double-buffered (unchanged, small)
// ---------------------------------------------------------------------------
__global__ __launch_bounds__(256, 2)
void gemm3_i8(const char* __restrict__ A, const char* __restrict__ W3p,
              float* __restrict__ part3, float s_base)
{
    __shared__ char As[2 * 8192];
    __shared__ char Bs[2 * 4096];

    const int tid  = threadIdx.x;
    const int wave = tid >> 6, lane = tid & 63;
    const int wm = wave >> 1, wn = wave & 1;

    const int rowbase = blockIdx.x * 128;
    const int z = blockIdx.y;
    const int p = z >> 1;
    const int kstart = (z & 1) * 2048;

    i32x4 acc[4][2];
#pragma unroll
    for (int i = 0; i < 4; ++i)
#pragma unroll
        for (int j = 0; j < 2; ++j) acc[i][j] = (i32x4)(0);

    const int soff0 = wave * 2048 + lane * 16;
    const int soff1 = soff0 + 1024;
    const int r0 = soff0 >> 6, r1 = soff1 >> 6;
    const int kb0 = ((((soff0 >> 4) & 3) ^ ((r0 >> 1) & 3)) << 4);
    const int kb1 = ((((soff1 >> 4) & 3) ^ ((r1 >> 1) & 3)) << 4);
    const int soffB = tid * 16;
    const int rB = soffB >> 6;
    const int kbB = ((((soffB >> 4) & 3) ^ ((rB >> 1) & 3)) << 4);

    const size_t aoff0 = (size_t)(rowbase + r0) * 4096 + kb0;
    const size_t aoff1 = (size_t)(rowbase + r1) * 4096 + kb1;
    const size_t boff  = (size_t)rB * 4096 + kbB;

    const char* Bp = W3p + (size_t)p * 64 * 4096;
    const int sbase = wave * 2048;
    const int sbaseB = wave * 1024;

    const int rlo = lane & 15, rhi = lane >> 4;
    const int qr = (rlo >> 1) & 3;
    const int rdA = (wm * 64 + rlo) * 64 + ((rhi ^ qr) << 4);
    const int rdB = (wn * 32 + rlo) * 64 + ((rhi ^ qr) << 4);

    {
        GLL16(A + kstart + aoff0, As + sbase);
        GLL16(A + kstart + aoff1, As + sbase + 1024);
        GLL16(Bp + kstart + boff, Bs + sbaseB);
    }
    __syncthreads();

    for (int it = 0; it < 32; ++it) {
        const int bufA = (it & 1) * 8192;
        const int bufB = (it & 1) * 4096;
        if (it + 1 < 32) {
            const int kn = kstart + (it + 1) * 64;
            GLL16(A + kn + aoff0, As + (8192 - bufA) + sbase);
            GLL16(A + kn + aoff1, As + (8192 - bufA) + sbase + 1024);
            GLL16(Bp + kn + boff, Bs + (4096 - bufB) + sbaseB);
        }

        const char* pAf = As + bufA + rdA;
        const char* pBf = Bs + bufB + rdB;
        i32x4 av[4], bv[2];
#pragma unroll
        for (int i = 0; i < 4; ++i) av[i] = *(const i32x4*)(pAf + i * 1024);
#pragma unroll
        for (int j = 0; j < 2; ++j) bv[j] = *(const i32x4*)(pBf + j * 1024);
#pragma unroll
        for (int i = 0; i < 4; ++i)
#pragma unroll
            for (int j = 0; j < 2; ++j)
                acc[i][j] = __builtin_amdgcn_mfma_i32_16x16x64_i8(
                    av[i], bv[j], acc[i][j], 0, 0, 0);
        __syncthreads();
    }

    const float sc = s_base * (float)(65536 >> (8 * p));
    float* pout = part3 + (size_t)z * (12800 * 64);
    const int orow = rowbase + wm * 64 + rhi * 4;
    const int ocol = wn * 32 + rlo;
#pragma unroll
    for (int i = 0; i < 4; ++i)
#pragma unroll
        for (int j = 0; j < 2; ++j)
#pragma unroll
            for (int r = 0; r < 4; ++r)
                pout[(size_t)(orow + i * 16 + r) * 64 + ocol + j * 16] =
                    (float)acc[i][j][r] * sc;
}

// ---------------------------------------------------------------------------
// elementwise LIF time-scan over 25 steps (one chunk)
// ---------------------------------------------------------------------------
__global__ __launch_bounds__(256)
void lif_scan(const float* __restrict__ cur, const float* __restrict__ bias,
              float* __restrict__ mem, char* __restrict__ sout)
{
    const int i4  = blockIdx.x * 256 + threadIdx.x;   // 0..262143
    const int col = (i4 << 2) & (N_H - 1);
    const int b   = i4 >> 10;
    const float4 bv = *(const float4*)&bias[col];
    const size_t mbase = (size_t)b * N_H + col;
    float4 m = *(const float4*)&mem[mbase];

    for (int t = 0; t < 25; ++t) {
        const size_t off = ((size_t)t * BATCH + b) * N_H + col;
        const float4 cv = *(const float4*)&cur[off];
        float4 mn;
        { const float c = cv.x + bv.x;
          mn.x = 0.9f * m.x + c - ((m.x > 1.0f) ? 1.0f : 0.0f); }
        { const float c = cv.y + bv.y;
          mn.y = 0.9f * m.y + c - ((m.y > 1.0f) ? 1.0f : 0.0f); }
        { const float c = cv.z + bv.z;
          mn.z = 0.9f * m.z + c - ((m.z > 1.0f) ? 1.0f : 0.0f); }
        { const float c = cv.w + bv.w;
          mn.w = 0.9f * m.w + c - ((m.w > 1.0f) ? 1.0f : 0.0f); }
        const uint32_t sp = (uint32_t)(mn.x > 1.0f) | ((uint32_t)(mn.y > 1.0f) << 8) |
                            ((uint32_t)(mn.z > 1.0f) << 16) | ((uint32_t)(mn.w > 1.0f) << 24);
        *(uint32_t*)&sout[off] = sp;
        m = mn;
    }
    *(float4*)&mem[mbase] = m;
}

template<int NG>
__global__ __launch_bounds__(256)
void lif3_scan(const float* __restrict__ part, const float* __restrict__ b3,
               float* __restrict__ out)
{
    const int g = blockIdx.x * 256 + threadIdx.x;
    const int j = g & 63;
    const int b = g >> 6;
    const float bj = b3[j];
    float m = 0.f, accum = 0.f;
    for (int t = 0; t < T_STEPS; ++t) {
        const size_t row = (size_t)t * 256 + b;
        float cur = bj;
#pragma unroll
        for (int q = 0; q < NG; ++q)
            cur += part[(size_t)q * (12800 * 64) + row * 64 + j];
        const float reset = (m > 1.0f) ? 1.0f : 0.0f;
        m = 0.9f * m + cur - reset;
        accum += (m > 1.0f) ? 1.0f : 0.0f;
    }
    out[g] = accum;
}

// ---------------------------------------------------------------------------
// fp32 fallback path (round 1) — used only if ws_size too small
// ---------------------------------------------------------------------------
template<int K, bool PACK_BITS>
__global__ __launch_bounds__(512)
void gemm_lif(const float* __restrict__ A, const float* __restrict__ W,
              const float* __restrict__ bias, float* __restrict__ mem,
              float* __restrict__ s_f32, uint32_t* __restrict__ s_bits)
{
    __shared__ float Asf[32][68];
    __shared__ float Wsf[32][68];
    __shared__ uint8_t us[64][64];

    const int tid = threadIdx.x;
    const int abase = blockIdx.y * 64;
    const int cbase = blockIdx.x * 64;
    const int tx = tid & 15;
    const int ty = tid >> 4;

    float acc[2][4];
#pragma unroll
    for (int i = 0; i < 2; ++i)
#pragma unroll
        for (int j = 0; j < 4; ++j) acc[i][j] = 0.f;

    const int lrow = tid >> 3;
    const int lg = tid & 7;

    for (int k0 = 0; k0 < K; k0 += 32) {
        const float4 av = *(const float4*)&A[(size_t)(abase + lrow) * K + k0 + lg * 4];
        const float4 wv = *(const float4*)&W[(size_t)(cbase + lrow) * K + k0 + lg * 4];
        __syncthreads();
        Asf[lg * 4 + 0][lrow] = av.x; Asf[lg * 4 + 1][lrow] = av.y;
        Asf[lg * 4 + 2][lrow] = av.z; Asf[lg * 4 + 3][lrow] = av.w;
        Wsf[lg * 4 + 0][lrow] = wv.x; Wsf[lg * 4 + 1][lrow] = wv.y;
        Wsf[lg * 4 + 2][lrow] = wv.z; Wsf[lg * 4 + 3][lrow] = wv.w;
        __syncthreads();
#pragma unroll
        for (int kk = 0; kk < 32; ++kk) {
            const float2 a2 = *(const float2*)&Asf[kk][ty * 2];
            const float4 b4 = *(const float4*)&Wsf[kk][tx * 4];
            acc[0][0] += a2.x * b4.x; acc[0][1] += a2.x * b4.y;
            acc[0][2] += a2.x * b4.z; acc[0][3] += a2.x * b4.w;
            acc[1][0] += a2.y * b4.x; acc[1][1] += a2.y * b4.y;
            acc[1][2] += a2.y * b4.z; acc[1][3] += a2.y * b4.w;
        }
    }

    const int r0 = abase + ty * 2;
    const int c0loc = tx * 4;
    const int c0 = cbase + c0loc;
    const float4 bv = *(const float4*)&bias[c0];

#pragma unroll
    for (int i = 0; i < 2; ++i) {
        const size_t off = (size_t)(r0 + i) * N_H + c0;
        const float4 mp = *(const float4*)&mem[off];
        float4 mn, sp;
        { float cur = acc[i][0] + bv.x;
          mn.x = 0.9f * mp.x + cur - ((mp.x > 1.0f) ? 1.0f : 0.0f);
          sp.x = (mn.x > 1.0f) ? 1.0f : 0.0f; }
        { float cur = acc[i][1] + bv.y;
          mn.y = 0.9f * mp.y + cur - ((mp.y > 1.0f) ? 1.0f : 0.0f);
          sp.y = (mn.y > 1.0f) ? 1.0f : 0.0f; }
        { float cur = acc[i][2] + bv.z;
          mn.z = 0.9f * mp.z + cur - ((mp.z > 1.0f) ? 1.0f : 0.0f);
          sp.z = (mn.z > 1.0f) ? 1.0f : 0.0f; }
        { float cur = acc[i][3] + bv.w;
          mn.w = 0.9f * mp.w + cur - ((mp.w > 1.0f) ? 1.0f : 0.0f);
          sp.w = (mn.w > 1.0f) ? 1.0f : 0.0f; }
        *(float4*)&mem[off] = mn;
        if constexpr (!PACK_BITS) {
            *(float4*)&s_f32[off] = sp;
        } else {
            us[ty * 2 + i][c0loc + 0] = (uint8_t)sp.x;
            us[ty * 2 + i][c0loc + 1] = (uint8_t)sp.y;
            us[ty * 2 + i][c0loc + 2] = (uint8_t)sp.z;
            us[ty * 2 + i][c0loc + 3] = (uint8_t)sp.w;
        }
    }

    if constexpr (PACK_BITS) {
        __syncthreads();
        if (tid < 128) {
            const int r = tid >> 1;
            const int w = tid & 1;
            uint32_t bits = 0;
#pragma unroll
            for (int b = 0; b < 32; ++b)
                bits |= ((uint32_t)us[r][w * 32 + b]) << b;
            s_bits[(size_t)(abase + r) * 128 + (cbase >> 5) + w] = bits;
        }
    }
}

__global__ __launch_bounds__(256)
void gemm3_bits(const uint32_t* __restrict__ s_bits, const float* __restrict__ W3,
                float* __restrict__ part)
{
    __shared__ float Asf[32][68];
    __shared__ float Wsf[32][68];

    const int tid = threadIdx.x;
    const int rowbase = blockIdx.x * 64;
    const int ks = blockIdx.y;
    const int tx = tid & 15;
    const int ty = tid >> 4;

    float acc[4][4];
#pragma unroll
    for (int i = 0; i < 4; ++i)
#pragma unroll
        for (int j = 0; j < 4; ++j) acc[i][j] = 0.f;

    const int r  = tid & 63;
    const int q  = tid >> 6;
    const int wr = tid >> 3;
    const int wg = tid & 7;

    for (int c = 0; c < 32; ++c) {
        const int k0 = ks * 1024 + c * 32;
        const uint32_t word = s_bits[(size_t)(rowbase + r) * 128 + (k0 >> 5)];
        const float4 wv0 = *(const float4*)&W3[(size_t)wr * 4096 + k0 + wg * 4];
        const float4 wv1 = *(const float4*)&W3[(size_t)(wr + 32) * 4096 + k0 + wg * 4];
        __syncthreads();
#pragma unroll
        for (int u = 0; u < 8; ++u)
            Asf[q * 8 + u][r] = (float)((word >> (q * 8 + u)) & 1u);
        Wsf[wg * 4 + 0][wr] = wv0.x;
        Wsf[wg * 4 + 1][wr] = wv0.y;
        Wsf[wg * 4 + 2][wr] = wv0.z;
        Wsf[wg * 4 + 3][wr] = wv0.w;
        Wsf[wg * 4 + 0][wr + 32] = wv1.x;
        Wsf[wg * 4 + 1][wr + 32] = wv1.y;
        Wsf[wg * 4 + 2][wr + 32] = wv1.z;
        Wsf[wg * 4 + 3][wr + 32] = wv1.w;
        __syncthreads();
#pragma unroll
        for (int kk = 0; kk < 32; ++kk) {
            const float4 a4 = *(const float4*)&Asf[kk][ty * 4];
            const float4 b4 = *(const float4*)&Wsf[kk][tx * 4];
            acc[0][0] += a4.x * b4.x; acc[0][1] += a4.x * b4.y;
            acc[0][2] += a4.x * b4.z; acc[0][3] += a4.x * b4.w;
            acc[1][0] += a4.y * b4.x; acc[1][1] += a4.y * b4.y;
            acc[1][2] += a4.y * b4.z; acc[1][3] += a4.y * b4.w;
            acc[2][0] += a4.z * b4.x; acc[2][1] += a4.z * b4.y;
            acc[2][2] += a4.z * b4.z; acc[2][3] += a4.z * b4.w;
            acc[3][0] += a4.w * b4.x; acc[3][1] += a4.w * b4.y;
            acc[3][2] += a4.w * b4.z; acc[3][3] += a4.w * b4.w;
        }
    }
#pragma unroll
    for (int i = 0; i < 4; ++i) {
        float4 v = make_float4(acc[i][0], acc[i][1], acc[i][2], acc[i][3]);
        *(float4*)&part[((size_t)ks * 12800 + rowbase + ty * 4 + i) * 64 + tx * 4] = v;
    }
}

// ---------------------------------------------------------------------------
extern "C" void kernel_launch(void* const* d_in, const int* in_sizes, int n_in,
                              void* d_out, int out_size, void* d_ws, size_t ws_size,
                              hipStream_t stream)
{
    const float* x  = (const float*)d_in[0];
    const float* W1 = (const float*)d_in[1];
    const float* b1 = (const float*)d_in[2];
    const float* W2 = (const float*)d_in[3];
    const float* b2 = (const float*)d_in[4];
    const float* W3 = (const float*)d_in[5];
    const float* b3 = (const float*)d_in[6];

    char* ws = (char*)d_ws;

    // layout (bytes):
    const size_t oW1p = 0;              //  18,874,368  W1 planes i8
    const size_t oW2p = 18874368;       //  50,331,648  W2 planes i8
    const size_t oW3p = 69206016;       //     786,432  W3 planes i8
    const size_t oXi8 = 69992448;       //  19,660,800  input spikes i8
    const size_t oS1  = 89653248;       //  26,214,400  s1 (one 25-step chunk)
    const size_t oS2  = 115867648;      //  52,428,800  s2 (all 50 steps)
    const size_t oM1  = 168296448;      //   4,194,304  m1 carry
    const size_t oM2  = 172490752;      //   4,194,304  m2 carry (contig w/ m1)
    const size_t oCur = 176685056;      // 104,857,600  cur1/cur2 shared; part3 alias
    const size_t NEED = 281542656;

    const double bnd1 = 1.0 / sqrt(1536.0);
    const double bnd2 = 1.0 / 64.0;
    const double bnd3 = 1.0 / 64.0;
    const float inv1 = (float)((double)DEN / bnd1), sb1 = (float)(bnd1 / (double)DEN);
    const float inv2 = (float)((double)DEN / bnd2), sb2 = (float)(bnd2 / (double)DEN);
    const float inv3 = (float)((double)DEN / bnd3), sb3 = (float)(bnd3 / (double)DEN);

    if (ws_size >= NEED) {
        char*  W1p  = ws + oW1p;
        char*  W2p  = ws + oW2p;
        char*  W3p  = ws + oW3p;
        char*  xi8  = ws + oXi8;
        char*  s1   = ws + oS1;
        char*  s2   = ws + oS2;
        float* m1   = (float*)(ws + oM1);
        float* m2   = (float*)(ws + oM2);
        float* cur  = (float*)(ws + oCur);
        float* part3 = cur;   // reuse after lif2_scan of chunk 1

        split3_i8<<<6144, 256, 0, stream>>>((const float4*)W1, W1p,
                                            (size_t)4096 * 1536, inv1);
        split3_i8<<<16384, 256, 0, stream>>>((const float4*)W2, W2p,
                                             (size_t)4096 * 4096, inv2);
        split3_i8<<<256, 256, 0, stream>>>((const float4*)W3, W3p,
                                           (size_t)64 * 4096, inv3);
        xcvt_i8<<<19200, 256, 0, stream>>>((const float4*)x, (uint32_t*)xi8);
        zero_ws<<<2048, 256, 0, stream>>>((float4*)m1);   // m1 + m2 contiguous

        const size_t chunk_rows = (size_t)25 * BATCH;     // 6400
        for (int chunk = 0; chunk < 2; ++chunk) {
            gemm_planes_bd3<1536><<<1600, 256, 0, stream>>>(
                xi8 + chunk * chunk_rows * 1536, W1p, cur, sb1);
            lif_scan<<<1024, 256, 0, stream>>>(cur, b1, m1, s1);
            gemm_planes_bd3<4096><<<1600, 256, 0, stream>>>(s1, W2p, cur, sb2);
            lif_scan<<<1024, 256, 0, stream>>>(cur, b2, m2,
                                               s2 + chunk * chunk_rows * N_H);
        }
        gemm3_i8<<<dim3(100, 6), 256, 0, stream>>>(s2, W3p, part3, sb3);
        lif3_scan<6><<<64, 256, 0, stream>>>(part3, b3, (float*)d_out);
    } else {
        float*    m1     = (float*)(ws);
        float*    m2     = (float*)(ws + (size_t)4 * 1024 * 1024);
        float*    s1f    = (float*)(ws + (size_t)8 * 1024 * 1024);
        uint32_t* s2bits = (uint32_t*)(ws + (size_t)12 * 1024 * 1024);
        float*    part   = (float*)(ws + (size_t)20 * 1024 * 1024);

        zero_ws<<<2048, 256, 0, stream>>>((float4*)m1);
        for (int t = 0; t < T_STEPS; ++t) {
            gemm_lif<1536, false><<<dim3(64, 4), 512, 0, stream>>>(
                x + (size_t)t * BATCH * 1536, W1, b1, m1, s1f, nullptr);
            gemm_lif<4096, true><<<dim3(64, 4), 512, 0, stream>>>(
                s1f, W2, b2, m2, nullptr, s2bits + (size_t)t * BATCH * 128);
        }
        gemm3_bits<<<dim3(200, 4), 256, 0, stream>>>(s2bits, W3, part);
        lif3_scan<4><<<64, 256, 0, stream>>>(part, b3, (float*)d_out);
    }
}

// Round 9
// 1301.723 us; speedup vs baseline: 4.9979x; 1.7854x over previous
//
#include <hip/hip_runtime.h>
#include <stdint.h>
#include <stddef.h>
#include <math.h>

// ContextSNN round 17: m201-style two-barrier phase schedule on r10's maps.
// r10's measured 1708cy/body == exact serial sum (MFMA 653 + LDS reads 750 +
// LDS writes 190 + sync) -> reads and MFMAs never overlap: reads for t+1 are
// issued before MFMA(t) in one barrier window and the pre-MFMA waitcnt
// covers them. Fix (verified pattern on gfx950, 62% MfmaUtil): per phase,
// ds_read CURRENT tile's frags BEFORE the barrier, MFMA after it; waves
// cross the trailing barrier with MFMAs draining, so the next phase's LDS
// burst overlaps this phase's MFMA drain. Counted vmcnt(6) before trailing
// barrier retires stage(t+1); never drains mid-loop. 4-slot ring (96 KiB),
// stage-3-ahead, single av/bv set (~116 arch regs, under the 512-thr cap).
// A/B staging maps, frag offsets, C-write, exact i32 plane fold: r10-verified.

#define T_STEPS 50
#define BATCH   256
#define N_H     4096
#define DEN     8355711   // 127*65536 + 127*256 + 127

typedef unsigned short u16;
typedef __attribute__((ext_vector_type(4))) int i32x4;
typedef __attribute__((ext_vector_type(4))) float f32x4;

#define GLL16(gp, lp) __builtin_amdgcn_global_load_lds( \
    (const __attribute__((address_space(1))) void*)(gp), \
    (__attribute__((address_space(3))) void*)(lp), 16, 0, 0)

// ---------------------------------------------------------------------------
// prep
// ---------------------------------------------------------------------------
__global__ __launch_bounds__(256) void zero_ws(float4* __restrict__ p) {
    p[(size_t)blockIdx.x * 256 + threadIdx.x] = make_float4(0.f, 0.f, 0.f, 0.f);
}

__device__ inline void digits3(float w, float inv_s, int& h, int& m, int& l) {
    int V = (int)rintf(w * inv_s);
    V = min(max(V, -DEN), DEN);
    l = ((V + 128) & 255) - 128;
    const int V2 = (V - l) >> 8;
    m = ((V2 + 128) & 255) - 128;
    h = (V2 - m) >> 8;
}

__global__ __launch_bounds__(256)
void split3_i8(const float4* __restrict__ W, char* __restrict__ P,
               size_t plane_elems, float inv_s)
{
    const size_t i = (size_t)blockIdx.x * 256 + threadIdx.x;
    const float4 w = W[i];
    int h0,m0,l0,h1,m1,l1,h2,m2,l2,h3,m3,l3;
    digits3(w.x, inv_s, h0, m0, l0);
    digits3(w.y, inv_s, h1, m1, l1);
    digits3(w.z, inv_s, h2, m2, l2);
    digits3(w.w, inv_s, h3, m3, l3);
    const uint32_t ph = (uint32_t)(uint8_t)h0 | ((uint32_t)(uint8_t)h1 << 8) |
                        ((uint32_t)(uint8_t)h2 << 16) | ((uint32_t)(uint8_t)h3 << 24);
    const uint32_t pm = (uint32_t)(uint8_t)m0 | ((uint32_t)(uint8_t)m1 << 8) |
                        ((uint32_t)(uint8_t)m2 << 16) | ((uint32_t)(uint8_t)m3 << 24);
    const uint32_t pl = (uint32_t)(uint8_t)l0 | ((uint32_t)(uint8_t)l1 << 8) |
                        ((uint32_t)(uint8_t)l2 << 16) | ((uint32_t)(uint8_t)l3 << 24);
    *(uint32_t*)&P[4 * i]                   = ph;
    *(uint32_t*)&P[plane_elems + 4 * i]     = pm;
    *(uint32_t*)&P[2 * plane_elems + 4 * i] = pl;
}

__global__ __launch_bounds__(256)
void xcvt_i8(const float4* __restrict__ in, uint32_t* __restrict__ out) {
    const size_t i = (size_t)blockIdx.x * 256 + threadIdx.x;
    const float4 v = in[i];
    out[i] = (uint32_t)(v.x > 0.5f) | ((uint32_t)(v.y > 0.5f) << 8) |
             ((uint32_t)(v.z > 0.5f) << 16) | ((uint32_t)(v.w > 0.5f) << 24);
}

// ---------------------------------------------------------------------------
// Two-barrier phase-scheduled batched 3-plane i8 GEMM.
// A[6400][K] x Wp[3][4096][K]^T -> cur[6400][4096].
// BM=256, BN=128, BK=64. 512 thr = 8 waves (4M x 2N); per-wave 64x64.
// LDS: 4-slot ring x 24 KiB (A 16K + B 8K) = 96 KiB dynamic, stage-3-ahead.
// Phase t: {ds_read frags(t) slot t%4; stage(t+3); BARRIER; sched_barrier;
//   setprio; 16 MFMA; setprio; vmcnt(6) [retires stage(t+1)]; fold; BARRIER}.
// Grid 800 = 25 row-blocks x 32 col-blocks (XCD swizzle on cols).
// ---------------------------------------------------------------------------
template<int K>
__global__ __launch_bounds__(512, 1)
void gemm_planes_ph(const char* __restrict__ A, const char* __restrict__ Wp,
                    float* __restrict__ cur, float s_base)
{
    const int ITERS = 3 * K / 64;     // 192 (K=4096) / 72 (K=1536); %4 == 0
    const int SLOT  = 24576;          // 16384 (A) + 8192 (B)
    extern __shared__ char Lds[];     // 4 * SLOT = 98304 B

    const int tid  = threadIdx.x;
    const int wave = tid >> 6, lane = tid & 63;
    const int wr = wave >> 1, wc = wave & 1;

    const int bid   = blockIdx.x;
    const int cbase = (((bid & 7) << 2) + ((bid >> 3) & 3)) * 128;
    const int abase = (bid >> 5) * 256;

    i32x4 acc[4][4];
    f32x4 facc[4][4];
#pragma unroll
    for (int i = 0; i < 4; ++i)
#pragma unroll
        for (int j = 0; j < 4; ++j) { acc[i][j] = (i32x4)(0); facc[i][j] = (f32x4)(0.f); }

    // staging map (verified r10): 3 x GLL16 per thread per tile.
    const int soff = tid * 16;               // 0..8191
    const int rs   = soff >> 6;              // row 0..127
    const int cs   = (soff >> 4) & 3;        // 16B chunk in row
    const int kbs  = ((cs ^ ((rs >> 1) & 3)) << 4);   // XOR bank swizzle
    const size_t aoff0 = (size_t)(abase + rs) * K + kbs;
    const size_t aoff1 = aoff0 + (size_t)128 * K;
    const size_t boff  = (size_t)(cbase + rs) * K + kbs;
    const int dstA0 = wave * 1024;
    const int dstA1 = 8192 + wave * 1024;
    const int dstB  = 16384 + wave * 1024;

    // fragment read offsets (verified r9/r10)
    const int rlo = lane & 15, rhi = lane >> 4;
    const int qr  = (rlo >> 1) & 3;
    const int rdA = (wr * 64 + rlo) * 64 + ((rhi ^ qr) << 4);
    const int rdB = 16384 + (wc * 64 + rlo) * 64 + ((rhi ^ qr) << 4);

    auto stage = [&](int u, int slot_off) {
        const int pn = (u * 64) / K;
        const int kn = u * 64 - pn * K;
        char* slot = Lds + slot_off;
        const char* ak = A + kn;
        const char* bk = Wp + (size_t)pn * ((size_t)N_H * K) + kn;
        GLL16(ak + aoff0, slot + dstA0);
        GLL16(ak + aoff1, slot + dstA1);
        GLL16(bk + boff,  slot + dstB);
    };

    i32x4 av[4], bv[4];

#define FOLD(tt)                                                              \
    if (((((tt) + 1) * 64) % K) == 0) {                                       \
        const int p_ = ((tt) * 64) / K;                                       \
        const float sc_ = s_base * (float)(65536 >> (8 * p_));                \
        _Pragma("unroll")                                                     \
        for (int i = 0; i < 4; ++i)                                           \
            _Pragma("unroll")                                                 \
            for (int j = 0; j < 4; ++j) {                                     \
                _Pragma("unroll")                                             \
                for (int r = 0; r < 4; ++r)                                   \
                    facc[i][j][r] += sc_ * (float)acc[i][j][r];               \
                acc[i][j] = (i32x4)(0);                                       \
            }                                                                 \
    }

// PH(tt, SN, SS, NW, GS, DOW):
//   ds_read frags(tt) from slot SN (retired+barriered last phase);
//   GS: issue stage(tt+3) -> slot SS;
//   BARRIER #1; sched_barrier(0) pin; setprio(1); 16 MFMA(tt); setprio(0);
//   DOW: s_waitcnt vmcnt(NW) [retires stage(tt+1) for next phase's read];
//   fold-if-plane-boundary; BARRIER #2.
#define PH(tt, SN, SS, NW, GS, DOW)                                           \
    {                                                                         \
        {                                                                     \
            const char* nb_ = Lds + (SN) * SLOT;                              \
            _Pragma("unroll")                                                 \
            for (int i = 0; i < 4; ++i)                                       \
                av[i] = *(const i32x4*)(nb_ + rdA + i * 1024);                \
            _Pragma("unroll")                                                 \
            for (int j = 0; j < 4; ++j)                                       \
                bv[j] = *(const i32x4*)(nb_ + rdB + j * 1024);                \
        }                                                                     \
        if (GS) stage((tt) + 3, (SS) * SLOT);                                 \
        __builtin_amdgcn_s_barrier();                                         \
        __builtin_amdgcn_sched_barrier(0);                                    \
        __builtin_amdgcn_s_setprio(1);                                        \
        _Pragma("unroll")                                                     \
        for (int i = 0; i < 4; ++i)                                           \
            _Pragma("unroll")                                                 \
            for (int j = 0; j < 4; ++j)                                       \
                acc[i][j] = __builtin_amdgcn_mfma_i32_16x16x64_i8(            \
                    av[i], bv[j], acc[i][j], 0, 0, 0);                        \
        __builtin_amdgcn_s_setprio(0);                                        \
        if (DOW) { asm volatile("s_waitcnt vmcnt(" #NW ")" ::: "memory"); }   \
        FOLD(tt);                                                             \
        __builtin_amdgcn_s_barrier();                                         \
    }

    // prologue: stage tiles 0,1,2 into slots 0,1,2 (9 loads);
    // retire stage(0) on every wave, barrier -> slot 0 readable by all.
    stage(0, 0); stage(1, SLOT); stage(2, 2 * SLOT);
    asm volatile("s_waitcnt vmcnt(6)" ::: "memory");
    __builtin_amdgcn_s_barrier();
    asm volatile("" ::: "memory");

    // main loop: phases tt..tt+3, slot residue tt%4 == 0. All stage-valid
    // (tt+6 <= ITERS-2). Steady vmcnt(6): outstanding 9 (stages tt+1..tt+3),
    // retire stage(tt+1).
    int t = 0;
    for (; t + 7 < ITERS; t += 4) {
        PH(t + 0, 0, 3, 6, 1, 1);
        PH(t + 1, 1, 0, 6, 1, 1);
        PH(t + 2, 2, 1, 6, 1, 1);
        PH(t + 3, 3, 2, 6, 1, 1);
    }
    // epilogue: t == ITERS-4 (residue 0).
    PH(t + 0, 0, 3, 6, 1, 1);   // stages tile ITERS-1 -> slot 3
    PH(t + 1, 1, 0, 3, 0, 1);   // outstanding 6; retire stage(ITERS-2)
    PH(t + 2, 2, 1, 0, 0, 1);   // outstanding 3; retire stage(ITERS-1)
    PH(t + 3, 3, 2, 0, 0, 0);   // last tile; no wait needed

#undef PH
#undef FOLD

    const int orow = abase + wr * 64 + rhi * 4;
    const int ocol = cbase + wc * 64 + rlo;
#pragma unroll
    for (int i = 0; i < 4; ++i)
#pragma unroll
        for (int j = 0; j < 4; ++j)
#pragma unroll
            for (int r = 0; r < 4; ++r)
                cur[(size_t)(orow + i * 16 + r) * N_H + ocol + j * 16] = facc[i][j][r];
}

// ---------------------------------------------------------------------------
// FALLBACK: r9 double-buffered plane GEMM (used if dynamic-LDS attr fails)
// ---------------------------------------------------------------------------
template<int K>
__global__ __launch_bounds__(256, 2)
void gemm_planes(const char* __restrict__ A, const char* __restrict__ Wp,
                 float* __restrict__ cur, float s_base)
{
    const int ITERS = 3 * K / 64;
    __shared__ char As[2 * 8192];
    __shared__ char Bs[2 * 8192];

    const int tid  = threadIdx.x;
    const int wave = tid >> 6, lane = tid & 63;
    const int wm = wave >> 1, wn = wave & 1;

    const int bid   = blockIdx.x;
    const int cbase = (((bid & 7) << 2) + ((bid >> 3) & 3)) * 128;
    const int abase = (bid >> 5) * 128;

    i32x4 acc[4][4];
    f32x4 facc[4][4];
#pragma unroll
    for (int i = 0; i < 4; ++i)
#pragma unroll
        for (int j = 0; j < 4; ++j) { acc[i][j] = (i32x4)(0); facc[i][j] = (f32x4)(0.f); }

    const int soff0 = wave * 2048 + lane * 16;
    const int soff1 = soff0 + 1024;
    const int r0 = soff0 >> 6, r1 = soff1 >> 6;
    const int kb0 = ((((soff0 >> 4) & 3) ^ ((r0 >> 1) & 3)) << 4);
    const int kb1 = ((((soff1 >> 4) & 3) ^ ((r1 >> 1) & 3)) << 4);

    const size_t aoff0 = (size_t)(abase + r0) * K + kb0;
    const size_t aoff1 = (size_t)(abase + r1) * K + kb1;
    const size_t boff0 = (size_t)(cbase + r0) * K + kb0;
    const size_t boff1 = (size_t)(cbase + r1) * K + kb1;

    const int sbase = wave * 2048;

    const int rlo = lane & 15, rhi = lane >> 4;
    const int qr = (rlo >> 1) & 3;
    const int rdA = (wm * 64 + rlo) * 64 + ((rhi ^ qr) << 4);
    const int rdB = (wn * 64 + rlo) * 64 + ((rhi ^ qr) << 4);

    {
        GLL16(A + aoff0, As + sbase);
        GLL16(A + aoff1, As + sbase + 1024);
        GLL16(Wp + boff0, Bs + sbase);
        GLL16(Wp + boff1, Bs + sbase + 1024);
    }
    __syncthreads();

    for (int it = 0; it < ITERS; ++it) {
        const int buf = (it & 1) * 8192;
        if (it + 1 < ITERS) {
            const int fn = (it + 1) * 64;
            const int pn = fn / K;
            const int kn = fn - pn * K;
            const int nbuf = 8192 - buf;
            const char* ak = A + kn;
            const char* bk = Wp + (size_t)pn * ((size_t)N_H * K) + kn;
            GLL16(ak + aoff0, As + nbuf + sbase);
            GLL16(ak + aoff1, As + nbuf + sbase + 1024);
            GLL16(bk + boff0, Bs + nbuf + sbase);
            GLL16(bk + boff1, Bs + nbuf + sbase + 1024);
        }

        const char* pAf = As + buf + rdA;
        const char* pBf = Bs + buf + rdB;
        i32x4 av[4], bv[4];
#pragma unroll
        for (int i = 0; i < 4; ++i) av[i] = *(const i32x4*)(pAf + i * 1024);
#pragma unroll
        for (int j = 0; j < 4; ++j) bv[j] = *(const i32x4*)(pBf + j * 1024);
#pragma unroll
        for (int i = 0; i < 4; ++i)
#pragma unroll
            for (int j = 0; j < 4; ++j)
                acc[i][j] = __builtin_amdgcn_mfma_i32_16x16x64_i8(
                    av[i], bv[j], acc[i][j], 0, 0, 0);

        if ((((it + 1) * 64) % K) == 0) {
            const int p = (it * 64) / K;
            const float sc = s_base * (float)(65536 >> (8 * p));
#pragma unroll
            for (int i = 0; i < 4; ++i)
#pragma unroll
                for (int j = 0; j < 4; ++j) {
#pragma unroll
                    for (int r = 0; r < 4; ++r)
                        facc[i][j][r] += sc * (float)acc[i][j][r];
                    acc[i][j] = (i32x4)(0);
                }
        }
        __syncthreads();
    }

    const int orow = abase + wm * 64 + rhi * 4;
    const int ocol = cbase + wn * 64 + rlo;
#pragma unroll
    for (int i = 0; i < 4; ++i)
#pragma unroll
        for (int j = 0; j < 4; ++j)
#pragma unroll
            for (int r = 0; r < 4; ++r)
                cur[(size_t)(orow + i * 16 + r) * N_H + ocol + j * 16] = facc[i][j][r];
}

// ---------------------------------------------------------------------------
// layer-3 i8 GEMM, double-buffered (unchanged, small)
// ---------------------------------------------------------------------------
__global__ __launch_bounds__(256, 2)
void gemm3_i8(const char* __restrict__ A, const char* __restrict__ W3p,
              float* __restrict__ part3, float s_base)
{
    __shared__ char As[2 * 8192];
    __shared__ char Bs[2 * 4096];

    const int tid  = threadIdx.x;
    const int wave = tid >> 6, lane = tid & 63;
    const int wm = wave >> 1, wn = wave & 1;

    const int rowbase = blockIdx.x * 128;
    const int z = blockIdx.y;
    const int p = z >> 1;
    const int kstart = (z & 1) * 2048;

    i32x4 acc[4][2];
#pragma unroll
    for (int i = 0; i < 4; ++i)
#pragma unroll
        for (int j = 0; j < 2; ++j) acc[i][j] = (i32x4)(0);

    const int soff0 = wave * 2048 + lane * 16;
    const int soff1 = soff0 + 1024;
    const int r0 = soff0 >> 6, r1 = soff1 >> 6;
    const int kb0 = ((((soff0 >> 4) & 3) ^ ((r0 >> 1) & 3)) << 4);
    const int kb1 = ((((soff1 >> 4) & 3) ^ ((r1 >> 1) & 3)) << 4);
    const int soffB = tid * 16;
    const int rB = soffB >> 6;
    const int kbB = ((((soffB >> 4) & 3) ^ ((rB >> 1) & 3)) << 4);

    const size_t aoff0 = (size_t)(rowbase + r0) * 4096 + kb0;
    const size_t aoff1 = (size_t)(rowbase + r1) * 4096 + kb1;
    const size_t boff  = (size_t)rB * 4096 + kbB;

    const char* Bp = W3p + (size_t)p * 64 * 4096;
    const int sbase = wave * 2048;
    const int sbaseB = wave * 1024;

    const int rlo = lane & 15, rhi = lane >> 4;
    const int qr = (rlo >> 1) & 3;
    const int rdA = (wm * 64 + rlo) * 64 + ((rhi ^ qr) << 4);
    const int rdB = (wn * 32 + rlo) * 64 + ((rhi ^ qr) << 4);

    {
        GLL16(A + kstart + aoff0, As + sbase);
        GLL16(A + kstart + aoff1, As + sbase + 1024);
        GLL16(Bp + kstart + boff, Bs + sbaseB);
    }
    __syncthreads();

    for (int it = 0; it < 32; ++it) {
        const int bufA = (it & 1) * 8192;
        const int bufB = (it & 1) * 4096;
        if (it + 1 < 32) {
            const int kn = kstart + (it + 1) * 64;
            GLL16(A + kn + aoff0, As + (8192 - bufA) + sbase);
            GLL16(A + kn + aoff1, As + (8192 - bufA) + sbase + 1024);
            GLL16(Bp + kn + boff, Bs + (4096 - bufB) + sbaseB);
        }

        const char* pAf = As + bufA + rdA;
        const char* pBf = Bs + bufB + rdB;
        i32x4 av[4], bv[2];
#pragma unroll
        for (int i = 0; i < 4; ++i) av[i] = *(const i32x4*)(pAf + i * 1024);
#pragma unroll
        for (int j = 0; j < 2; ++j) bv[j] = *(const i32x4*)(pBf + j * 1024);
#pragma unroll
        for (int i = 0; i < 4; ++i)
#pragma unroll
            for (int j = 0; j < 2; ++j)
                acc[i][j] = __builtin_amdgcn_mfma_i32_16x16x64_i8(
                    av[i], bv[j], acc[i][j], 0, 0, 0);
        __syncthreads();
    }

    const float sc = s_base * (float)(65536 >> (8 * p));
    float* pout = part3 + (size_t)z * (12800 * 64);
    const int orow = rowbase + wm * 64 + rhi * 4;
    const int ocol = wn * 32 + rlo;
#pragma unroll
    for (int i = 0; i < 4; ++i)
#pragma unroll
        for (int j = 0; j < 2; ++j)
#pragma unroll
            for (int r = 0; r < 4; ++r)
                pout[(size_t)(orow + i * 16 + r) * 64 + ocol + j * 16] =
                    (float)acc[i][j][r] * sc;
}

// ---------------------------------------------------------------------------
// elementwise LIF time-scan over 25 steps (one chunk)
// ---------------------------------------------------------------------------
__global__ __launch_bounds__(256)
void lif_scan(const float* __restrict__ cur, const float* __restrict__ bias,
              float* __restrict__ mem, char* __restrict__ sout)
{
    const int i4  = blockIdx.x * 256 + threadIdx.x;   // 0..262143
    const int col = (i4 << 2) & (N_H - 1);
    const int b   = i4 >> 10;
    const float4 bv = *(const float4*)&bias[col];
    const size_t mbase = (size_t)b * N_H + col;
    float4 m = *(const float4*)&mem[mbase];

    for (int t = 0; t < 25; ++t) {
        const size_t off = ((size_t)t * BATCH + b) * N_H + col;
        const float4 cv = *(const float4*)&cur[off];
        float4 mn;
        { const float c = cv.x + bv.x;
          mn.x = 0.9f * m.x + c - ((m.x > 1.0f) ? 1.0f : 0.0f); }
        { const float c = cv.y + bv.y;
          mn.y = 0.9f * m.y + c - ((m.y > 1.0f) ? 1.0f : 0.0f); }
        { const float c = cv.z + bv.z;
          mn.z = 0.9f * m.z + c - ((m.z > 1.0f) ? 1.0f : 0.0f); }
        { const float c = cv.w + bv.w;
          mn.w = 0.9f * m.w + c - ((m.w > 1.0f) ? 1.0f : 0.0f); }
        const uint32_t sp = (uint32_t)(mn.x > 1.0f) | ((uint32_t)(mn.y > 1.0f) << 8) |
                            ((uint32_t)(mn.z > 1.0f) << 16) | ((uint32_t)(mn.w > 1.0f) << 24);
        *(uint32_t*)&sout[off] = sp;
        m = mn;
    }
    *(float4*)&mem[mbase] = m;
}

template<int NG>
__global__ __launch_bounds__(256)
void lif3_scan(const float* __restrict__ part, const float* __restrict__ b3,
               float* __restrict__ out)
{
    const int g = blockIdx.x * 256 + threadIdx.x;
    const int j = g & 63;
    const int b = g >> 6;
    const float bj = b3[j];
    float m = 0.f, accum = 0.f;
    for (int t = 0; t < T_STEPS; ++t) {
        const size_t row = (size_t)t * 256 + b;
        float cur = bj;
#pragma unroll
        for (int q = 0; q < NG; ++q)
            cur += part[(size_t)q * (12800 * 64) + row * 64 + j];
        const float reset = (m > 1.0f) ? 1.0f : 0.0f;
        m = 0.9f * m + cur - reset;
        accum += (m > 1.0f) ? 1.0f : 0.0f;
    }
    out[g] = accum;
}

// ---------------------------------------------------------------------------
// fp32 fallback path (round 1) — used only if ws_size too small
// ---------------------------------------------------------------------------
template<int K, bool PACK_BITS>
__global__ __launch_bounds__(512)
void gemm_lif(const float* __restrict__ A, const float* __restrict__ W,
              const float* __restrict__ bias, float* __restrict__ mem,
              float* __restrict__ s_f32, uint32_t* __restrict__ s_bits)
{
    __shared__ float Asf[32][68];
    __shared__ float Wsf[32][68];
    __shared__ uint8_t us[64][64];

    const int tid = threadIdx.x;
    const int abase = blockIdx.y * 64;
    const int cbase = blockIdx.x * 64;
    const int tx = tid & 15;
    const int ty = tid >> 4;

    float acc[2][4];
#pragma unroll
    for (int i = 0; i < 2; ++i)
#pragma unroll
        for (int j = 0; j < 4; ++j) acc[i][j] = 0.f;

    const int lrow = tid >> 3;
    const int lg = tid & 7;

    for (int k0 = 0; k0 < K; k0 += 32) {
        const float4 av = *(const float4*)&A[(size_t)(abase + lrow) * K + k0 + lg * 4];
        const float4 wv = *(const float4*)&W[(size_t)(cbase + lrow) * K + k0 + lg * 4];
        __syncthreads();
        Asf[lg * 4 + 0][lrow] = av.x; Asf[lg * 4 + 1][lrow] = av.y;
        Asf[lg * 4 + 2][lrow] = av.z; Asf[lg * 4 + 3][lrow] = av.w;
        Wsf[lg * 4 + 0][lrow] = wv.x; Wsf[lg * 4 + 1][lrow] = wv.y;
        Wsf[lg * 4 + 2][lrow] = wv.z; Wsf[lg * 4 + 3][lrow] = wv.w;
        __syncthreads();
#pragma unroll
        for (int kk = 0; kk < 32; ++kk) {
            const float2 a2 = *(const float2*)&Asf[kk][ty * 2];
            const float4 b4 = *(const float4*)&Wsf[kk][tx * 4];
            acc[0][0] += a2.x * b4.x; acc[0][1] += a2.x * b4.y;
            acc[0][2] += a2.x * b4.z; acc[0][3] += a2.x * b4.w;
            acc[1][0] += a2.y * b4.x; acc[1][1] += a2.y * b4.y;
            acc[1][2] += a2.y * b4.z; acc[1][3] += a2.y * b4.w;
        }
    }

    const int r0 = abase + ty * 2;
    const int c0loc = tx * 4;
    const int c0 = cbase + c0loc;
    const float4 bv = *(const float4*)&bias[c0];

#pragma unroll
    for (int i = 0; i < 2; ++i) {
        const size_t off = (size_t)(r0 + i) * N_H + c0;
        const float4 mp = *(const float4*)&mem[off];
        float4 mn, sp;
        { float cur = acc[i][0] + bv.x;
          mn.x = 0.9f * mp.x + cur - ((mp.x > 1.0f) ? 1.0f : 0.0f);
          sp.x = (mn.x > 1.0f) ? 1.0f : 0.0f; }
        { float cur = acc[i][1] + bv.y;
          mn.y = 0.9f * mp.y + cur - ((mp.y > 1.0f) ? 1.0f : 0.0f);
          sp.y = (mn.y > 1.0f) ? 1.0f : 0.0f; }
        { float cur = acc[i][2] + bv.z;
          mn.z = 0.9f * mp.z + cur - ((mp.z > 1.0f) ? 1.0f : 0.0f);
          sp.z = (mn.z > 1.0f) ? 1.0f : 0.0f; }
        { float cur = acc[i][3] + bv.w;
          mn.w = 0.9f * mp.w + cur - ((mp.w > 1.0f) ? 1.0f : 0.0f);
          sp.w = (mn.w > 1.0f) ? 1.0f : 0.0f; }
        *(float4*)&mem[off] = mn;
        if constexpr (!PACK_BITS) {
            *(float4*)&s_f32[off] = sp;
        } else {
            us[ty * 2 + i][c0loc + 0] = (uint8_t)sp.x;
            us[ty * 2 + i][c0loc + 1] = (uint8_t)sp.y;
            us[ty * 2 + i][c0loc + 2] = (uint8_t)sp.z;
            us[ty * 2 + i][c0loc + 3] = (uint8_t)sp.w;
        }
    }

    if constexpr (PACK_BITS) {
        __syncthreads();
        if (tid < 128) {
            const int r = tid >> 1;
            const int w = tid & 1;
            uint32_t bits = 0;
#pragma unroll
            for (int b = 0; b < 32; ++b)
                bits |= ((uint32_t)us[r][w * 32 + b]) << b;
            s_bits[(size_t)(abase + r) * 128 + (cbase >> 5) + w] = bits;
        }
    }
}

__global__ __launch_bounds__(256)
void gemm3_bits(const uint32_t* __restrict__ s_bits, const float* __restrict__ W3,
                float* __restrict__ part)
{
    __shared__ float Asf[32][68];
    __shared__ float Wsf[32][68];

    const int tid = threadIdx.x;
    const int rowbase = blockIdx.x * 64;
    const int ks = blockIdx.y;
    const int tx = tid & 15;
    const int ty = tid >> 4;

    float acc[4][4];
#pragma unroll
    for (int i = 0; i < 4; ++i)
#pragma unroll
        for (int j = 0; j < 4; ++j) acc[i][j] = 0.f;

    const int r  = tid & 63;
    const int q  = tid >> 6;
    const int wr = tid >> 3;
    const int wg = tid & 7;

    for (int c = 0; c < 32; ++c) {
        const int k0 = ks * 1024 + c * 32;
        const uint32_t word = s_bits[(size_t)(rowbase + r) * 128 + (k0 >> 5)];
        const float4 wv0 = *(const float4*)&W3[(size_t)wr * 4096 + k0 + wg * 4];
        const float4 wv1 = *(const float4*)&W3[(size_t)(wr + 32) * 4096 + k0 + wg * 4];
        __syncthreads();
#pragma unroll
        for (int u = 0; u < 8; ++u)
            Asf[q * 8 + u][r] = (float)((word >> (q * 8 + u)) & 1u);
        Wsf[wg * 4 + 0][wr] = wv0.x;
        Wsf[wg * 4 + 1][wr] = wv0.y;
        Wsf[wg * 4 + 2][wr] = wv0.z;
        Wsf[wg * 4 + 3][wr] = wv0.w;
        Wsf[wg * 4 + 0][wr + 32] = wv1.x;
        Wsf[wg * 4 + 1][wr + 32] = wv1.y;
        Wsf[wg * 4 + 2][wr + 32] = wv1.z;
        Wsf[wg * 4 + 3][wr + 32] = wv1.w;
        __syncthreads();
#pragma unroll
        for (int kk = 0; kk < 32; ++kk) {
            const float4 a4 = *(const float4*)&Asf[kk][ty * 4];
            const float4 b4 = *(const float4*)&Wsf[kk][tx * 4];
            acc[0][0] += a4.x * b4.x; acc[0][1] += a4.x * b4.y;
            acc[0][2] += a4.x * b4.z; acc[0][3] += a4.x * b4.w;
            acc[1][0] += a4.y * b4.x; acc[1][1] += a4.y * b4.y;
            acc[1][2] += a4.y * b4.z; acc[1][3] += a4.y * b4.w;
            acc[2][0] += a4.z * b4.x; acc[2][1] += a4.z * b4.y;
            acc[2][2] += a4.z * b4.z; acc[2][3] += a4.z * b4.w;
            acc[3][0] += a4.w * b4.x; acc[3][1] += a4.w * b4.y;
            acc[3][2] += a4.w * b4.z; acc[3][3] += a4.w * b4.w;
        }
    }
#pragma unroll
    for (int i = 0; i < 4; ++i) {
        float4 v = make_float4(acc[i][0], acc[i][1], acc[i][2], acc[i][3]);
        *(float4*)&part[((size_t)ks * 12800 + rowbase + ty * 4 + i) * 64 + tx * 4] = v;
    }
}

// ---------------------------------------------------------------------------
extern "C" void kernel_launch(void* const* d_in, const int* in_sizes, int n_in,
                              void* d_out, int out_size, void* d_ws, size_t ws_size,
                              hipStream_t stream)
{
    const float* x  = (const float*)d_in[0];
    const float* W1 = (const float*)d_in[1];
    const float* b1 = (const float*)d_in[2];
    const float* W2 = (const float*)d_in[3];
    const float* b2 = (const float*)d_in[4];
    const float* W3 = (const float*)d_in[5];
    const float* b3 = (const float*)d_in[6];

    char* ws = (char*)d_ws;

    // layout (bytes):
    const size_t oW1p = 0;              //  18,874,368  W1 planes i8
    const size_t oW2p = 18874368;       //  50,331,648  W2 planes i8
    const size_t oW3p = 69206016;       //     786,432  W3 planes i8
    const size_t oXi8 = 69992448;       //  19,660,800  input spikes i8
    const size_t oS1  = 89653248;       //  26,214,400  s1 (one 25-step chunk)
    const size_t oS2  = 115867648;      //  52,428,800  s2 (all 50 steps)
    const size_t oM1  = 168296448;      //   4,194,304  m1 carry
    const size_t oM2  = 172490752;      //   4,194,304  m2 carry (contig w/ m1)
    const size_t oCur = 176685056;      // 104,857,600  cur1/cur2 shared; part3 alias
    const size_t NEED = 281542656;

    const double bnd1 = 1.0 / sqrt(1536.0);
    const double bnd2 = 1.0 / 64.0;
    const double bnd3 = 1.0 / 64.0;
    const float inv1 = (float)((double)DEN / bnd1), sb1 = (float)(bnd1 / (double)DEN);
    const float inv2 = (float)((double)DEN / bnd2), sb2 = (float)(bnd2 / (double)DEN);
    const float inv3 = (float)((double)DEN / bnd3), sb3 = (float)(bnd3 / (double)DEN);

    // one-time: allow 96 KiB dynamic LDS for the phase kernels (host-side
    // config, graph-capture safe). Fallback to the r9 kernel if it fails.
    static const bool ph_ok = []() {
        hipError_t e1 = hipFuncSetAttribute(
            reinterpret_cast<const void*>(&gemm_planes_ph<1536>),
            hipFuncAttributeMaxDynamicSharedMemorySize, 98304);
        hipError_t e2 = hipFuncSetAttribute(
            reinterpret_cast<const void*>(&gemm_planes_ph<4096>),
            hipFuncAttributeMaxDynamicSharedMemorySize, 98304);
        return e1 == hipSuccess && e2 == hipSuccess;
    }();

    if (ws_size >= NEED) {
        char*  W1p  = ws + oW1p;
        char*  W2p  = ws + oW2p;
        char*  W3p  = ws + oW3p;
        char*  xi8  = ws + oXi8;
        char*  s1   = ws + oS1;
        char*  s2   = ws + oS2;
        float* m1   = (float*)(ws + oM1);
        float* m2   = (float*)(ws + oM2);
        float* cur  = (float*)(ws + oCur);
        float* part3 = cur;   // reuse after lif2_scan of chunk 1

        split3_i8<<<6144, 256, 0, stream>>>((const float4*)W1, W1p,
                                            (size_t)4096 * 1536, inv1);
        split3_i8<<<16384, 256, 0, stream>>>((const float4*)W2, W2p,
                                             (size_t)4096 * 4096, inv2);
        split3_i8<<<256, 256, 0, stream>>>((const float4*)W3, W3p,
                                           (size_t)64 * 4096, inv3);
        xcvt_i8<<<19200, 256, 0, stream>>>((const float4*)x, (uint32_t*)xi8);
        zero_ws<<<2048, 256, 0, stream>>>((float4*)m1);   // m1 + m2 contiguous

        const size_t chunk_rows = (size_t)25 * BATCH;     // 6400
        for (int chunk = 0; chunk < 2; ++chunk) {
            if (ph_ok) {
                gemm_planes_ph<1536><<<800, 512, 98304, stream>>>(
                    xi8 + chunk * chunk_rows * 1536, W1p, cur, sb1);
            } else {
                gemm_planes<1536><<<1600, 256, 0, stream>>>(
                    xi8 + chunk * chunk_rows * 1536, W1p, cur, sb1);
            }
            lif_scan<<<1024, 256, 0, stream>>>(cur, b1, m1, s1);
            if (ph_ok) {
                gemm_planes_ph<4096><<<800, 512, 98304, stream>>>(
                    s1, W2p, cur, sb2);
            } else {
                gemm_planes<4096><<<1600, 256, 0, stream>>>(s1, W2p, cur, sb2);
            }
            lif_scan<<<1024, 256, 0, stream>>>(cur, b2, m2,
                                               s2 + chunk * chunk_rows * N_H);
        }
        gemm3_i8<<<dim3(100, 6), 256, 0, stream>>>(s2, W3p, part3, sb3);
        lif3_scan<6><<<64, 256, 0, stream>>>(part3, b3, (float*)d_out);
    } else {
        float*    m1     = (float*)(ws);
        float*    m2     = (float*)(ws + (size_t)4 * 1024 * 1024);
        float*    s1f    = (float*)(ws + (size_t)8 * 1024 * 1024);
        uint32_t* s2bits = (uint32_t*)(ws + (size_t)12 * 1024 * 1024);
        float*    part   = (float*)(ws + (size_t)20 * 1024 * 1024);

        zero_ws<<<2048, 256, 0, stream>>>((float4*)m1);
        for (int t = 0; t < T_STEPS; ++t) {
            gemm_lif<1536, false><<<dim3(64, 4), 512, 0, stream>>>(
                x + (size_t)t * BATCH * 1536, W1, b1, m1, s1f, nullptr);
            gemm_lif<4096, true><<<dim3(64, 4), 512, 0, stream>>>(
                s1f, W2, b2, m2, nullptr, s2bits + (size_t)t * BATCH * 128);
        }
        gemm3_bits<<<dim3(200, 4), 256, 0, stream>>>(s2bits, W3, part);
        lif3_scan<4><<<64, 256, 0, stream>>>(part, b3, (float*)d_out);
    }
}